// Round 7
// baseline (678.073 us; speedup 1.0000x reference)
//
#include <hip/hip_runtime.h>

#define NN 100000
#define NE 1600000
#define ET 1700000        // NE + NN self-loops
#define NEG 0.2f
#define FNEG 3.4e38f
#define NBSC 98           // scan blocks: ceil(NN/1024)
#define GX_PAD 136        // LDS channel pad: slot stride 272B -> 2-way (free)

// ---------------- workspace layout (bytes) ----------------
#define SRC_OFF   0ULL
#define DST_OFF   6800000ULL
#define RP_OFF    13600000ULL         // rowptr (NN+1)*4
#define CNT_OFF   14000128ULL         // deg / fill cursor NN*4
#define CSR_OFF   14400128ULL         // ET*4
#define W1F_OFF   21200128ULL         // 65536  (16mf x 4kk x 64lane x 8 bf16)
#define W2F_OFF   21265664ULL         // 16384
#define W3F_OFF   21282048ULL         // 3072
#define WSD_OFF   21285120ULL         // 4096   (a_s|a_d contracted W1: 4kk x 64 x 8)
#define SC_OFF    21289216ULL         // 1024 (block sums)
#define XB_OFF    21290240ULL         // x as bf16: N*128*2 = 25.6MB
#define H_OFF     46890240ULL         // h2b (6.4MB) / h3b (8MB)
#define AGG_OFF   54890240ULL         // agg1 51.2MB bf16; reused agg2
#define ALPH_OFF  106090240ULL        // alpha: ET*8*2 = 27.2MB (l1); ET*2 (l2,l3)
#define WS_NEED   133290240ULL
#define AS_OFF    SRC_OFF             // aS aliases src (dead after k_fill)
#define AD_OFF    DST_OFF

typedef short bf16x8 __attribute__((ext_vector_type(8)));
typedef float f32x4 __attribute__((ext_vector_type(4)));

__device__ __forceinline__ float lrelu(float x) { return x > 0.f ? x : NEG * x; }
__device__ __forceinline__ float b2f(unsigned short u) {
  return __uint_as_float(((unsigned)u) << 16);
}
__device__ __forceinline__ unsigned short f2bu(float f) {   // RNE f32->bf16
  unsigned u = __float_as_uint(f);
  return (unsigned short)((u + 0x7FFFu + ((u >> 16) & 1u)) >> 16);
}

__global__ __launch_bounds__(256) void k_sentinel(float* out, int n) {
  int i = blockIdx.x * 256 + threadIdx.x;
  if (i < n) out[i] = 12345.0f;
}

// Normalize edge_index (int32/int64 auto-detected) into int32 src/dst with
// self-loops appended; fused in-degree count.
__global__ __launch_bounds__(256) void k_prep_edges(const int* __restrict__ raw,
                                                    int* __restrict__ src,
                                                    int* __restrict__ dst,
                                                    int* __restrict__ deg) {
  bool is64 = true;
  #pragma unroll
  for (int i = 1; i < 32; i += 2) is64 = is64 && (raw[i] == 0);
  long long e = (long long)blockIdx.x * 256 + threadIdx.x;
  if (e >= ET) return;
  int s, d;
  if (e < NE) {
    if (is64) {
      const long long* r = (const long long*)raw;
      s = (int)r[e];
      d = (int)r[NE + e];
    } else {
      s = raw[e];
      d = raw[NE + e];
    }
  } else {
    s = d = (int)(e - NE);
  }
  src[e] = s;
  dst[e] = d;
  atomicAdd(&deg[d], 1);
}

// Block-level inclusive scan; rowptr[i+1] = block-local inclusive, bsum[b]=total.
__global__ __launch_bounds__(1024) void k_scan_a(const int* __restrict__ deg,
                                                 int* __restrict__ rowptr,
                                                 int* __restrict__ bsum) {
  __shared__ int wsum[16];
  const int lane = threadIdx.x & 63, wid = threadIdx.x >> 6;
  int i = blockIdx.x * 1024 + threadIdx.x;
  int x = (i < NN) ? deg[i] : 0;
  int inc = x;
  #pragma unroll
  for (int off = 1; off < 64; off <<= 1) {
    int t = __shfl_up(inc, off);
    if (lane >= off) inc += t;
  }
  if (lane == 63) wsum[wid] = inc;
  __syncthreads();
  if (wid == 0) {
    int w = (lane < 16) ? wsum[lane] : 0;
    #pragma unroll
    for (int off = 1; off < 16; off <<= 1) {
      int t = __shfl_up(w, off);
      if (lane >= off) w += t;
    }
    if (lane < 16) wsum[lane] = w;
  }
  __syncthreads();
  int base = wid ? wsum[wid - 1] : 0;
  if (i < NN) rowptr[i + 1] = base + inc;
  if (threadIdx.x == 1023) bsum[blockIdx.x] = base + inc;
}

// Exclusive scan of NBSC block sums (in place).
__global__ __launch_bounds__(128) void k_scan_b(int* __restrict__ bsum) {
  __shared__ int w0tot;
  int tid = threadIdx.x;
  int v = (tid < NBSC) ? bsum[tid] : 0;
  int inc = v;
  #pragma unroll
  for (int off = 1; off < 64; off <<= 1) {
    int t = __shfl_up(inc, off);
    if ((tid & 63) >= off) inc += t;
  }
  if (tid == 63) w0tot = inc;
  __syncthreads();
  if (tid >= 64) inc += w0tot;
  if (tid < NBSC) bsum[tid] = inc - v;
}

__global__ __launch_bounds__(1024) void k_scan_c(int* __restrict__ rowptr,
                                                 const int* __restrict__ bsum) {
  int i = blockIdx.x * 1024 + threadIdx.x;
  if (i < NN) rowptr[i + 1] += bsum[blockIdx.x];
  if (i == 0) rowptr[0] = 0;
}

__global__ __launch_bounds__(256) void k_fill(const int* __restrict__ src,
                                              const int* __restrict__ dst,
                                              const int* __restrict__ rowptr,
                                              int* __restrict__ cnt,
                                              int* __restrict__ csr) {
  long long e = (long long)blockIdx.x * 256 + threadIdx.x;
  if (e >= ET) return;
  int d = dst[e];
  int p = atomicAdd(&cnt[d], 1);
  csr[rowptr[d] + p] = src[e];
}

// Pre-arrange weights into MFMA A-fragment order as bf16.
// A-frag convention: row(channel) = lane&15, k = (lane>>4)*8 + j.
// Also builds WSD: [Ws1|Wd1] = per-head contraction of W1 with as1/ad1
// (channels 0-7 = a_s heads, 8-15 = a_d heads), K=128 in 4 kk-frags.
__global__ __launch_bounds__(256) void k_prep_w(const float* __restrict__ W1,
                                                const float* __restrict__ W2,
                                                const float* __restrict__ W3,
                                                const float* __restrict__ as1,
                                                const float* __restrict__ ad1,
                                                unsigned short* __restrict__ W1f,
                                                unsigned short* __restrict__ W2f,
                                                unsigned short* __restrict__ W3f,
                                                unsigned short* __restrict__ WSDf) {
  int idx = blockIdx.x * 256 + threadIdx.x;
  if (idx < 4096) {                       // W1: 16 mf x 4 kk
    int fg = idx >> 6, lane = idx & 63;
    int mf = fg >> 2, kk = fg & 3;
    int c = mf * 16 + (lane & 15), k0 = kk * 32 + (lane >> 4) * 8;
    unsigned short* o = W1f + idx * 8;
    #pragma unroll
    for (int j = 0; j < 8; ++j) o[j] = f2bu(W1[(k0 + j) * 256 + c]);
  } else if (idx < 5120) {                // W2: 2 mf x 8 kk
    int t = idx - 4096;
    int fg = t >> 6, lane = t & 63;
    int mf = fg >> 3, kk = fg & 7;
    int c = mf * 16 + (lane & 15), k0 = kk * 32 + (lane >> 4) * 8;
    unsigned short* o = W2f + t * 8;
    #pragma unroll
    for (int j = 0; j < 8; ++j) o[j] = f2bu(W2[(k0 + j) * 32 + c]);
  } else if (idx < 5312) {                // W3: 3 mf x 1 kk (pad ch>=40 with 0)
    int t = idx - 5120;
    int mf = t >> 6, lane = t & 63;
    int c = mf * 16 + (lane & 15), k0 = (lane >> 4) * 8;
    unsigned short* o = W3f + t * 8;
    #pragma unroll
    for (int j = 0; j < 8; ++j) o[j] = (c < 40) ? f2bu(W3[(k0 + j) * 40 + c]) : 0;
  } else if (idx < 5568) {                // WSD: 1 mf x 4 kk
    int t = idx - 5312;
    int kk = t >> 6, lane = t & 63;
    int c = lane & 15, hd = c & 7;
    int k0 = kk * 32 + (lane >> 4) * 8;
    const float* att = (c < 8) ? as1 : ad1;
    unsigned short* o = WSDf + t * 8;
    #pragma unroll
    for (int j = 0; j < 8; ++j) {
      float sacc = 0.f;
      for (int cc = 0; cc < 32; ++cc)
        sacc += W1[(k0 + j) * 256 + hd * 32 + cc] * att[hd * 32 + cc];
      o[j] = f2bu(sacc);
    }
  }
}

// a_s/a_d[n,8] = x[n,:] @ [Ws1|Wd1] via MFMA; also emits x as bf16 (xb).
// 64 nodes/block (4 waves x 16), K=128 (4 kk), 1 channel-frag (16 ch).
__global__ __launch_bounds__(256) void k_attx(const float* __restrict__ x,
                                              const bf16x8* __restrict__ WSDf,
                                              unsigned short* __restrict__ xb,
                                              float* __restrict__ a_s,
                                              float* __restrict__ a_d) {
  __shared__ __align__(16) unsigned short xs[64 * 128];
  const int tid = threadIdx.x;
  const int n0 = blockIdx.x * 64;
  for (int j = tid; j < 2048; j += 256) {       // stage x -> bf16 LDS + xb
    int r = j >> 5;
    int c4 = (j & 31) << 2;
    long long row = n0 + r; if (row >= NN) row = NN - 1;
    float4 v = *(const float4*)(x + row * 128 + c4);
    ushort4 o;
    o.x = f2bu(v.x); o.y = f2bu(v.y); o.z = f2bu(v.z); o.w = f2bu(v.w);
    *(ushort4*)&xs[r * 128 + c4] = o;
    *(ushort4*)(xb + row * 128 + c4) = o;       // clamped dup-write is benign
  }
  __syncthreads();
  const int w = tid >> 6, lane = tid & 63;
  const int nloc = w * 16 + (lane & 15);
  const int node = n0 + nloc;
  f32x4 acc = {0.f, 0.f, 0.f, 0.f};
  #pragma unroll
  for (int kk = 0; kk < 4; ++kk) {
    bf16x8 bfr = *(const bf16x8*)&xs[nloc * 128 + kk * 32 + (lane >> 4) * 8];
    acc = __builtin_amdgcn_mfma_f32_16x16x32_bf16(WSDf[kk * 64 + lane], bfr, acc, 0, 0, 0);
  }
  const int rg = lane >> 4;     // rows rg*4..rg*4+3: 0-7 a_s heads, 8-15 a_d heads
  if (node < NN) {
    float4 o = {acc[0], acc[1], acc[2], acc[3]};
    if (rg < 2) *(float4*)(a_s + node * 8 + rg * 4) = o;
    else        *(float4*)(a_d + node * 8 + (rg - 2) * 4) = o;
  }
}

// Layer-1 softmax: per-node max/sum + write alpha[ET][8] bf16. Wave per node.
__global__ __launch_bounds__(256) void k_msalpha1(const int* __restrict__ rowptr,
                                                  const int* __restrict__ csr,
                                                  const float* __restrict__ a_s,
                                                  const float* __restrict__ a_d,
                                                  unsigned short* __restrict__ alph) {
  const int node = blockIdx.x * 4 + (threadIdx.x >> 6);
  const int lane = threadIdx.x & 63;
  const int beg = rowptr[node], end = rowptr[node + 1];
  const int hd = lane & 7;
  const int eg = lane >> 3;
  const float adv = a_d[node * 8 + hd];
  float mx = -FNEG, sm = 0.f;
  for (int i = beg + eg; i < end; i += 8) {
    int s = csr[i];
    float v = lrelu(a_s[s * 8 + hd] + adv);
    float nm = fmaxf(mx, v);
    sm = sm * __expf(mx - nm) + __expf(v - nm);
    mx = nm;
  }
  #pragma unroll
  for (int off = 8; off < 64; off <<= 1) {
    float mo = __shfl_xor(mx, off);
    float so = __shfl_xor(sm, off);
    float nm = fmaxf(mx, mo);
    sm = sm * __expf(mx - nm) + so * __expf(mo - nm);
    mx = nm;
  }
  float rden = 1.0f / sm;
  for (int i = beg + eg; i < end; i += 8) {
    int s = csr[i];
    float v = lrelu(a_s[s * 8 + hd] + adv);
    alph[i * 8 + hd] = f2bu(__expf(v - mx) * rden);
  }
}

// Layer-1 x-space gather + deferred W1 GEMM + bias + ELU -> agg1 bf16.
// 16 nodes/block (16 waves); wave w gathers node n0+w into 8 head-acc float2;
// aggx -> LDS [8hd][16slot][136]; barrier; wave w computes output frag mf=w
// (head w>>1) via 4 MFMA reusing W1f; fused bias+ELU epilogue.
__global__ __launch_bounds__(1024) void k_gatherx(const int* __restrict__ rowptr,
                                                  const int* __restrict__ csr,
                                                  const unsigned short* __restrict__ alph,
                                                  const unsigned short* __restrict__ xb,
                                                  const bf16x8* __restrict__ W1f,
                                                  const float* __restrict__ b,
                                                  unsigned short* __restrict__ out) {
  __shared__ __align__(16) unsigned short ax[8 * 16 * GX_PAD];
  const int tid = threadIdx.x;
  const int w = tid >> 6, lane = tid & 63;
  const int n0 = blockIdx.x * 16;
  const int node = n0 + w;
  const int l2 = lane * 2;
  float2 acc[8];
  #pragma unroll
  for (int hd = 0; hd < 8; ++hd) acc[hd] = make_float2(0.f, 0.f);
  if (node < NN) {
    const int beg = rowptr[node], end = rowptr[node + 1];
    int s = csr[beg];
    uint4 ar = *(const uint4*)(alph + (long long)beg * 8);
    unsigned xr = *(const unsigned*)(xb + (long long)s * 128 + l2);
    for (int i = beg; i < end; ++i) {
      int sn = 0; uint4 arn = ar; unsigned xrn = xr;
      if (i + 1 < end) {                        // software-pipelined prefetch
        sn = csr[i + 1];
        arn = *(const uint4*)(alph + (long long)(i + 1) * 8);
        xrn = *(const unsigned*)(xb + (long long)sn * 128 + l2);
      }
      float x0 = b2f((unsigned short)(xr & 0xFFFFu));
      float x1 = b2f((unsigned short)(xr >> 16));
      unsigned aw0 = ar.x, aw1 = ar.y, aw2 = ar.z, aw3 = ar.w;
      float a0 = b2f((unsigned short)(aw0 & 0xFFFFu)), a1 = b2f((unsigned short)(aw0 >> 16));
      float a2 = b2f((unsigned short)(aw1 & 0xFFFFu)), a3 = b2f((unsigned short)(aw1 >> 16));
      float a4 = b2f((unsigned short)(aw2 & 0xFFFFu)), a5 = b2f((unsigned short)(aw2 >> 16));
      float a6 = b2f((unsigned short)(aw3 & 0xFFFFu)), a7 = b2f((unsigned short)(aw3 >> 16));
      acc[0].x += a0 * x0; acc[0].y += a0 * x1;
      acc[1].x += a1 * x0; acc[1].y += a1 * x1;
      acc[2].x += a2 * x0; acc[2].y += a2 * x1;
      acc[3].x += a3 * x0; acc[3].y += a3 * x1;
      acc[4].x += a4 * x0; acc[4].y += a4 * x1;
      acc[5].x += a5 * x0; acc[5].y += a5 * x1;
      acc[6].x += a6 * x0; acc[6].y += a6 * x1;
      acc[7].x += a7 * x0; acc[7].y += a7 * x1;
      s = sn; ar = arn; xr = xrn;
    }
  }
  #pragma unroll
  for (int hd = 0; hd < 8; ++hd) {              // aggx -> LDS slot w
    unsigned short* p = &ax[(hd * 16 + w) * GX_PAD + l2];
    p[0] = f2bu(acc[hd].x);
    p[1] = f2bu(acc[hd].y);
  }
  __syncthreads();
  // phase 2: wave w owns output frag mf=w (channels w*16..w*16+15), head w>>1
  const int hd = w >> 1;
  f32x4 c = {0.f, 0.f, 0.f, 0.f};
  #pragma unroll
  for (int kk = 0; kk < 4; ++kk) {
    bf16x8 bfr = *(const bf16x8*)&ax[(hd * 16 + (lane & 15)) * GX_PAD + kk * 32 + (lane >> 4) * 8];
    c = __builtin_amdgcn_mfma_f32_16x16x32_bf16(W1f[(w * 4 + kk) * 64 + lane], bfr, c, 0, 0, 0);
  }
  const int onode = n0 + (lane & 15);
  const int ch0 = w * 16 + (lane >> 4) * 4;
  if (onode < NN) {
    float4 bv = *(const float4*)(b + ch0);
    float v0 = c[0] + bv.x, v1 = c[1] + bv.y, v2 = c[2] + bv.z, v3 = c[3] + bv.w;
    v0 = v0 > 0.f ? v0 : expm1f(v0);
    v1 = v1 > 0.f ? v1 : expm1f(v1);
    v2 = v2 > 0.f ? v2 : expm1f(v2);
    v3 = v3 > 0.f ? v3 : expm1f(v3);
    ushort4 o;
    o.x = f2bu(v0); o.y = f2bu(v1); o.z = f2bu(v2); o.w = f2bu(v3);
    *(ushort4*)(out + (long long)onode * 256 + ch0) = o;
  }
}

// h2b[N,32](bf16) = x2b[N,256](bf16) @ W2, fused a_s/a_d (H=1).
__global__ __launch_bounds__(256) void k_gemm2(const unsigned short* __restrict__ x2,
                                               const bf16x8* __restrict__ W2f,
                                               const float* __restrict__ as2,
                                               const float* __restrict__ ad2,
                                               unsigned short* __restrict__ h,
                                               float* __restrict__ a_s,
                                               float* __restrict__ a_d) {
  __shared__ __align__(16) unsigned short xs[64 * 256];
  __shared__ float asL[32], adL[32];
  const int tid = threadIdx.x;
  const int n0 = blockIdx.x * 64;
  if (tid < 32) { asL[tid] = as2[tid]; adL[tid] = ad2[tid]; }
  for (int j = tid; j < 2048; j += 256) {
    int r = j >> 5;
    int c8 = (j & 31) << 3;
    long long row = n0 + r; if (row >= NN) row = NN - 1;
    *(uint4*)&xs[r * 256 + c8] = *(const uint4*)(x2 + row * 256 + c8);
  }
  __syncthreads();
  const int w = tid >> 6, lane = tid & 63;
  const int nloc = w * 16 + (lane & 15);
  const int node = n0 + nloc;
  bf16x8 bfr[8];
  #pragma unroll
  for (int kk = 0; kk < 8; ++kk)
    bfr[kk] = *(const bf16x8*)&xs[nloc * 256 + kk * 32 + (lane >> 4) * 8];
  const int ch_base = (lane >> 4) * 4;
  float sA = 0.f, sD = 0.f;
  #pragma unroll
  for (int mf = 0; mf < 2; ++mf) {
    f32x4 acc = {0.f, 0.f, 0.f, 0.f};
    #pragma unroll
    for (int kk = 0; kk < 8; ++kk) {
      bf16x8 af = W2f[(mf * 8 + kk) * 64 + lane];
      acc = __builtin_amdgcn_mfma_f32_16x16x32_bf16(af, bfr[kk], acc, 0, 0, 0);
    }
    const float* av = &asL[mf * 16 + ch_base];
    const float* dv = &adL[mf * 16 + ch_base];
    float ps = acc[0] * av[0] + acc[1] * av[1] + acc[2] * av[2] + acc[3] * av[3];
    float pd = acc[0] * dv[0] + acc[1] * dv[1] + acc[2] * dv[2] + acc[3] * dv[3];
    ps += __shfl_xor(ps, 16); ps += __shfl_xor(ps, 32);
    pd += __shfl_xor(pd, 16); pd += __shfl_xor(pd, 32);
    sA += ps; sD += pd;
    if (node < NN) {
      ushort4 o;
      o.x = f2bu(acc[0]); o.y = f2bu(acc[1]); o.z = f2bu(acc[2]); o.w = f2bu(acc[3]);
      *(ushort4*)&h[(long long)node * 32 + mf * 16 + ch_base] = o;
    }
  }
  if (lane < 16 && node < NN) { a_s[node] = sA; a_d[node] = sD; }
}

// h3b[N,40](bf16) = x3b[N,32](bf16) @ W3, fused a_s/a_d (H=1, 40ch padded).
__global__ __launch_bounds__(256) void k_gemm3(const unsigned short* __restrict__ x3,
                                               const bf16x8* __restrict__ W3f,
                                               const float* __restrict__ as3,
                                               const float* __restrict__ ad3,
                                               unsigned short* __restrict__ h,
                                               float* __restrict__ a_s,
                                               float* __restrict__ a_d) {
  __shared__ __align__(16) unsigned short xs[64 * 32];
  __shared__ float asL[48], adL[48];
  const int tid = threadIdx.x;
  const int n0 = blockIdx.x * 64;
  if (tid < 48) {
    asL[tid] = (tid < 40) ? as3[tid] : 0.f;
    adL[tid] = (tid < 40) ? ad3[tid] : 0.f;
  }
  {
    int r = tid >> 2;
    int c8 = (tid & 3) << 3;
    long long row = n0 + r; if (row >= NN) row = NN - 1;
    *(uint4*)&xs[r * 32 + c8] = *(const uint4*)(x3 + row * 32 + c8);
  }
  __syncthreads();
  const int w = tid >> 6, lane = tid & 63;
  const int nloc = w * 16 + (lane & 15);
  const int node = n0 + nloc;
  bf16x8 bfr = *(const bf16x8*)&xs[nloc * 32 + (lane >> 4) * 8];
  const int ch_base = (lane >> 4) * 4;
  float sA = 0.f, sD = 0.f;
  #pragma unroll
  for (int mf = 0; mf < 3; ++mf) {
    f32x4 acc = {0.f, 0.f, 0.f, 0.f};
    bf16x8 af = W3f[mf * 64 + lane];
    acc = __builtin_amdgcn_mfma_f32_16x16x32_bf16(af, bfr, acc, 0, 0, 0);
    const float* av = &asL[mf * 16 + ch_base];
    const float* dv = &adL[mf * 16 + ch_base];
    float ps = acc[0] * av[0] + acc[1] * av[1] + acc[2] * av[2] + acc[3] * av[3];
    float pd = acc[0] * dv[0] + acc[1] * dv[1] + acc[2] * dv[2] + acc[3] * dv[3];
    ps += __shfl_xor(ps, 16); ps += __shfl_xor(ps, 32);
    pd += __shfl_xor(pd, 16); pd += __shfl_xor(pd, 32);
    sA += ps; sD += pd;
    int ch0 = mf * 16 + ch_base;
    if (node < NN && ch0 < 40) {
      ushort4 o;
      o.x = f2bu(acc[0]); o.y = f2bu(acc[1]); o.z = f2bu(acc[2]); o.w = f2bu(acc[3]);
      *(ushort4*)&h[(long long)node * 40 + ch0] = o;
    }
  }
  if (lane < 16 && node < NN) { a_s[node] = sA; a_d[node] = sD; }
}

// H=1 softmax: max/sum + write alpha[ET] bf16. Half-wave per node (layers 2&3).
__global__ __launch_bounds__(256) void k_msalpha2(const int* __restrict__ rowptr,
                                                  const int* __restrict__ csr,
                                                  const float* __restrict__ a_s,
                                                  const float* __restrict__ a_d,
                                                  unsigned short* __restrict__ alph) {
  const int node = blockIdx.x * 8 + (threadIdx.x >> 5);
  const int lane = threadIdx.x & 31;
  const int beg = rowptr[node], end = rowptr[node + 1];
  const float adv = a_d[node];
  float mx = -FNEG, sm = 0.f;
  for (int i = beg + lane; i < end; i += 32) {
    float v = lrelu(a_s[csr[i]] + adv);
    float nm = fmaxf(mx, v);
    sm = sm * __expf(mx - nm) + __expf(v - nm);
    mx = nm;
  }
  #pragma unroll
  for (int off = 1; off < 32; off <<= 1) {
    float mo = __shfl_xor(mx, off, 32);
    float so = __shfl_xor(sm, off, 32);
    float nm = fmaxf(mx, mo);
    sm = sm * __expf(mx - nm) + so * __expf(mo - nm);
    mx = nm;
  }
  float rden = 1.0f / sm;
  for (int i = beg + lane; i < end; i += 32) {
    float v = lrelu(a_s[csr[i]] + adv);
    alph[i] = f2bu(__expf(v - mx) * rden);
  }
}

// Layer-2 pure gather + bias + ELU -> bf16. Half-wave per node, 2-way unroll.
__global__ __launch_bounds__(256) void k_gather2(const int* __restrict__ rowptr,
                                                 const int* __restrict__ csr,
                                                 const unsigned short* __restrict__ alph,
                                                 const unsigned short* __restrict__ h,
                                                 const float* __restrict__ b,
                                                 unsigned short* __restrict__ out) {
  const int node = blockIdx.x * 8 + (threadIdx.x >> 5);
  const int lane = threadIdx.x & 31;
  const int beg = rowptr[node], end = rowptr[node + 1];
  float acc = 0.f;
  int i = beg;
  for (; i + 2 <= end; i += 2) {
    int s0 = csr[i], s1 = csr[i + 1];
    float a0 = b2f(alph[i]), a1 = b2f(alph[i + 1]);
    acc += a0 * b2f(h[(long long)s0 * 32 + lane]);
    acc += a1 * b2f(h[(long long)s1 * 32 + lane]);
  }
  if (i < end) {
    acc += b2f(alph[i]) * b2f(h[(long long)csr[i] * 32 + lane]);
  }
  acc += b[lane];
  out[(long long)node * 32 + lane] = f2bu(acc > 0.f ? acc : expm1f(acc));
}

// Layer-3 pure gather + bias + log_softmax -> f32 out. Wave per node.
__global__ __launch_bounds__(256) void k_gather3(const int* __restrict__ rowptr,
                                                 const int* __restrict__ csr,
                                                 const unsigned short* __restrict__ alph,
                                                 const unsigned short* __restrict__ h,
                                                 const float* __restrict__ b,
                                                 float* __restrict__ out) {
  const int node = blockIdx.x * 4 + (threadIdx.x >> 6);
  const int lane = threadIdx.x & 63;
  const int beg = rowptr[node], end = rowptr[node + 1];
  float acc = 0.f;
  int i = beg;
  for (; i + 2 <= end; i += 2) {
    int s0 = csr[i], s1 = csr[i + 1];
    float a0 = b2f(alph[i]), a1 = b2f(alph[i + 1]);
    if (lane < 40) {
      acc += a0 * b2f(h[(long long)s0 * 40 + lane]);
      acc += a1 * b2f(h[(long long)s1 * 40 + lane]);
    }
  }
  if (i < end && lane < 40) {
    acc += b2f(alph[i]) * b2f(h[(long long)csr[i] * 40 + lane]);
  }
  float v = (lane < 40) ? acc + b[lane] : -FNEG;
  float vmax = v;
  #pragma unroll
  for (int off = 1; off < 64; off <<= 1) vmax = fmaxf(vmax, __shfl_xor(vmax, off));
  float ex = (lane < 40) ? __expf(v - vmax) : 0.f;
  float es = ex;
  #pragma unroll
  for (int off = 1; off < 64; off <<= 1) es += __shfl_xor(es, off);
  float lse = vmax + __logf(es);
  if (lane < 40) out[(long long)node * 40 + lane] = v - lse;
}

extern "C" void kernel_launch(void* const* d_in, const int* in_sizes, int n_in,
                              void* d_out, int out_size, void* d_ws, size_t ws_size,
                              hipStream_t stream) {
  const float* x   = (const float*)d_in[0];
  const int*   eix = (const int*)d_in[1];
  const float* W1  = (const float*)d_in[2];
  const float* as1 = (const float*)d_in[3];
  const float* ad1 = (const float*)d_in[4];
  const float* b1  = (const float*)d_in[5];
  const float* W2  = (const float*)d_in[6];
  const float* as2 = (const float*)d_in[7];
  const float* ad2 = (const float*)d_in[8];
  const float* b2  = (const float*)d_in[9];
  const float* W3  = (const float*)d_in[10];
  const float* as3 = (const float*)d_in[11];
  const float* ad3 = (const float*)d_in[12];
  const float* b3  = (const float*)d_in[13];
  float* out = (float*)d_out;

  if (ws_size < WS_NEED) {
    k_sentinel<<<(out_size + 255) / 256, 256, 0, stream>>>(out, out_size);
    return;
  }

  char* ws = (char*)d_ws;
  int*    src    = (int*)(ws + SRC_OFF);
  int*    dst    = (int*)(ws + DST_OFF);
  int*    rowptr = (int*)(ws + RP_OFF);
  int*    cnt    = (int*)(ws + CNT_OFF);
  int*    csr    = (int*)(ws + CSR_OFF);
  unsigned short* W1f  = (unsigned short*)(ws + W1F_OFF);
  unsigned short* W2f  = (unsigned short*)(ws + W2F_OFF);
  unsigned short* W3f  = (unsigned short*)(ws + W3F_OFF);
  unsigned short* WSDf = (unsigned short*)(ws + WSD_OFF);
  int*    bsum   = (int*)(ws + SC_OFF);
  unsigned short* xb   = (unsigned short*)(ws + XB_OFF);
  unsigned short* h2b  = (unsigned short*)(ws + H_OFF);
  unsigned short* h3b  = (unsigned short*)(ws + H_OFF);
  unsigned short* agg1 = (unsigned short*)(ws + AGG_OFF);
  unsigned short* agg2 = (unsigned short*)(ws + AGG_OFF);
  unsigned short* alph = (unsigned short*)(ws + ALPH_OFF);
  float*  aS     = (float*)(ws + AS_OFF);
  float*  aD     = (float*)(ws + AD_OFF);

  // ---- CSR build + weight prep ----
  k_prep_w<<<22, 256, 0, stream>>>(W1, W2, W3, as1, ad1, W1f, W2f, W3f, WSDf);
  hipMemsetAsync(ws + CNT_OFF, 0, 400000, stream);
  k_prep_edges<<<(ET + 255) / 256, 256, 0, stream>>>(eix, src, dst, cnt);
  k_scan_a<<<NBSC, 1024, 0, stream>>>(cnt, rowptr, bsum);
  k_scan_b<<<1, 128, 0, stream>>>(bsum);
  k_scan_c<<<NBSC, 1024, 0, stream>>>(rowptr, bsum);
  hipMemsetAsync(ws + CNT_OFF, 0, 400000, stream);
  k_fill<<<(ET + 255) / 256, 256, 0, stream>>>(src, dst, rowptr, cnt, csr);

  // ---- layer 1 (x-space): 128 -> 8x32 concat ----
  k_attx<<<(NN + 63) / 64, 256, 0, stream>>>(x, (const bf16x8*)WSDf, xb, aS, aD);
  k_msalpha1<<<NN / 4, 256, 0, stream>>>(rowptr, csr, aS, aD, alph);
  k_gatherx<<<(NN + 15) / 16, 1024, 0, stream>>>(rowptr, csr, alph, xb,
                                                 (const bf16x8*)W1f, b1, agg1);

  // ---- layer 2: 256 -> 32 ----
  k_gemm2<<<(NN + 63) / 64, 256, 0, stream>>>(agg1, (const bf16x8*)W2f, as2, ad2,
                                              h2b, aS, aD);
  k_msalpha2<<<NN / 8, 256, 0, stream>>>(rowptr, csr, aS, aD, alph);
  k_gather2<<<NN / 8, 256, 0, stream>>>(rowptr, csr, alph, h2b, b2, agg2);

  // ---- layer 3: 32 -> 40 ----
  k_gemm3<<<(NN + 63) / 64, 256, 0, stream>>>(agg2, (const bf16x8*)W3f, as3, ad3,
                                              h3b, aS, aD);
  k_msalpha2<<<NN / 8, 256, 0, stream>>>(rowptr, csr, aS, aD, alph);
  k_gather3<<<NN / 4, 256, 0, stream>>>(rowptr, csr, alph, h3b, b3, out);
}

// Round 8
// 589.863 us; speedup vs baseline: 1.1495x; 1.1495x over previous
//
#include <hip/hip_runtime.h>

#define NN 100000
#define NE 1600000
#define ET 1700000        // NE + NN self-loops
#define NEG 0.2f
#define FNEG 3.4e38f
#define NBSC 98           // scan blocks: ceil(NN/1024)

// ---------------- workspace layout (bytes) ----------------
#define SRC_OFF   0ULL
#define DST_OFF   6800000ULL
#define RP_OFF    13600000ULL         // rowptr (NN+1)*4
#define CNT_OFF   14000128ULL         // deg / fill cursor NN*4
#define CSR_OFF   14400128ULL         // ET*4
#define W1F_OFF   21200128ULL         // 65536  (16mf x 4kk x 64lane x 8 bf16)
#define W2F_OFF   21265664ULL         // 16384
#define W3F_OFF   21282048ULL         // 3072
#define SC_OFF    21285120ULL         // 1024 (block sums)
#define H_OFF     21286144ULL         // h1b 51.2MB (bf16); reused h2b/h3b
#define AGG_OFF   72486144ULL         // agg1 51.2MB bf16; reused agg2
#define ALPH_OFF  123686144ULL        // alpha: ET*8*2 = 27.2MB (l1); ET*2 (l2,l3)
#define WS_NEED   150886144ULL
#define AS_OFF    SRC_OFF             // aS aliases src (dead after k_fill)
#define AD_OFF    DST_OFF

typedef short bf16x8 __attribute__((ext_vector_type(8)));
typedef float f32x4 __attribute__((ext_vector_type(4)));

__device__ __forceinline__ float lrelu(float x) { return x > 0.f ? x : NEG * x; }
__device__ __forceinline__ float b2f(unsigned short u) {
  return __uint_as_float(((unsigned)u) << 16);
}
__device__ __forceinline__ unsigned short f2bu(float f) {   // RNE f32->bf16
  unsigned u = __float_as_uint(f);
  return (unsigned short)((u + 0x7FFFu + ((u >> 16) & 1u)) >> 16);
}

__global__ __launch_bounds__(256) void k_sentinel(float* out, int n) {
  int i = blockIdx.x * 256 + threadIdx.x;
  if (i < n) out[i] = 12345.0f;
}

// Normalize edge_index (int32/int64 auto-detected) into int32 src/dst with
// self-loops appended; fused in-degree count.
__global__ __launch_bounds__(256) void k_prep_edges(const int* __restrict__ raw,
                                                    int* __restrict__ src,
                                                    int* __restrict__ dst,
                                                    int* __restrict__ deg) {
  bool is64 = true;
  #pragma unroll
  for (int i = 1; i < 32; i += 2) is64 = is64 && (raw[i] == 0);
  long long e = (long long)blockIdx.x * 256 + threadIdx.x;
  if (e >= ET) return;
  int s, d;
  if (e < NE) {
    if (is64) {
      const long long* r = (const long long*)raw;
      s = (int)r[e];
      d = (int)r[NE + e];
    } else {
      s = raw[e];
      d = raw[NE + e];
    }
  } else {
    s = d = (int)(e - NE);
  }
  src[e] = s;
  dst[e] = d;
  atomicAdd(&deg[d], 1);
}

// Block-level inclusive scan; rowptr[i+1] = block-local inclusive, bsum[b]=total.
__global__ __launch_bounds__(1024) void k_scan_a(const int* __restrict__ deg,
                                                 int* __restrict__ rowptr,
                                                 int* __restrict__ bsum) {
  __shared__ int wsum[16];
  const int lane = threadIdx.x & 63, wid = threadIdx.x >> 6;
  int i = blockIdx.x * 1024 + threadIdx.x;
  int x = (i < NN) ? deg[i] : 0;
  int inc = x;
  #pragma unroll
  for (int off = 1; off < 64; off <<= 1) {
    int t = __shfl_up(inc, off);
    if (lane >= off) inc += t;
  }
  if (lane == 63) wsum[wid] = inc;
  __syncthreads();
  if (wid == 0) {
    int w = (lane < 16) ? wsum[lane] : 0;
    #pragma unroll
    for (int off = 1; off < 16; off <<= 1) {
      int t = __shfl_up(w, off);
      if (lane >= off) w += t;
    }
    if (lane < 16) wsum[lane] = w;
  }
  __syncthreads();
  int base = wid ? wsum[wid - 1] : 0;
  if (i < NN) rowptr[i + 1] = base + inc;
  if (threadIdx.x == 1023) bsum[blockIdx.x] = base + inc;
}

// Exclusive scan of NBSC block sums (in place).
__global__ __launch_bounds__(128) void k_scan_b(int* __restrict__ bsum) {
  __shared__ int w0tot;
  int tid = threadIdx.x;
  int v = (tid < NBSC) ? bsum[tid] : 0;
  int inc = v;
  #pragma unroll
  for (int off = 1; off < 64; off <<= 1) {
    int t = __shfl_up(inc, off);
    if ((tid & 63) >= off) inc += t;
  }
  if (tid == 63) w0tot = inc;
  __syncthreads();
  if (tid >= 64) inc += w0tot;
  if (tid < NBSC) bsum[tid] = inc - v;
}

__global__ __launch_bounds__(1024) void k_scan_c(int* __restrict__ rowptr,
                                                 const int* __restrict__ bsum) {
  int i = blockIdx.x * 1024 + threadIdx.x;
  if (i < NN) rowptr[i + 1] += bsum[blockIdx.x];
  if (i == 0) rowptr[0] = 0;
}

__global__ __launch_bounds__(256) void k_fill(const int* __restrict__ src,
                                              const int* __restrict__ dst,
                                              const int* __restrict__ rowptr,
                                              int* __restrict__ cnt,
                                              int* __restrict__ csr) {
  long long e = (long long)blockIdx.x * 256 + threadIdx.x;
  if (e >= ET) return;
  int d = dst[e];
  int p = atomicAdd(&cnt[d], 1);
  csr[rowptr[d] + p] = src[e];
}

// Pre-arrange W1/W2/W3 (f32) into MFMA A-fragment order as bf16.
// A-frag convention: row(channel) = lane&15, k = (lane>>4)*8 + j.
__global__ __launch_bounds__(256) void k_prep_w(const float* __restrict__ W1,
                                                const float* __restrict__ W2,
                                                const float* __restrict__ W3,
                                                unsigned short* __restrict__ W1f,
                                                unsigned short* __restrict__ W2f,
                                                unsigned short* __restrict__ W3f) {
  int idx = blockIdx.x * 256 + threadIdx.x;
  if (idx < 4096) {                       // W1: 16 mf x 4 kk
    int fg = idx >> 6, lane = idx & 63;
    int mf = fg >> 2, kk = fg & 3;
    int c = mf * 16 + (lane & 15), k0 = kk * 32 + (lane >> 4) * 8;
    unsigned short* o = W1f + idx * 8;
    #pragma unroll
    for (int j = 0; j < 8; ++j) o[j] = f2bu(W1[(k0 + j) * 256 + c]);
  } else if (idx < 5120) {                // W2: 2 mf x 8 kk
    int t = idx - 4096;
    int fg = t >> 6, lane = t & 63;
    int mf = fg >> 3, kk = fg & 7;
    int c = mf * 16 + (lane & 15), k0 = kk * 32 + (lane >> 4) * 8;
    unsigned short* o = W2f + t * 8;
    #pragma unroll
    for (int j = 0; j < 8; ++j) o[j] = f2bu(W2[(k0 + j) * 32 + c]);
  } else if (idx < 5312) {                // W3: 3 mf x 1 kk (pad ch>=40 with 0)
    int t = idx - 5120;
    int mf = t >> 6, lane = t & 63;
    int c = mf * 16 + (lane & 15), k0 = (lane >> 4) * 8;
    unsigned short* o = W3f + t * 8;
    #pragma unroll
    for (int j = 0; j < 8; ++j) o[j] = (c < 40) ? f2bu(W3[(k0 + j) * 40 + c]) : 0;
  }
}

// h1b[N,256](bf16) = x[N,128] @ W1, fused a_s/a_d epilogue.
// 64 nodes/block (4 waves x 16), K=128 (4 k-steps), 16 channel-frags.
__global__ __launch_bounds__(256) void k_gemm1(const float* __restrict__ x,
                                               const bf16x8* __restrict__ W1f,
                                               const float* __restrict__ as1,
                                               const float* __restrict__ ad1,
                                               unsigned short* __restrict__ h,
                                               float* __restrict__ a_s,
                                               float* __restrict__ a_d) {
  __shared__ __align__(16) unsigned short xs[64 * 128];
  __shared__ float asL[256], adL[256];
  const int tid = threadIdx.x;
  const int n0 = blockIdx.x * 64;
  asL[tid] = as1[tid];
  adL[tid] = ad1[tid];
  for (int j = tid; j < 2048; j += 256) {       // stage x -> bf16 LDS
    int r = j >> 5;
    int c4 = (j & 31) << 2;
    long long row = n0 + r; if (row >= NN) row = NN - 1;
    float4 v = *(const float4*)(x + row * 128 + c4);
    unsigned short* p = &xs[r * 128 + c4];
    p[0] = f2bu(v.x); p[1] = f2bu(v.y); p[2] = f2bu(v.z); p[3] = f2bu(v.w);
  }
  __syncthreads();
  const int w = tid >> 6, lane = tid & 63;
  const int nloc = w * 16 + (lane & 15);
  const int node = n0 + nloc;
  bf16x8 bfr[4];
  #pragma unroll
  for (int kk = 0; kk < 4; ++kk)
    bfr[kk] = *(const bf16x8*)&xs[nloc * 128 + kk * 32 + (lane >> 4) * 8];
  const int ch_base = (lane >> 4) * 4;
  float sA[8] = {}, sD[8] = {};
  #pragma unroll
  for (int mf = 0; mf < 16; ++mf) {
    f32x4 acc = {0.f, 0.f, 0.f, 0.f};
    #pragma unroll
    for (int kk = 0; kk < 4; ++kk) {
      bf16x8 af = W1f[(mf * 4 + kk) * 64 + lane];
      acc = __builtin_amdgcn_mfma_f32_16x16x32_bf16(af, bfr[kk], acc, 0, 0, 0);
    }
    const float* av = &asL[mf * 16 + ch_base];
    const float* dv = &adL[mf * 16 + ch_base];
    float ps = acc[0] * av[0] + acc[1] * av[1] + acc[2] * av[2] + acc[3] * av[3];
    float pd = acc[0] * dv[0] + acc[1] * dv[1] + acc[2] * dv[2] + acc[3] * dv[3];
    ps += __shfl_xor(ps, 16); ps += __shfl_xor(ps, 32);
    pd += __shfl_xor(pd, 16); pd += __shfl_xor(pd, 32);
    sA[mf >> 1] += ps; sD[mf >> 1] += pd;
    if (node < NN) {
      ushort4 o;
      o.x = f2bu(acc[0]); o.y = f2bu(acc[1]); o.z = f2bu(acc[2]); o.w = f2bu(acc[3]);
      *(ushort4*)&h[(long long)node * 256 + mf * 16 + ch_base] = o;
    }
  }
  if (lane < 16 && node < NN) {
    #pragma unroll
    for (int hd = 0; hd < 8; ++hd) {
      a_s[node * 8 + hd] = sA[hd];
      a_d[node * 8 + hd] = sD[hd];
    }
  }
}

// Layer-1 softmax: per-node max/sum + write alpha[ET][8] bf16. Wave per node.
__global__ __launch_bounds__(256) void k_msalpha1(const int* __restrict__ rowptr,
                                                  const int* __restrict__ csr,
                                                  const float* __restrict__ a_s,
                                                  const float* __restrict__ a_d,
                                                  unsigned short* __restrict__ alph) {
  const int node = blockIdx.x * 4 + (threadIdx.x >> 6);
  const int lane = threadIdx.x & 63;
  const int beg = rowptr[node], end = rowptr[node + 1];
  const int hd = lane & 7;
  const int eg = lane >> 3;
  const float adv = a_d[node * 8 + hd];
  float mx = -FNEG, sm = 0.f;
  for (int i = beg + eg; i < end; i += 8) {
    int s = csr[i];
    float v = lrelu(a_s[s * 8 + hd] + adv);
    float nm = fmaxf(mx, v);
    sm = sm * __expf(mx - nm) + __expf(v - nm);
    mx = nm;
  }
  #pragma unroll
  for (int off = 8; off < 64; off <<= 1) {
    float mo = __shfl_xor(mx, off);
    float so = __shfl_xor(sm, off);
    float nm = fmaxf(mx, mo);
    sm = sm * __expf(mx - nm) + so * __expf(mo - nm);
    mx = nm;
  }
  float rden = 1.0f / sm;
  for (int i = beg + eg; i < end; i += 8) {
    int s = csr[i];
    float v = lrelu(a_s[s * 8 + hd] + adv);
    alph[i * 8 + hd] = f2bu(__expf(v - mx) * rden);
  }
}

// Layer-1 pure gather + bias + ELU -> bf16. Wave per node, 4-deep MLP.
__global__ __launch_bounds__(256) void k_gather1(const int* __restrict__ rowptr,
                                                 const int* __restrict__ csr,
                                                 const unsigned short* __restrict__ alph,
                                                 const unsigned short* __restrict__ h,
                                                 const float* __restrict__ b,
                                                 unsigned short* __restrict__ out) {
  const int node = blockIdx.x * 4 + (threadIdx.x >> 6);
  const int lane = threadIdx.x & 63;
  const int beg = rowptr[node], end = rowptr[node + 1];
  const int hd2 = lane >> 3;
  float4 acc = {0.f, 0.f, 0.f, 0.f};
  int i = beg;
  for (; i + 4 <= end; i += 4) {
    // 4 independent csr/alpha/h load triples -> 4 h-loads in flight
    int s0 = csr[i], s1 = csr[i + 1], s2 = csr[i + 2], s3 = csr[i + 3];
    float a0 = b2f(alph[(i + 0) * 8 + hd2]);
    float a1 = b2f(alph[(i + 1) * 8 + hd2]);
    float a2 = b2f(alph[(i + 2) * 8 + hd2]);
    float a3 = b2f(alph[(i + 3) * 8 + hd2]);
    ushort4 h0 = *(const ushort4*)(h + (long long)s0 * 256 + lane * 4);
    ushort4 h1 = *(const ushort4*)(h + (long long)s1 * 256 + lane * 4);
    ushort4 h2 = *(const ushort4*)(h + (long long)s2 * 256 + lane * 4);
    ushort4 h3 = *(const ushort4*)(h + (long long)s3 * 256 + lane * 4);
    acc.x += a0 * b2f(h0.x) + a1 * b2f(h1.x) + a2 * b2f(h2.x) + a3 * b2f(h3.x);
    acc.y += a0 * b2f(h0.y) + a1 * b2f(h1.y) + a2 * b2f(h2.y) + a3 * b2f(h3.y);
    acc.z += a0 * b2f(h0.z) + a1 * b2f(h1.z) + a2 * b2f(h2.z) + a3 * b2f(h3.z);
    acc.w += a0 * b2f(h0.w) + a1 * b2f(h1.w) + a2 * b2f(h2.w) + a3 * b2f(h3.w);
  }
  for (; i < end; ++i) {
    int s0 = csr[i];
    float a0 = b2f(alph[i * 8 + hd2]);
    ushort4 h0 = *(const ushort4*)(h + (long long)s0 * 256 + lane * 4);
    acc.x += a0 * b2f(h0.x);
    acc.y += a0 * b2f(h0.y);
    acc.z += a0 * b2f(h0.z);
    acc.w += a0 * b2f(h0.w);
  }
  float4 bv = *(const float4*)(b + lane * 4);
  acc.x += bv.x; acc.y += bv.y; acc.z += bv.z; acc.w += bv.w;
  acc.x = acc.x > 0.f ? acc.x : expm1f(acc.x);
  acc.y = acc.y > 0.f ? acc.y : expm1f(acc.y);
  acc.z = acc.z > 0.f ? acc.z : expm1f(acc.z);
  acc.w = acc.w > 0.f ? acc.w : expm1f(acc.w);
  ushort4 o;
  o.x = f2bu(acc.x); o.y = f2bu(acc.y); o.z = f2bu(acc.z); o.w = f2bu(acc.w);
  *(ushort4*)(out + (long long)node * 256 + lane * 4) = o;
}

// h2b[N,32](bf16) = x2b[N,256](bf16) @ W2, fused a_s/a_d (H=1).
__global__ __launch_bounds__(256) void k_gemm2(const unsigned short* __restrict__ x2,
                                               const bf16x8* __restrict__ W2f,
                                               const float* __restrict__ as2,
                                               const float* __restrict__ ad2,
                                               unsigned short* __restrict__ h,
                                               float* __restrict__ a_s,
                                               float* __restrict__ a_d) {
  __shared__ __align__(16) unsigned short xs[64 * 256];
  __shared__ float asL[32], adL[32];
  const int tid = threadIdx.x;
  const int n0 = blockIdx.x * 64;
  if (tid < 32) { asL[tid] = as2[tid]; adL[tid] = ad2[tid]; }
  for (int j = tid; j < 2048; j += 256) {
    int r = j >> 5;
    int c8 = (j & 31) << 3;
    long long row = n0 + r; if (row >= NN) row = NN - 1;
    *(uint4*)&xs[r * 256 + c8] = *(const uint4*)(x2 + row * 256 + c8);
  }
  __syncthreads();
  const int w = tid >> 6, lane = tid & 63;
  const int nloc = w * 16 + (lane & 15);
  const int node = n0 + nloc;
  bf16x8 bfr[8];
  #pragma unroll
  for (int kk = 0; kk < 8; ++kk)
    bfr[kk] = *(const bf16x8*)&xs[nloc * 256 + kk * 32 + (lane >> 4) * 8];
  const int ch_base = (lane >> 4) * 4;
  float sA = 0.f, sD = 0.f;
  #pragma unroll
  for (int mf = 0; mf < 2; ++mf) {
    f32x4 acc = {0.f, 0.f, 0.f, 0.f};
    #pragma unroll
    for (int kk = 0; kk < 8; ++kk) {
      bf16x8 af = W2f[(mf * 8 + kk) * 64 + lane];
      acc = __builtin_amdgcn_mfma_f32_16x16x32_bf16(af, bfr[kk], acc, 0, 0, 0);
    }
    const float* av = &asL[mf * 16 + ch_base];
    const float* dv = &adL[mf * 16 + ch_base];
    float ps = acc[0] * av[0] + acc[1] * av[1] + acc[2] * av[2] + acc[3] * av[3];
    float pd = acc[0] * dv[0] + acc[1] * dv[1] + acc[2] * dv[2] + acc[3] * dv[3];
    ps += __shfl_xor(ps, 16); ps += __shfl_xor(ps, 32);
    pd += __shfl_xor(pd, 16); pd += __shfl_xor(pd, 32);
    sA += ps; sD += pd;
    if (node < NN) {
      ushort4 o;
      o.x = f2bu(acc[0]); o.y = f2bu(acc[1]); o.z = f2bu(acc[2]); o.w = f2bu(acc[3]);
      *(ushort4*)&h[(long long)node * 32 + mf * 16 + ch_base] = o;
    }
  }
  if (lane < 16 && node < NN) { a_s[node] = sA; a_d[node] = sD; }
}

// h3b[N,40](bf16) = x3b[N,32](bf16) @ W3, fused a_s/a_d (H=1, 40ch padded).
__global__ __launch_bounds__(256) void k_gemm3(const unsigned short* __restrict__ x3,
                                               const bf16x8* __restrict__ W3f,
                                               const float* __restrict__ as3,
                                               const float* __restrict__ ad3,
                                               unsigned short* __restrict__ h,
                                               float* __restrict__ a_s,
                                               float* __restrict__ a_d) {
  __shared__ __align__(16) unsigned short xs[64 * 32];
  __shared__ float asL[48], adL[48];
  const int tid = threadIdx.x;
  const int n0 = blockIdx.x * 64;
  if (tid < 48) {
    asL[tid] = (tid < 40) ? as3[tid] : 0.f;
    adL[tid] = (tid < 40) ? ad3[tid] : 0.f;
  }
  {
    int r = tid >> 2;
    int c8 = (tid & 3) << 3;
    long long row = n0 + r; if (row >= NN) row = NN - 1;
    *(uint4*)&xs[r * 32 + c8] = *(const uint4*)(x3 + row * 32 + c8);
  }
  __syncthreads();
  const int w = tid >> 6, lane = tid & 63;
  const int nloc = w * 16 + (lane & 15);
  const int node = n0 + nloc;
  bf16x8 bfr = *(const bf16x8*)&xs[nloc * 32 + (lane >> 4) * 8];
  const int ch_base = (lane >> 4) * 4;
  float sA = 0.f, sD = 0.f;
  #pragma unroll
  for (int mf = 0; mf < 3; ++mf) {
    f32x4 acc = {0.f, 0.f, 0.f, 0.f};
    bf16x8 af = W3f[mf * 64 + lane];
    acc = __builtin_amdgcn_mfma_f32_16x16x32_bf16(af, bfr, acc, 0, 0, 0);
    const float* av = &asL[mf * 16 + ch_base];
    const float* dv = &adL[mf * 16 + ch_base];
    float ps = acc[0] * av[0] + acc[1] * av[1] + acc[2] * av[2] + acc[3] * av[3];
    float pd = acc[0] * dv[0] + acc[1] * dv[1] + acc[2] * dv[2] + acc[3] * dv[3];
    ps += __shfl_xor(ps, 16); ps += __shfl_xor(ps, 32);
    pd += __shfl_xor(pd, 16); pd += __shfl_xor(pd, 32);
    sA += ps; sD += pd;
    int ch0 = mf * 16 + ch_base;
    if (node < NN && ch0 < 40) {
      ushort4 o;
      o.x = f2bu(acc[0]); o.y = f2bu(acc[1]); o.z = f2bu(acc[2]); o.w = f2bu(acc[3]);
      *(ushort4*)&h[(long long)node * 40 + ch0] = o;
    }
  }
  if (lane < 16 && node < NN) { a_s[node] = sA; a_d[node] = sD; }
}

// H=1 softmax: max/sum + write alpha[ET] bf16. Half-wave per node (layers 2&3).
__global__ __launch_bounds__(256) void k_msalpha2(const int* __restrict__ rowptr,
                                                  const int* __restrict__ csr,
                                                  const float* __restrict__ a_s,
                                                  const float* __restrict__ a_d,
                                                  unsigned short* __restrict__ alph) {
  const int node = blockIdx.x * 8 + (threadIdx.x >> 5);
  const int lane = threadIdx.x & 31;
  const int beg = rowptr[node], end = rowptr[node + 1];
  const float adv = a_d[node];
  float mx = -FNEG, sm = 0.f;
  for (int i = beg + lane; i < end; i += 32) {
    float v = lrelu(a_s[csr[i]] + adv);
    float nm = fmaxf(mx, v);
    sm = sm * __expf(mx - nm) + __expf(v - nm);
    mx = nm;
  }
  #pragma unroll
  for (int off = 1; off < 32; off <<= 1) {
    float mo = __shfl_xor(mx, off, 32);
    float so = __shfl_xor(sm, off, 32);
    float nm = fmaxf(mx, mo);
    sm = sm * __expf(mx - nm) + so * __expf(mo - nm);
    mx = nm;
  }
  float rden = 1.0f / sm;
  for (int i = beg + lane; i < end; i += 32) {
    float v = lrelu(a_s[csr[i]] + adv);
    alph[i] = f2bu(__expf(v - mx) * rden);
  }
}

// Layer-2 pure gather + bias + ELU -> bf16. Half-wave per node, 4-deep MLP.
__global__ __launch_bounds__(256) void k_gather2(const int* __restrict__ rowptr,
                                                 const int* __restrict__ csr,
                                                 const unsigned short* __restrict__ alph,
                                                 const unsigned short* __restrict__ h,
                                                 const float* __restrict__ b,
                                                 unsigned short* __restrict__ out) {
  const int node = blockIdx.x * 8 + (threadIdx.x >> 5);
  const int lane = threadIdx.x & 31;
  const int beg = rowptr[node], end = rowptr[node + 1];
  float acc = 0.f;
  int i = beg;
  for (; i + 4 <= end; i += 4) {
    int s0 = csr[i], s1 = csr[i + 1], s2 = csr[i + 2], s3 = csr[i + 3];
    float a0 = b2f(alph[i]), a1 = b2f(alph[i + 1]);
    float a2 = b2f(alph[i + 2]), a3 = b2f(alph[i + 3]);
    unsigned short v0 = h[(long long)s0 * 32 + lane];
    unsigned short v1 = h[(long long)s1 * 32 + lane];
    unsigned short v2 = h[(long long)s2 * 32 + lane];
    unsigned short v3 = h[(long long)s3 * 32 + lane];
    acc += a0 * b2f(v0) + a1 * b2f(v1) + a2 * b2f(v2) + a3 * b2f(v3);
  }
  for (; i < end; ++i) {
    acc += b2f(alph[i]) * b2f(h[(long long)csr[i] * 32 + lane]);
  }
  acc += b[lane];
  out[(long long)node * 32 + lane] = f2bu(acc > 0.f ? acc : expm1f(acc));
}

// Layer-3 pure gather + bias + log_softmax -> f32 out. Wave per node, 4-deep.
__global__ __launch_bounds__(256) void k_gather3(const int* __restrict__ rowptr,
                                                 const int* __restrict__ csr,
                                                 const unsigned short* __restrict__ alph,
                                                 const unsigned short* __restrict__ h,
                                                 const float* __restrict__ b,
                                                 float* __restrict__ out) {
  const int node = blockIdx.x * 4 + (threadIdx.x >> 6);
  const int lane = threadIdx.x & 63;
  const int beg = rowptr[node], end = rowptr[node + 1];
  float acc = 0.f;
  int i = beg;
  for (; i + 4 <= end; i += 4) {
    int s0 = csr[i], s1 = csr[i + 1], s2 = csr[i + 2], s3 = csr[i + 3];
    float a0 = b2f(alph[i]), a1 = b2f(alph[i + 1]);
    float a2 = b2f(alph[i + 2]), a3 = b2f(alph[i + 3]);
    if (lane < 40) {
      unsigned short v0 = h[(long long)s0 * 40 + lane];
      unsigned short v1 = h[(long long)s1 * 40 + lane];
      unsigned short v2 = h[(long long)s2 * 40 + lane];
      unsigned short v3 = h[(long long)s3 * 40 + lane];
      acc += a0 * b2f(v0) + a1 * b2f(v1) + a2 * b2f(v2) + a3 * b2f(v3);
    }
  }
  for (; i < end; ++i) {
    if (lane < 40) acc += b2f(alph[i]) * b2f(h[(long long)csr[i] * 40 + lane]);
  }
  float v = (lane < 40) ? acc + b[lane] : -FNEG;
  float vmax = v;
  #pragma unroll
  for (int off = 1; off < 64; off <<= 1) vmax = fmaxf(vmax, __shfl_xor(vmax, off));
  float ex = (lane < 40) ? __expf(v - vmax) : 0.f;
  float es = ex;
  #pragma unroll
  for (int off = 1; off < 64; off <<= 1) es += __shfl_xor(es, off);
  float lse = vmax + __logf(es);
  if (lane < 40) out[(long long)node * 40 + lane] = v - lse;
}

extern "C" void kernel_launch(void* const* d_in, const int* in_sizes, int n_in,
                              void* d_out, int out_size, void* d_ws, size_t ws_size,
                              hipStream_t stream) {
  const float* x   = (const float*)d_in[0];
  const int*   eix = (const int*)d_in[1];
  const float* W1  = (const float*)d_in[2];
  const float* as1 = (const float*)d_in[3];
  const float* ad1 = (const float*)d_in[4];
  const float* b1  = (const float*)d_in[5];
  const float* W2  = (const float*)d_in[6];
  const float* as2 = (const float*)d_in[7];
  const float* ad2 = (const float*)d_in[8];
  const float* b2  = (const float*)d_in[9];
  const float* W3  = (const float*)d_in[10];
  const float* as3 = (const float*)d_in[11];
  const float* ad3 = (const float*)d_in[12];
  const float* b3  = (const float*)d_in[13];
  float* out = (float*)d_out;

  if (ws_size < WS_NEED) {
    k_sentinel<<<(out_size + 255) / 256, 256, 0, stream>>>(out, out_size);
    return;
  }

  char* ws = (char*)d_ws;
  int*    src    = (int*)(ws + SRC_OFF);
  int*    dst    = (int*)(ws + DST_OFF);
  int*    rowptr = (int*)(ws + RP_OFF);
  int*    cnt    = (int*)(ws + CNT_OFF);
  int*    csr    = (int*)(ws + CSR_OFF);
  unsigned short* W1f = (unsigned short*)(ws + W1F_OFF);
  unsigned short* W2f = (unsigned short*)(ws + W2F_OFF);
  unsigned short* W3f = (unsigned short*)(ws + W3F_OFF);
  int*    bsum   = (int*)(ws + SC_OFF);
  unsigned short* h1b  = (unsigned short*)(ws + H_OFF);
  unsigned short* h2b  = (unsigned short*)(ws + H_OFF);
  unsigned short* h3b  = (unsigned short*)(ws + H_OFF);
  unsigned short* agg1 = (unsigned short*)(ws + AGG_OFF);
  unsigned short* agg2 = (unsigned short*)(ws + AGG_OFF);
  unsigned short* alph = (unsigned short*)(ws + ALPH_OFF);
  float*  aS     = (float*)(ws + AS_OFF);
  float*  aD     = (float*)(ws + AD_OFF);

  // ---- CSR build + weight prep ----
  k_prep_w<<<21, 256, 0, stream>>>(W1, W2, W3, W1f, W2f, W3f);
  hipMemsetAsync(ws + CNT_OFF, 0, 400000, stream);
  k_prep_edges<<<(ET + 255) / 256, 256, 0, stream>>>(eix, src, dst, cnt);
  k_scan_a<<<NBSC, 1024, 0, stream>>>(cnt, rowptr, bsum);
  k_scan_b<<<1, 128, 0, stream>>>(bsum);
  k_scan_c<<<NBSC, 1024, 0, stream>>>(rowptr, bsum);
  hipMemsetAsync(ws + CNT_OFF, 0, 400000, stream);
  k_fill<<<(ET + 255) / 256, 256, 0, stream>>>(src, dst, rowptr, cnt, csr);

  // ---- layer 1: 128 -> 8x32 concat ----
  k_gemm1<<<(NN + 63) / 64, 256, 0, stream>>>(x, (const bf16x8*)W1f, as1, ad1,
                                              h1b, aS, aD);  // aS/aD over src/dst (dead)
  k_msalpha1<<<NN / 4, 256, 0, stream>>>(rowptr, csr, aS, aD, alph);
  k_gather1<<<NN / 4, 256, 0, stream>>>(rowptr, csr, alph, h1b, b1, agg1);

  // ---- layer 2: 256 -> 32 ----
  k_gemm2<<<(NN + 63) / 64, 256, 0, stream>>>(agg1, (const bf16x8*)W2f, as2, ad2,
                                              h2b, aS, aD);
  k_msalpha2<<<NN / 8, 256, 0, stream>>>(rowptr, csr, aS, aD, alph);
  k_gather2<<<NN / 8, 256, 0, stream>>>(rowptr, csr, alph, h2b, b2, agg2);

  // ---- layer 3: 32 -> 40 ----
  k_gemm3<<<(NN + 63) / 64, 256, 0, stream>>>(agg2, (const bf16x8*)W3f, as3, ad3,
                                              h3b, aS, aD);
  k_msalpha2<<<NN / 8, 256, 0, stream>>>(rowptr, csr, aS, aD, alph);
  k_gather3<<<NN / 4, 256, 0, stream>>>(rowptr, csr, alph, h3b, b3, out);
}

// Round 9
// 538.275 us; speedup vs baseline: 1.2597x; 1.0958x over previous
//
#include <hip/hip_runtime.h>

#define NN 100000
#define NE 1600000
#define ET 1700000        // NE + NN self-loops
#define NEG 0.2f
#define FNEG 3.4e38f
#define NBSC 98           // scan blocks: ceil(NN/1024)

// ---------------- workspace layout (bytes) ----------------
#define SRC_OFF   0ULL
#define DST_OFF   6800000ULL
#define RP_OFF    13600000ULL         // rowptr (NN+1)*4
#define CNT_OFF   14000128ULL         // deg / fill cursor NN*4
#define CSR_OFF   14400128ULL         // ET*4
#define W1F_OFF   21200128ULL         // 65536  (16mf x 4kk x 64lane x 8 bf16)
#define W2F_OFF   21265664ULL         // 16384
#define W3F_OFF   21282048ULL         // 3072
#define SC_OFF    21285120ULL         // 1024 (block sums)
#define H_OFF     21286144ULL         // h1b 51.2MB (bf16)
#define H2B_OFF   72486144ULL         // h2b 6.4MB
#define H3B_OFF   88486144ULL         // h3b 8MB
#define ALPH_OFF  123686144ULL        // alpha: ET*8*2 = 27.2MB (l1); ET*2 (l2,l3)
#define WS_NEED   150886144ULL
#define AS_OFF    SRC_OFF             // aS aliases src (dead after k_fill)
#define AD_OFF    DST_OFF

typedef short bf16x8 __attribute__((ext_vector_type(8)));
typedef float f32x4 __attribute__((ext_vector_type(4)));

__device__ __forceinline__ float lrelu(float x) { return x > 0.f ? x : NEG * x; }
__device__ __forceinline__ float b2f(unsigned short u) {
  return __uint_as_float(((unsigned)u) << 16);
}
__device__ __forceinline__ unsigned short f2bu(float f) {   // RNE f32->bf16
  unsigned u = __float_as_uint(f);
  return (unsigned short)((u + 0x7FFFu + ((u >> 16) & 1u)) >> 16);
}

__global__ __launch_bounds__(256) void k_sentinel(float* out, int n) {
  int i = blockIdx.x * 256 + threadIdx.x;
  if (i < n) out[i] = 12345.0f;
}

// Normalize edge_index (int32/int64 auto-detected) into int32 src/dst with
// self-loops appended; fused in-degree count.
__global__ __launch_bounds__(256) void k_prep_edges(const int* __restrict__ raw,
                                                    int* __restrict__ src,
                                                    int* __restrict__ dst,
                                                    int* __restrict__ deg) {
  bool is64 = true;
  #pragma unroll
  for (int i = 1; i < 32; i += 2) is64 = is64 && (raw[i] == 0);
  long long e = (long long)blockIdx.x * 256 + threadIdx.x;
  if (e >= ET) return;
  int s, d;
  if (e < NE) {
    if (is64) {
      const long long* r = (const long long*)raw;
      s = (int)r[e];
      d = (int)r[NE + e];
    } else {
      s = raw[e];
      d = raw[NE + e];
    }
  } else {
    s = d = (int)(e - NE);
  }
  src[e] = s;
  dst[e] = d;
  atomicAdd(&deg[d], 1);
}

// Block-level inclusive scan; rowptr[i+1] = block-local inclusive, bsum[b]=total.
__global__ __launch_bounds__(1024) void k_scan_a(const int* __restrict__ deg,
                                                 int* __restrict__ rowptr,
                                                 int* __restrict__ bsum) {
  __shared__ int wsum[16];
  const int lane = threadIdx.x & 63, wid = threadIdx.x >> 6;
  int i = blockIdx.x * 1024 + threadIdx.x;
  int x = (i < NN) ? deg[i] : 0;
  int inc = x;
  #pragma unroll
  for (int off = 1; off < 64; off <<= 1) {
    int t = __shfl_up(inc, off);
    if (lane >= off) inc += t;
  }
  if (lane == 63) wsum[wid] = inc;
  __syncthreads();
  if (wid == 0) {
    int w = (lane < 16) ? wsum[lane] : 0;
    #pragma unroll
    for (int off = 1; off < 16; off <<= 1) {
      int t = __shfl_up(w, off);
      if (lane >= off) w += t;
    }
    if (lane < 16) wsum[lane] = w;
  }
  __syncthreads();
  int base = wid ? wsum[wid - 1] : 0;
  if (i < NN) rowptr[i + 1] = base + inc;
  if (threadIdx.x == 1023) bsum[blockIdx.x] = base + inc;
}

// Exclusive scan of NBSC block sums (in place).
__global__ __launch_bounds__(128) void k_scan_b(int* __restrict__ bsum) {
  __shared__ int w0tot;
  int tid = threadIdx.x;
  int v = (tid < NBSC) ? bsum[tid] : 0;
  int inc = v;
  #pragma unroll
  for (int off = 1; off < 64; off <<= 1) {
    int t = __shfl_up(inc, off);
    if ((tid & 63) >= off) inc += t;
  }
  if (tid == 63) w0tot = inc;
  __syncthreads();
  if (tid >= 64) inc += w0tot;
  if (tid < NBSC) bsum[tid] = inc - v;
}

__global__ __launch_bounds__(1024) void k_scan_c(int* __restrict__ rowptr,
                                                 const int* __restrict__ bsum) {
  int i = blockIdx.x * 1024 + threadIdx.x;
  if (i < NN) rowptr[i + 1] += bsum[blockIdx.x];
  if (i == 0) rowptr[0] = 0;
}

__global__ __launch_bounds__(256) void k_fill(const int* __restrict__ src,
                                              const int* __restrict__ dst,
                                              const int* __restrict__ rowptr,
                                              int* __restrict__ cnt,
                                              int* __restrict__ csr) {
  long long e = (long long)blockIdx.x * 256 + threadIdx.x;
  if (e >= ET) return;
  int d = dst[e];
  int p = atomicAdd(&cnt[d], 1);
  csr[rowptr[d] + p] = src[e];
}

// Pre-arrange W1/W2/W3 (f32) into MFMA A-fragment order as bf16.
// A-frag convention: row(channel) = lane&15, k = (lane>>4)*8 + j.
__global__ __launch_bounds__(256) void k_prep_w(const float* __restrict__ W1,
                                                const float* __restrict__ W2,
                                                const float* __restrict__ W3,
                                                unsigned short* __restrict__ W1f,
                                                unsigned short* __restrict__ W2f,
                                                unsigned short* __restrict__ W3f) {
  int idx = blockIdx.x * 256 + threadIdx.x;
  if (idx < 4096) {                       // W1: 16 mf x 4 kk
    int fg = idx >> 6, lane = idx & 63;
    int mf = fg >> 2, kk = fg & 3;
    int c = mf * 16 + (lane & 15), k0 = kk * 32 + (lane >> 4) * 8;
    unsigned short* o = W1f + idx * 8;
    #pragma unroll
    for (int j = 0; j < 8; ++j) o[j] = f2bu(W1[(k0 + j) * 256 + c]);
  } else if (idx < 5120) {                // W2: 2 mf x 8 kk
    int t = idx - 4096;
    int fg = t >> 6, lane = t & 63;
    int mf = fg >> 3, kk = fg & 7;
    int c = mf * 16 + (lane & 15), k0 = kk * 32 + (lane >> 4) * 8;
    unsigned short* o = W2f + t * 8;
    #pragma unroll
    for (int j = 0; j < 8; ++j) o[j] = f2bu(W2[(k0 + j) * 32 + c]);
  } else if (idx < 5312) {                // W3: 3 mf x 1 kk (pad ch>=40 with 0)
    int t = idx - 5120;
    int mf = t >> 6, lane = t & 63;
    int c = mf * 16 + (lane & 15), k0 = (lane >> 4) * 8;
    unsigned short* o = W3f + t * 8;
    #pragma unroll
    for (int j = 0; j < 8; ++j) o[j] = (c < 40) ? f2bu(W3[(k0 + j) * 40 + c]) : 0;
  }
}

// h1b[N,256](bf16) = x[N,128] @ W1, fused a_s/a_d epilogue.
// 64 nodes/block (4 waves x 16), K=128 (4 k-steps), 16 channel-frags.
__global__ __launch_bounds__(256) void k_gemm1(const float* __restrict__ x,
                                               const bf16x8* __restrict__ W1f,
                                               const float* __restrict__ as1,
                                               const float* __restrict__ ad1,
                                               unsigned short* __restrict__ h,
                                               float* __restrict__ a_s,
                                               float* __restrict__ a_d) {
  __shared__ __align__(16) unsigned short xs[64 * 128];
  __shared__ float asL[256], adL[256];
  const int tid = threadIdx.x;
  const int n0 = blockIdx.x * 64;
  asL[tid] = as1[tid];
  adL[tid] = ad1[tid];
  for (int j = tid; j < 2048; j += 256) {       // stage x -> bf16 LDS
    int r = j >> 5;
    int c4 = (j & 31) << 2;
    long long row = n0 + r; if (row >= NN) row = NN - 1;
    float4 v = *(const float4*)(x + row * 128 + c4);
    unsigned short* p = &xs[r * 128 + c4];
    p[0] = f2bu(v.x); p[1] = f2bu(v.y); p[2] = f2bu(v.z); p[3] = f2bu(v.w);
  }
  __syncthreads();
  const int w = tid >> 6, lane = tid & 63;
  const int nloc = w * 16 + (lane & 15);
  const int node = n0 + nloc;
  bf16x8 bfr[4];
  #pragma unroll
  for (int kk = 0; kk < 4; ++kk)
    bfr[kk] = *(const bf16x8*)&xs[nloc * 128 + kk * 32 + (lane >> 4) * 8];
  const int ch_base = (lane >> 4) * 4;
  float sA[8] = {}, sD[8] = {};
  #pragma unroll
  for (int mf = 0; mf < 16; ++mf) {
    f32x4 acc = {0.f, 0.f, 0.f, 0.f};
    #pragma unroll
    for (int kk = 0; kk < 4; ++kk) {
      bf16x8 af = W1f[(mf * 4 + kk) * 64 + lane];
      acc = __builtin_amdgcn_mfma_f32_16x16x32_bf16(af, bfr[kk], acc, 0, 0, 0);
    }
    const float* av = &asL[mf * 16 + ch_base];
    const float* dv = &adL[mf * 16 + ch_base];
    float ps = acc[0] * av[0] + acc[1] * av[1] + acc[2] * av[2] + acc[3] * av[3];
    float pd = acc[0] * dv[0] + acc[1] * dv[1] + acc[2] * dv[2] + acc[3] * dv[3];
    ps += __shfl_xor(ps, 16); ps += __shfl_xor(ps, 32);
    pd += __shfl_xor(pd, 16); pd += __shfl_xor(pd, 32);
    sA[mf >> 1] += ps; sD[mf >> 1] += pd;
    if (node < NN) {
      ushort4 o;
      o.x = f2bu(acc[0]); o.y = f2bu(acc[1]); o.z = f2bu(acc[2]); o.w = f2bu(acc[3]);
      *(ushort4*)&h[(long long)node * 256 + mf * 16 + ch_base] = o;
    }
  }
  if (lane < 16 && node < NN) {
    #pragma unroll
    for (int hd = 0; hd < 8; ++hd) {
      a_s[node * 8 + hd] = sA[hd];
      a_d[node * 8 + hd] = sD[hd];
    }
  }
}

// Layer-1 softmax: per-node max/sum + write alpha[ET][8] bf16. Wave per node.
// Fast path (deg<=32, wave-uniform): cache v in 4 statically-indexed regs,
// skip the second random a_s sweep.
__global__ __launch_bounds__(256) void k_msalpha1(const int* __restrict__ rowptr,
                                                  const int* __restrict__ csr,
                                                  const float* __restrict__ a_s,
                                                  const float* __restrict__ a_d,
                                                  unsigned short* __restrict__ alph) {
  const int node = blockIdx.x * 4 + (threadIdx.x >> 6);
  const int lane = threadIdx.x & 63;
  const int beg = rowptr[node], end = rowptr[node + 1];
  const int hd = lane & 7;
  const int eg = lane >> 3;
  const float adv = a_d[node * 8 + hd];
  float mx = -FNEG, sm = 0.f;
  if (end - beg <= 32) {
    float vc0 = 0.f, vc1 = 0.f, vc2 = 0.f, vc3 = 0.f;
    #pragma unroll
    for (int k = 0; k < 4; ++k) {
      int i = beg + eg + k * 8;
      if (i < end) {
        float v = lrelu(a_s[csr[i] * 8 + hd] + adv);
        if (k == 0) vc0 = v; else if (k == 1) vc1 = v;
        else if (k == 2) vc2 = v; else vc3 = v;
        float nm = fmaxf(mx, v);
        sm = sm * __expf(mx - nm) + __expf(v - nm);
        mx = nm;
      }
    }
    #pragma unroll
    for (int off = 8; off < 64; off <<= 1) {
      float mo = __shfl_xor(mx, off);
      float so = __shfl_xor(sm, off);
      float nm = fmaxf(mx, mo);
      sm = sm * __expf(mx - nm) + so * __expf(mo - nm);
      mx = nm;
    }
    float rden = 1.0f / sm;
    #pragma unroll
    for (int k = 0; k < 4; ++k) {
      int i = beg + eg + k * 8;
      if (i < end) {
        float v = (k == 0) ? vc0 : (k == 1) ? vc1 : (k == 2) ? vc2 : vc3;
        alph[i * 8 + hd] = f2bu(__expf(v - mx) * rden);
      }
    }
  } else {
    for (int i = beg + eg; i < end; i += 8) {
      int s = csr[i];
      float v = lrelu(a_s[s * 8 + hd] + adv);
      float nm = fmaxf(mx, v);
      sm = sm * __expf(mx - nm) + __expf(v - nm);
      mx = nm;
    }
    #pragma unroll
    for (int off = 8; off < 64; off <<= 1) {
      float mo = __shfl_xor(mx, off);
      float so = __shfl_xor(sm, off);
      float nm = fmaxf(mx, mo);
      sm = sm * __expf(mx - nm) + so * __expf(mo - nm);
      mx = nm;
    }
    float rden = 1.0f / sm;
    for (int i = beg + eg; i < end; i += 8) {
      int s = csr[i];
      float v = lrelu(a_s[s * 8 + hd] + adv);
      alph[i * 8 + hd] = f2bu(__expf(v - mx) * rden);
    }
  }
}

// Layer-1 gather+bias+ELU fused with gemm2 (+layer-2 a_s/a_d epilogue).
// 1024 threads = 16 waves = 16 nodes/block. Wave w gathers node n0+w into
// registers (4-deep MLP), ELU -> LDS [16][256] bf16; barrier; wave 0 runs
// gemm2's 2mf x 8kk MFMAs + attention dots -> h2b, aS, aD.
__global__ __launch_bounds__(1024) void k_gather1f(const int* __restrict__ rowptr,
                                                   const int* __restrict__ csr,
                                                   const unsigned short* __restrict__ alph,
                                                   const unsigned short* __restrict__ h,
                                                   const float* __restrict__ b,
                                                   const bf16x8* __restrict__ W2f,
                                                   const float* __restrict__ as2,
                                                   const float* __restrict__ ad2,
                                                   unsigned short* __restrict__ h2,
                                                   float* __restrict__ a_s,
                                                   float* __restrict__ a_d) {
  __shared__ __align__(16) unsigned short xs[16 * 256];
  const int tid = threadIdx.x;
  const int w = tid >> 6, lane = tid & 63;
  const int n0 = blockIdx.x * 16;
  const int node = n0 + w;
  const int beg = rowptr[node], end = rowptr[node + 1];
  const int hd2 = lane >> 3;
  float4 acc = {0.f, 0.f, 0.f, 0.f};
  int i = beg;
  for (; i + 4 <= end; i += 4) {
    int s0 = csr[i], s1 = csr[i + 1], s2 = csr[i + 2], s3 = csr[i + 3];
    float a0 = b2f(alph[(i + 0) * 8 + hd2]);
    float a1 = b2f(alph[(i + 1) * 8 + hd2]);
    float a2 = b2f(alph[(i + 2) * 8 + hd2]);
    float a3 = b2f(alph[(i + 3) * 8 + hd2]);
    ushort4 h0 = *(const ushort4*)(h + (long long)s0 * 256 + lane * 4);
    ushort4 h1 = *(const ushort4*)(h + (long long)s1 * 256 + lane * 4);
    ushort4 h2v = *(const ushort4*)(h + (long long)s2 * 256 + lane * 4);
    ushort4 h3v = *(const ushort4*)(h + (long long)s3 * 256 + lane * 4);
    acc.x += a0 * b2f(h0.x) + a1 * b2f(h1.x) + a2 * b2f(h2v.x) + a3 * b2f(h3v.x);
    acc.y += a0 * b2f(h0.y) + a1 * b2f(h1.y) + a2 * b2f(h2v.y) + a3 * b2f(h3v.y);
    acc.z += a0 * b2f(h0.z) + a1 * b2f(h1.z) + a2 * b2f(h2v.z) + a3 * b2f(h3v.z);
    acc.w += a0 * b2f(h0.w) + a1 * b2f(h1.w) + a2 * b2f(h2v.w) + a3 * b2f(h3v.w);
  }
  for (; i < end; ++i) {
    int s0 = csr[i];
    float a0 = b2f(alph[i * 8 + hd2]);
    ushort4 h0 = *(const ushort4*)(h + (long long)s0 * 256 + lane * 4);
    acc.x += a0 * b2f(h0.x);
    acc.y += a0 * b2f(h0.y);
    acc.z += a0 * b2f(h0.z);
    acc.w += a0 * b2f(h0.w);
  }
  float4 bv = *(const float4*)(b + lane * 4);
  acc.x += bv.x; acc.y += bv.y; acc.z += bv.z; acc.w += bv.w;
  acc.x = acc.x > 0.f ? acc.x : expm1f(acc.x);
  acc.y = acc.y > 0.f ? acc.y : expm1f(acc.y);
  acc.z = acc.z > 0.f ? acc.z : expm1f(acc.z);
  acc.w = acc.w > 0.f ? acc.w : expm1f(acc.w);
  {
    ushort4 o;
    o.x = f2bu(acc.x); o.y = f2bu(acc.y); o.z = f2bu(acc.z); o.w = f2bu(acc.w);
    *(ushort4*)&xs[w * 256 + lane * 4] = o;
  }
  __syncthreads();
  if (w == 0) {     // gemm2 phase: 16-node tile @ K=256 -> 32 ch + a_s/a_d
    const int nloc = lane & 15;
    const int node2 = n0 + nloc;
    const int ch_base = (lane >> 4) * 4;
    float sA = 0.f, sD = 0.f;
    #pragma unroll
    for (int mf = 0; mf < 2; ++mf) {
      f32x4 c2 = {0.f, 0.f, 0.f, 0.f};
      #pragma unroll
      for (int kk = 0; kk < 8; ++kk) {
        bf16x8 bfr = *(const bf16x8*)&xs[nloc * 256 + kk * 32 + (lane >> 4) * 8];
        c2 = __builtin_amdgcn_mfma_f32_16x16x32_bf16(W2f[(mf * 8 + kk) * 64 + lane],
                                                     bfr, c2, 0, 0, 0);
      }
      float4 av = *(const float4*)(as2 + mf * 16 + ch_base);
      float4 dv = *(const float4*)(ad2 + mf * 16 + ch_base);
      float ps = c2[0] * av.x + c2[1] * av.y + c2[2] * av.z + c2[3] * av.w;
      float pd = c2[0] * dv.x + c2[1] * dv.y + c2[2] * dv.z + c2[3] * dv.w;
      ps += __shfl_xor(ps, 16); ps += __shfl_xor(ps, 32);
      pd += __shfl_xor(pd, 16); pd += __shfl_xor(pd, 32);
      sA += ps; sD += pd;
      ushort4 o;
      o.x = f2bu(c2[0]); o.y = f2bu(c2[1]); o.z = f2bu(c2[2]); o.w = f2bu(c2[3]);
      *(ushort4*)&h2[(long long)node2 * 32 + mf * 16 + ch_base] = o;
    }
    if (lane < 16) { a_s[node2] = sA; a_d[node2] = sD; }
  }
}

// H=1 softmax: max/sum + write alpha[ET] bf16. Half-wave per node (layers 2&3).
__global__ __launch_bounds__(256) void k_msalpha2(const int* __restrict__ rowptr,
                                                  const int* __restrict__ csr,
                                                  const float* __restrict__ a_s,
                                                  const float* __restrict__ a_d,
                                                  unsigned short* __restrict__ alph) {
  const int node = blockIdx.x * 8 + (threadIdx.x >> 5);
  const int lane = threadIdx.x & 31;
  const int beg = rowptr[node], end = rowptr[node + 1];
  const float adv = a_d[node];
  float mx = -FNEG, sm = 0.f;
  for (int i = beg + lane; i < end; i += 32) {
    float v = lrelu(a_s[csr[i]] + adv);
    float nm = fmaxf(mx, v);
    sm = sm * __expf(mx - nm) + __expf(v - nm);
    mx = nm;
  }
  #pragma unroll
  for (int off = 1; off < 32; off <<= 1) {
    float mo = __shfl_xor(mx, off, 32);
    float so = __shfl_xor(sm, off, 32);
    float nm = fmaxf(mx, mo);
    sm = sm * __expf(mx - nm) + so * __expf(mo - nm);
    mx = nm;
  }
  float rden = 1.0f / sm;
  for (int i = beg + lane; i < end; i += 32) {
    float v = lrelu(a_s[csr[i]] + adv);
    alph[i] = f2bu(__expf(v - mx) * rden);
  }
}

// Layer-2 gather+bias+ELU fused with gemm3 (+layer-3 a_s/a_d epilogue).
// 512 threads = 16 half-waves = 16 nodes/block. Half-wave hw gathers node
// n0+hw (C=32, 4-deep MLP) -> LDS [16][32] bf16; barrier; wave 0 runs
// gemm3's 3 MFMAs + attention dots -> h3b, aS, aD.
__global__ __launch_bounds__(512) void k_gather2f(const int* __restrict__ rowptr,
                                                  const int* __restrict__ csr,
                                                  const unsigned short* __restrict__ alph,
                                                  const unsigned short* __restrict__ h,
                                                  const float* __restrict__ b,
                                                  const bf16x8* __restrict__ W3f,
                                                  const float* __restrict__ as3,
                                                  const float* __restrict__ ad3,
                                                  unsigned short* __restrict__ h3,
                                                  float* __restrict__ a_s,
                                                  float* __restrict__ a_d) {
  __shared__ __align__(16) unsigned short xs[16 * 32];
  const int tid = threadIdx.x;
  const int hw = tid >> 5, lane32 = tid & 31;
  const int n0 = blockIdx.x * 16;
  const int node = n0 + hw;
  const int beg = rowptr[node], end = rowptr[node + 1];
  float acc = 0.f;
  int i = beg;
  for (; i + 4 <= end; i += 4) {
    int s0 = csr[i], s1 = csr[i + 1], s2 = csr[i + 2], s3 = csr[i + 3];
    float a0 = b2f(alph[i]), a1 = b2f(alph[i + 1]);
    float a2 = b2f(alph[i + 2]), a3 = b2f(alph[i + 3]);
    unsigned short v0 = h[(long long)s0 * 32 + lane32];
    unsigned short v1 = h[(long long)s1 * 32 + lane32];
    unsigned short v2 = h[(long long)s2 * 32 + lane32];
    unsigned short v3 = h[(long long)s3 * 32 + lane32];
    acc += a0 * b2f(v0) + a1 * b2f(v1) + a2 * b2f(v2) + a3 * b2f(v3);
  }
  for (; i < end; ++i) {
    acc += b2f(alph[i]) * b2f(h[(long long)csr[i] * 32 + lane32]);
  }
  acc += b[lane32];
  acc = acc > 0.f ? acc : expm1f(acc);
  xs[hw * 32 + lane32] = f2bu(acc);
  __syncthreads();
  if (tid < 64) {   // gemm3 phase: 16-node tile @ K=32 -> 40 ch + a_s/a_d
    const int lane = tid;
    const int nloc = lane & 15;
    const int node3 = n0 + nloc;
    const int ch_base = (lane >> 4) * 4;
    bf16x8 bfr = *(const bf16x8*)&xs[nloc * 32 + (lane >> 4) * 8];
    float sA = 0.f, sD = 0.f;
    #pragma unroll
    for (int mf = 0; mf < 3; ++mf) {
      f32x4 c3 = {0.f, 0.f, 0.f, 0.f};
      c3 = __builtin_amdgcn_mfma_f32_16x16x32_bf16(W3f[mf * 64 + lane], bfr, c3, 0, 0, 0);
      int ch0 = mf * 16 + ch_base;
      float4 av = {0.f, 0.f, 0.f, 0.f}, dv = {0.f, 0.f, 0.f, 0.f};
      if (ch0 < 40) {
        av = *(const float4*)(as3 + ch0);
        dv = *(const float4*)(ad3 + ch0);
      }
      float ps = c3[0] * av.x + c3[1] * av.y + c3[2] * av.z + c3[3] * av.w;
      float pd = c3[0] * dv.x + c3[1] * dv.y + c3[2] * dv.z + c3[3] * dv.w;
      ps += __shfl_xor(ps, 16); ps += __shfl_xor(ps, 32);
      pd += __shfl_xor(pd, 16); pd += __shfl_xor(pd, 32);
      sA += ps; sD += pd;
      if (ch0 < 40) {
        ushort4 o;
        o.x = f2bu(c3[0]); o.y = f2bu(c3[1]); o.z = f2bu(c3[2]); o.w = f2bu(c3[3]);
        *(ushort4*)&h3[(long long)node3 * 40 + ch0] = o;
      }
    }
    if (lane < 16) { a_s[node3] = sA; a_d[node3] = sD; }
  }
}

// Layer-3 pure gather + bias + log_softmax -> f32 out. Wave per node, 4-deep.
__global__ __launch_bounds__(256) void k_gather3(const int* __restrict__ rowptr,
                                                 const int* __restrict__ csr,
                                                 const unsigned short* __restrict__ alph,
                                                 const unsigned short* __restrict__ h,
                                                 const float* __restrict__ b,
                                                 float* __restrict__ out) {
  const int node = blockIdx.x * 4 + (threadIdx.x >> 6);
  const int lane = threadIdx.x & 63;
  const int beg = rowptr[node], end = rowptr[node + 1];
  float acc = 0.f;
  int i = beg;
  for (; i + 4 <= end; i += 4) {
    int s0 = csr[i], s1 = csr[i + 1], s2 = csr[i + 2], s3 = csr[i + 3];
    float a0 = b2f(alph[i]), a1 = b2f(alph[i + 1]);
    float a2 = b2f(alph[i + 2]), a3 = b2f(alph[i + 3]);
    if (lane < 40) {
      unsigned short v0 = h[(long long)s0 * 40 + lane];
      unsigned short v1 = h[(long long)s1 * 40 + lane];
      unsigned short v2 = h[(long long)s2 * 40 + lane];
      unsigned short v3 = h[(long long)s3 * 40 + lane];
      acc += a0 * b2f(v0) + a1 * b2f(v1) + a2 * b2f(v2) + a3 * b2f(v3);
    }
  }
  for (; i < end; ++i) {
    if (lane < 40) acc += b2f(alph[i]) * b2f(h[(long long)csr[i] * 40 + lane]);
  }
  float v = (lane < 40) ? acc + b[lane] : -FNEG;
  float vmax = v;
  #pragma unroll
  for (int off = 1; off < 64; off <<= 1) vmax = fmaxf(vmax, __shfl_xor(vmax, off));
  float ex = (lane < 40) ? __expf(v - vmax) : 0.f;
  float es = ex;
  #pragma unroll
  for (int off = 1; off < 64; off <<= 1) es += __shfl_xor(es, off);
  float lse = vmax + __logf(es);
  if (lane < 40) out[(long long)node * 40 + lane] = v - lse;
}

extern "C" void kernel_launch(void* const* d_in, const int* in_sizes, int n_in,
                              void* d_out, int out_size, void* d_ws, size_t ws_size,
                              hipStream_t stream) {
  const float* x   = (const float*)d_in[0];
  const int*   eix = (const int*)d_in[1];
  const float* W1  = (const float*)d_in[2];
  const float* as1 = (const float*)d_in[3];
  const float* ad1 = (const float*)d_in[4];
  const float* b1  = (const float*)d_in[5];
  const float* W2  = (const float*)d_in[6];
  const float* as2 = (const float*)d_in[7];
  const float* ad2 = (const float*)d_in[8];
  const float* b2  = (const float*)d_in[9];
  const float* W3  = (const float*)d_in[10];
  const float* as3 = (const float*)d_in[11];
  const float* ad3 = (const float*)d_in[12];
  const float* b3  = (const float*)d_in[13];
  float* out = (float*)d_out;

  if (ws_size < WS_NEED) {
    k_sentinel<<<(out_size + 255) / 256, 256, 0, stream>>>(out, out_size);
    return;
  }

  char* ws = (char*)d_ws;
  int*    src    = (int*)(ws + SRC_OFF);
  int*    dst    = (int*)(ws + DST_OFF);
  int*    rowptr = (int*)(ws + RP_OFF);
  int*    cnt    = (int*)(ws + CNT_OFF);
  int*    csr    = (int*)(ws + CSR_OFF);
  unsigned short* W1f = (unsigned short*)(ws + W1F_OFF);
  unsigned short* W2f = (unsigned short*)(ws + W2F_OFF);
  unsigned short* W3f = (unsigned short*)(ws + W3F_OFF);
  int*    bsum   = (int*)(ws + SC_OFF);
  unsigned short* h1b  = (unsigned short*)(ws + H_OFF);
  unsigned short* h2b  = (unsigned short*)(ws + H2B_OFF);
  unsigned short* h3b  = (unsigned short*)(ws + H3B_OFF);
  unsigned short* alph = (unsigned short*)(ws + ALPH_OFF);
  float*  aS     = (float*)(ws + AS_OFF);
  float*  aD     = (float*)(ws + AD_OFF);

  // ---- CSR build + weight prep ----
  k_prep_w<<<21, 256, 0, stream>>>(W1, W2, W3, W1f, W2f, W3f);
  hipMemsetAsync(ws + CNT_OFF, 0, 400000, stream);
  k_prep_edges<<<(ET + 255) / 256, 256, 0, stream>>>(eix, src, dst, cnt);
  k_scan_a<<<NBSC, 1024, 0, stream>>>(cnt, rowptr, bsum);
  k_scan_b<<<1, 128, 0, stream>>>(bsum);
  k_scan_c<<<NBSC, 1024, 0, stream>>>(rowptr, bsum);
  hipMemsetAsync(ws + CNT_OFF, 0, 400000, stream);
  k_fill<<<(ET + 255) / 256, 256, 0, stream>>>(src, dst, rowptr, cnt, csr);

  // ---- layer 1: 128 -> 8x32 concat (gemm2 fused into gather) ----
  k_gemm1<<<(NN + 63) / 64, 256, 0, stream>>>(x, (const bf16x8*)W1f, as1, ad1,
                                              h1b, aS, aD);  // aS/aD over src/dst (dead)
  k_msalpha1<<<NN / 4, 256, 0, stream>>>(rowptr, csr, aS, aD, alph);
  k_gather1f<<<NN / 16, 1024, 0, stream>>>(rowptr, csr, alph, h1b, b1,
                                           (const bf16x8*)W2f, as2, ad2,
                                           h2b, aS, aD);

  // ---- layer 2: 256 -> 32 (gemm3 fused into gather) ----
  k_msalpha2<<<NN / 8, 256, 0, stream>>>(rowptr, csr, aS, aD, alph);
  k_gather2f<<<NN / 16, 512, 0, stream>>>(rowptr, csr, alph, h2b, b2,
                                          (const bf16x8*)W3f, as3, ad3,
                                          h3b, aS, aD);

  // ---- layer 3: 32 -> 40 ----
  k_msalpha2<<<NN / 8, 256, 0, stream>>>(rowptr, csr, aS, aD, alph);
  k_gather3<<<NN / 4, 256, 0, stream>>>(rowptr, csr, alph, h3b, b3, out);
}

// Round 10
// 508.629 us; speedup vs baseline: 1.3331x; 1.0583x over previous
//
#include <hip/hip_runtime.h>

#define NN 100000
#define NE 1600000
#define ET 1700000        // NE + NN self-loops
#define NEG 0.2f
#define FNEG 3.4e38f
#define NBSC 98           // scan blocks: ceil(NN/1024)
#define GEMM1_NB 1563     // ceil(NN/64)
#define PE_NB 6641        // ceil(ET/256)
#define FATA_NB 8305      // 5 * 1661 covers 4:1 interleave of PE_NB:GEMM1_NB

// ---------------- workspace layout (bytes) ----------------
#define SRC_OFF   0ULL
#define DST_OFF   6800000ULL
#define RP_OFF    13600000ULL         // rowptr (NN+1)*4
#define CNT_OFF   14000128ULL         // deg / fill cursor NN*4
#define CSR_OFF   14400128ULL         // ET*4
#define W1F_OFF   21200128ULL         // 65536  (16mf x 4kk x 64lane x 8 bf16)
#define W2F_OFF   21265664ULL         // 16384
#define W3F_OFF   21282048ULL         // 3072
#define SC_OFF    21285120ULL         // 1024 (block sums)
#define H_OFF     21286144ULL         // h1b 51.2MB (bf16)
#define H2B_OFF   72486144ULL         // h2b 6.4MB
#define H3B_OFF   88486144ULL         // h3b 8MB
#define ALPH_OFF  123686144ULL        // alpha: ET*8*2 = 27.2MB (l1); ET*2 (l2,l3)
#define ASN_OFF   150886144ULL        // a_s (de-aliased from src): 3.2MB
#define ADN_OFF   154086144ULL        // a_d: 3.2MB
#define WS_NEED   157286144ULL

typedef short bf16x8 __attribute__((ext_vector_type(8)));
typedef float f32x4 __attribute__((ext_vector_type(4)));

__device__ __forceinline__ float lrelu(float x) { return x > 0.f ? x : NEG * x; }
__device__ __forceinline__ float b2f(unsigned short u) {
  return __uint_as_float(((unsigned)u) << 16);
}
__device__ __forceinline__ unsigned short f2bu(float f) {   // RNE f32->bf16
  unsigned u = __float_as_uint(f);
  return (unsigned short)((u + 0x7FFFu + ((u >> 16) & 1u)) >> 16);
}

__global__ __launch_bounds__(256) void k_sentinel(float* out, int n) {
  int i = blockIdx.x * 256 + threadIdx.x;
  if (i < n) out[i] = 12345.0f;
}

// Pre-arrange W1/W2/W3 (f32) into MFMA A-fragment order as bf16.
// A-frag convention: row(channel) = lane&15, k = (lane>>4)*8 + j.
__global__ __launch_bounds__(256) void k_prep_w(const float* __restrict__ W1,
                                                const float* __restrict__ W2,
                                                const float* __restrict__ W3,
                                                unsigned short* __restrict__ W1f,
                                                unsigned short* __restrict__ W2f,
                                                unsigned short* __restrict__ W3f) {
  int idx = blockIdx.x * 256 + threadIdx.x;
  if (idx < 4096) {                       // W1: 16 mf x 4 kk
    int fg = idx >> 6, lane = idx & 63;
    int mf = fg >> 2, kk = fg & 3;
    int c = mf * 16 + (lane & 15), k0 = kk * 32 + (lane >> 4) * 8;
    unsigned short* o = W1f + idx * 8;
    #pragma unroll
    for (int j = 0; j < 8; ++j) o[j] = f2bu(W1[(k0 + j) * 256 + c]);
  } else if (idx < 5120) {                // W2: 2 mf x 8 kk
    int t = idx - 4096;
    int fg = t >> 6, lane = t & 63;
    int mf = fg >> 3, kk = fg & 7;
    int c = mf * 16 + (lane & 15), k0 = kk * 32 + (lane >> 4) * 8;
    unsigned short* o = W2f + t * 8;
    #pragma unroll
    for (int j = 0; j < 8; ++j) o[j] = f2bu(W2[(k0 + j) * 32 + c]);
  } else if (idx < 5312) {                // W3: 3 mf x 1 kk (pad ch>=40 with 0)
    int t = idx - 5120;
    int mf = t >> 6, lane = t & 63;
    int c = mf * 16 + (lane & 15), k0 = (lane >> 4) * 8;
    unsigned short* o = W3f + t * 8;
    #pragma unroll
    for (int j = 0; j < 8; ++j) o[j] = (c < 40) ? f2bu(W3[(k0 + j) * 40 + c]) : 0;
  }
}

// Fat kernel A: prep_edges (+deg count) interleaved 4:1 with gemm1
// (h1b = x@W1 + fused a_s/a_d epilogue). Independent workloads overlap.
__global__ __launch_bounds__(256) void k_fatA(const int* __restrict__ raw,
                                              int* __restrict__ src,
                                              int* __restrict__ dst,
                                              int* __restrict__ deg,
                                              const float* __restrict__ x,
                                              const bf16x8* __restrict__ W1f,
                                              const float* __restrict__ as1,
                                              const float* __restrict__ ad1,
                                              unsigned short* __restrict__ h,
                                              float* __restrict__ a_s,
                                              float* __restrict__ a_d) {
  __shared__ __align__(16) unsigned short xs[64 * 128];
  __shared__ float asL[256], adL[256];
  const int bid = blockIdx.x;
  const int grp = bid / 5, rem = bid - grp * 5;
  const int tid = threadIdx.x;

  if (rem != 4) {                               // ---- prep_edges ----
    int pe = grp * 4 + rem;
    if (pe >= PE_NB) return;
    bool is64 = true;
    #pragma unroll
    for (int i = 1; i < 32; i += 2) is64 = is64 && (raw[i] == 0);
    long long e = (long long)pe * 256 + tid;
    if (e >= ET) return;
    int s, d;
    if (e < NE) {
      if (is64) {
        const long long* r = (const long long*)raw;
        s = (int)r[e];
        d = (int)r[NE + e];
      } else {
        s = raw[e];
        d = raw[NE + e];
      }
    } else {
      s = d = (int)(e - NE);
    }
    src[e] = s;
    dst[e] = d;
    atomicAdd(&deg[d], 1);
    return;
  }

  // ---- gemm1 ----
  if (grp >= GEMM1_NB) return;
  const int n0 = grp * 64;
  asL[tid] = as1[tid];
  adL[tid] = ad1[tid];
  for (int j = tid; j < 2048; j += 256) {       // stage x -> bf16 LDS
    int r = j >> 5;
    int c4 = (j & 31) << 2;
    long long row = n0 + r; if (row >= NN) row = NN - 1;
    float4 v = *(const float4*)(x + row * 128 + c4);
    unsigned short* p = &xs[r * 128 + c4];
    p[0] = f2bu(v.x); p[1] = f2bu(v.y); p[2] = f2bu(v.z); p[3] = f2bu(v.w);
  }
  __syncthreads();
  const int w = tid >> 6, lane = tid & 63;
  const int nloc = w * 16 + (lane & 15);
  const int node = n0 + nloc;
  bf16x8 bfr[4];
  #pragma unroll
  for (int kk = 0; kk < 4; ++kk)
    bfr[kk] = *(const bf16x8*)&xs[nloc * 128 + kk * 32 + (lane >> 4) * 8];
  const int ch_base = (lane >> 4) * 4;
  float sA[8] = {}, sD[8] = {};
  #pragma unroll
  for (int mf = 0; mf < 16; ++mf) {
    f32x4 acc = {0.f, 0.f, 0.f, 0.f};
    #pragma unroll
    for (int kk = 0; kk < 4; ++kk) {
      bf16x8 af = W1f[(mf * 4 + kk) * 64 + lane];
      acc = __builtin_amdgcn_mfma_f32_16x16x32_bf16(af, bfr[kk], acc, 0, 0, 0);
    }
    const float* av = &asL[mf * 16 + ch_base];
    const float* dv = &adL[mf * 16 + ch_base];
    float ps = acc[0] * av[0] + acc[1] * av[1] + acc[2] * av[2] + acc[3] * av[3];
    float pd = acc[0] * dv[0] + acc[1] * dv[1] + acc[2] * dv[2] + acc[3] * dv[3];
    ps += __shfl_xor(ps, 16); ps += __shfl_xor(ps, 32);
    pd += __shfl_xor(pd, 16); pd += __shfl_xor(pd, 32);
    sA[mf >> 1] += ps; sD[mf >> 1] += pd;
    if (node < NN) {
      ushort4 o;
      o.x = f2bu(acc[0]); o.y = f2bu(acc[1]); o.z = f2bu(acc[2]); o.w = f2bu(acc[3]);
      *(ushort4*)&h[(unsigned)(node * 256 + mf * 16 + ch_base)] = o;
    }
  }
  if (lane < 16 && node < NN) {
    #pragma unroll
    for (int hd = 0; hd < 8; ++hd) {
      a_s[node * 8 + hd] = sA[hd];
      a_d[node * 8 + hd] = sD[hd];
    }
  }
}

// Block-level inclusive scan; rowptr[i+1] = block-local inclusive, bsum[b]=total.
__global__ __launch_bounds__(1024) void k_scan_a(const int* __restrict__ deg,
                                                 int* __restrict__ rowptr,
                                                 int* __restrict__ bsum) {
  __shared__ int wsum[16];
  const int lane = threadIdx.x & 63, wid = threadIdx.x >> 6;
  int i = blockIdx.x * 1024 + threadIdx.x;
  int x = (i < NN) ? deg[i] : 0;
  int inc = x;
  #pragma unroll
  for (int off = 1; off < 64; off <<= 1) {
    int t = __shfl_up(inc, off);
    if (lane >= off) inc += t;
  }
  if (lane == 63) wsum[wid] = inc;
  __syncthreads();
  if (wid == 0) {
    int w = (lane < 16) ? wsum[lane] : 0;
    #pragma unroll
    for (int off = 1; off < 16; off <<= 1) {
      int t = __shfl_up(w, off);
      if (lane >= off) w += t;
    }
    if (lane < 16) wsum[lane] = w;
  }
  __syncthreads();
  int base = wid ? wsum[wid - 1] : 0;
  if (i < NN) rowptr[i + 1] = base + inc;
  if (threadIdx.x == 1023) bsum[blockIdx.x] = base + inc;
}

// Exclusive scan of NBSC block sums (in place).
__global__ __launch_bounds__(128) void k_scan_b(int* __restrict__ bsum) {
  __shared__ int w0tot;
  int tid = threadIdx.x;
  int v = (tid < NBSC) ? bsum[tid] : 0;
  int inc = v;
  #pragma unroll
  for (int off = 1; off < 64; off <<= 1) {
    int t = __shfl_up(inc, off);
    if ((tid & 63) >= off) inc += t;
  }
  if (tid == 63) w0tot = inc;
  __syncthreads();
  if (tid >= 64) inc += w0tot;
  if (tid < NBSC) bsum[tid] = inc - v;
}

// Adds block offsets AND zeroes cnt for the fill pass (saves a memset dispatch).
__global__ __launch_bounds__(1024) void k_scan_c(int* __restrict__ rowptr,
                                                 const int* __restrict__ bsum,
                                                 int* __restrict__ cnt) {
  int i = blockIdx.x * 1024 + threadIdx.x;
  if (i < NN) {
    rowptr[i + 1] += bsum[blockIdx.x];
    cnt[i] = 0;
  }
  if (i == 0) rowptr[0] = 0;
}

__global__ __launch_bounds__(256) void k_fill(const int* __restrict__ src,
                                              const int* __restrict__ dst,
                                              const int* __restrict__ rowptr,
                                              int* __restrict__ cnt,
                                              int* __restrict__ csr) {
  long long e = (long long)blockIdx.x * 256 + threadIdx.x;
  if (e >= ET) return;
  int d = dst[e];
  int p = atomicAdd(&cnt[d], 1);
  csr[rowptr[d] + p] = src[e];
}

// Layer-1 softmax: per-node max/sum + write alpha[ET][8] bf16. Wave per node.
// Fast path (deg<=32, wave-uniform): cache v in 4 statically-indexed regs.
__global__ __launch_bounds__(256) void k_msalpha1(const int* __restrict__ rowptr,
                                                  const int* __restrict__ csr,
                                                  const float* __restrict__ a_s,
                                                  const float* __restrict__ a_d,
                                                  unsigned short* __restrict__ alph) {
  const int node = blockIdx.x * 4 + (threadIdx.x >> 6);
  const int lane = threadIdx.x & 63;
  const int beg = __builtin_amdgcn_readfirstlane(rowptr[node]);
  const int end = __builtin_amdgcn_readfirstlane(rowptr[node + 1]);
  const int hd = lane & 7;
  const int eg = lane >> 3;
  const float adv = a_d[node * 8 + hd];
  float mx = -FNEG, sm = 0.f;
  if (end - beg <= 32) {
    float vc0 = 0.f, vc1 = 0.f, vc2 = 0.f, vc3 = 0.f;
    #pragma unroll
    for (int k = 0; k < 4; ++k) {
      int i = beg + eg + k * 8;
      if (i < end) {
        float v = lrelu(a_s[csr[i] * 8 + hd] + adv);
        if (k == 0) vc0 = v; else if (k == 1) vc1 = v;
        else if (k == 2) vc2 = v; else vc3 = v;
        float nm = fmaxf(mx, v);
        sm = sm * __expf(mx - nm) + __expf(v - nm);
        mx = nm;
      }
    }
    #pragma unroll
    for (int off = 8; off < 64; off <<= 1) {
      float mo = __shfl_xor(mx, off);
      float so = __shfl_xor(sm, off);
      float nm = fmaxf(mx, mo);
      sm = sm * __expf(mx - nm) + so * __expf(mo - nm);
      mx = nm;
    }
    float rden = 1.0f / sm;
    #pragma unroll
    for (int k = 0; k < 4; ++k) {
      int i = beg + eg + k * 8;
      if (i < end) {
        float v = (k == 0) ? vc0 : (k == 1) ? vc1 : (k == 2) ? vc2 : vc3;
        alph[i * 8 + hd] = f2bu(__expf(v - mx) * rden);
      }
    }
  } else {
    for (int i = beg + eg; i < end; i += 8) {
      int s = csr[i];
      float v = lrelu(a_s[s * 8 + hd] + adv);
      float nm = fmaxf(mx, v);
      sm = sm * __expf(mx - nm) + __expf(v - nm);
      mx = nm;
    }
    #pragma unroll
    for (int off = 8; off < 64; off <<= 1) {
      float mo = __shfl_xor(mx, off);
      float so = __shfl_xor(sm, off);
      float nm = fmaxf(mx, mo);
      sm = sm * __expf(mx - nm) + so * __expf(mo - nm);
      mx = nm;
    }
    float rden = 1.0f / sm;
    for (int i = beg + eg; i < end; i += 8) {
      int s = csr[i];
      float v = lrelu(a_s[s * 8 + hd] + adv);
      alph[i * 8 + hd] = f2bu(__expf(v - mx) * rden);
    }
  }
}

// Layer-1 gather+bias+ELU fused with gemm2 (+layer-2 a_s/a_d epilogue).
// 1024 threads = 16 waves = 16 nodes/block. Scalarized csr/rowptr (wave-
// uniform), 32-bit h indexing (no 64-bit address muls).
__global__ __launch_bounds__(1024) void k_gather1f(const int* __restrict__ rowptr,
                                                   const int* __restrict__ csr,
                                                   const unsigned short* __restrict__ alph,
                                                   const unsigned short* __restrict__ h,
                                                   const float* __restrict__ b,
                                                   const bf16x8* __restrict__ W2f,
                                                   const float* __restrict__ as2,
                                                   const float* __restrict__ ad2,
                                                   unsigned short* __restrict__ h2,
                                                   float* __restrict__ a_s,
                                                   float* __restrict__ a_d) {
  __shared__ __align__(16) unsigned short xs[16 * 256];
  const int tid = threadIdx.x;
  const int w = tid >> 6, lane = tid & 63;
  const int n0 = blockIdx.x * 16;
  const int node = n0 + w;
  const int beg = __builtin_amdgcn_readfirstlane(rowptr[node]);
  const int end = __builtin_amdgcn_readfirstlane(rowptr[node + 1]);
  const int hd2 = lane >> 3;
  const unsigned l4 = lane * 4;
  float4 acc = {0.f, 0.f, 0.f, 0.f};
  int i = beg;
  for (; i + 4 <= end; i += 4) {
    int s0 = __builtin_amdgcn_readfirstlane(csr[i]);
    int s1 = __builtin_amdgcn_readfirstlane(csr[i + 1]);
    int s2 = __builtin_amdgcn_readfirstlane(csr[i + 2]);
    int s3 = __builtin_amdgcn_readfirstlane(csr[i + 3]);
    float a0 = b2f(alph[(i + 0) * 8 + hd2]);
    float a1 = b2f(alph[(i + 1) * 8 + hd2]);
    float a2 = b2f(alph[(i + 2) * 8 + hd2]);
    float a3 = b2f(alph[(i + 3) * 8 + hd2]);
    ushort4 h0 = *(const ushort4*)(h + ((unsigned)(s0 << 8) + l4));
    ushort4 h1 = *(const ushort4*)(h + ((unsigned)(s1 << 8) + l4));
    ushort4 h2v = *(const ushort4*)(h + ((unsigned)(s2 << 8) + l4));
    ushort4 h3v = *(const ushort4*)(h + ((unsigned)(s3 << 8) + l4));
    acc.x += a0 * b2f(h0.x) + a1 * b2f(h1.x) + a2 * b2f(h2v.x) + a3 * b2f(h3v.x);
    acc.y += a0 * b2f(h0.y) + a1 * b2f(h1.y) + a2 * b2f(h2v.y) + a3 * b2f(h3v.y);
    acc.z += a0 * b2f(h0.z) + a1 * b2f(h1.z) + a2 * b2f(h2v.z) + a3 * b2f(h3v.z);
    acc.w += a0 * b2f(h0.w) + a1 * b2f(h1.w) + a2 * b2f(h2v.w) + a3 * b2f(h3v.w);
  }
  for (; i < end; ++i) {
    int s0 = __builtin_amdgcn_readfirstlane(csr[i]);
    float a0 = b2f(alph[i * 8 + hd2]);
    ushort4 h0 = *(const ushort4*)(h + ((unsigned)(s0 << 8) + l4));
    acc.x += a0 * b2f(h0.x);
    acc.y += a0 * b2f(h0.y);
    acc.z += a0 * b2f(h0.z);
    acc.w += a0 * b2f(h0.w);
  }
  float4 bv = *(const float4*)(b + l4);
  acc.x += bv.x; acc.y += bv.y; acc.z += bv.z; acc.w += bv.w;
  acc.x = acc.x > 0.f ? acc.x : expm1f(acc.x);
  acc.y = acc.y > 0.f ? acc.y : expm1f(acc.y);
  acc.z = acc.z > 0.f ? acc.z : expm1f(acc.z);
  acc.w = acc.w > 0.f ? acc.w : expm1f(acc.w);
  {
    ushort4 o;
    o.x = f2bu(acc.x); o.y = f2bu(acc.y); o.z = f2bu(acc.z); o.w = f2bu(acc.w);
    *(ushort4*)&xs[w * 256 + l4] = o;
  }
  __syncthreads();
  if (w == 0) {     // gemm2 phase: 16-node tile @ K=256 -> 32 ch + a_s/a_d
    const int nloc = lane & 15;
    const int node2 = n0 + nloc;
    const int ch_base = (lane >> 4) * 4;
    float sA = 0.f, sD = 0.f;
    #pragma unroll
    for (int mf = 0; mf < 2; ++mf) {
      f32x4 c2 = {0.f, 0.f, 0.f, 0.f};
      #pragma unroll
      for (int kk = 0; kk < 8; ++kk) {
        bf16x8 bfr = *(const bf16x8*)&xs[nloc * 256 + kk * 32 + (lane >> 4) * 8];
        c2 = __builtin_amdgcn_mfma_f32_16x16x32_bf16(W2f[(mf * 8 + kk) * 64 + lane],
                                                     bfr, c2, 0, 0, 0);
      }
      float4 av = *(const float4*)(as2 + mf * 16 + ch_base);
      float4 dv = *(const float4*)(ad2 + mf * 16 + ch_base);
      float ps = c2[0] * av.x + c2[1] * av.y + c2[2] * av.z + c2[3] * av.w;
      float pd = c2[0] * dv.x + c2[1] * dv.y + c2[2] * dv.z + c2[3] * dv.w;
      ps += __shfl_xor(ps, 16); ps += __shfl_xor(ps, 32);
      pd += __shfl_xor(pd, 16); pd += __shfl_xor(pd, 32);
      sA += ps; sD += pd;
      ushort4 o;
      o.x = f2bu(c2[0]); o.y = f2bu(c2[1]); o.z = f2bu(c2[2]); o.w = f2bu(c2[3]);
      *(ushort4*)&h2[(unsigned)(node2 * 32 + mf * 16 + ch_base)] = o;
    }
    if (lane < 16) { a_s[node2] = sA; a_d[node2] = sD; }
  }
}

// H=1 softmax: max/sum + write alpha[ET] bf16. Half-wave per node (layers 2&3).
__global__ __launch_bounds__(256) void k_msalpha2(const int* __restrict__ rowptr,
                                                  const int* __restrict__ csr,
                                                  const float* __restrict__ a_s,
                                                  const float* __restrict__ a_d,
                                                  unsigned short* __restrict__ alph) {
  const int node = blockIdx.x * 8 + (threadIdx.x >> 5);
  const int lane = threadIdx.x & 31;
  const int beg = rowptr[node], end = rowptr[node + 1];
  const float adv = a_d[node];
  float mx = -FNEG, sm = 0.f;
  for (int i = beg + lane; i < end; i += 32) {
    float v = lrelu(a_s[csr[i]] + adv);
    float nm = fmaxf(mx, v);
    sm = sm * __expf(mx - nm) + __expf(v - nm);
    mx = nm;
  }
  #pragma unroll
  for (int off = 1; off < 32; off <<= 1) {
    float mo = __shfl_xor(mx, off, 32);
    float so = __shfl_xor(sm, off, 32);
    float nm = fmaxf(mx, mo);
    sm = sm * __expf(mx - nm) + so * __expf(mo - nm);
    mx = nm;
  }
  float rden = 1.0f / sm;
  for (int i = beg + lane; i < end; i += 32) {
    float v = lrelu(a_s[csr[i]] + adv);
    alph[i] = f2bu(__expf(v - mx) * rden);
  }
}

// Layer-2 gather+bias+ELU fused with gemm3 (+layer-3 a_s/a_d epilogue).
// 512 threads = 16 half-waves = 16 nodes/block (half-wave: keep vector idx).
__global__ __launch_bounds__(512) void k_gather2f(const int* __restrict__ rowptr,
                                                  const int* __restrict__ csr,
                                                  const unsigned short* __restrict__ alph,
                                                  const unsigned short* __restrict__ h,
                                                  const float* __restrict__ b,
                                                  const bf16x8* __restrict__ W3f,
                                                  const float* __restrict__ as3,
                                                  const float* __restrict__ ad3,
                                                  unsigned short* __restrict__ h3,
                                                  float* __restrict__ a_s,
                                                  float* __restrict__ a_d) {
  __shared__ __align__(16) unsigned short xs[16 * 32];
  const int tid = threadIdx.x;
  const int hw = tid >> 5, lane32 = tid & 31;
  const int n0 = blockIdx.x * 16;
  const int node = n0 + hw;
  const int beg = rowptr[node], end = rowptr[node + 1];
  float acc = 0.f;
  int i = beg;
  for (; i + 4 <= end; i += 4) {
    int s0 = csr[i], s1 = csr[i + 1], s2 = csr[i + 2], s3 = csr[i + 3];
    float a0 = b2f(alph[i]), a1 = b2f(alph[i + 1]);
    float a2 = b2f(alph[i + 2]), a3 = b2f(alph[i + 3]);
    unsigned short v0 = h[(unsigned)(s0 * 32 + lane32)];
    unsigned short v1 = h[(unsigned)(s1 * 32 + lane32)];
    unsigned short v2 = h[(unsigned)(s2 * 32 + lane32)];
    unsigned short v3 = h[(unsigned)(s3 * 32 + lane32)];
    acc += a0 * b2f(v0) + a1 * b2f(v1) + a2 * b2f(v2) + a3 * b2f(v3);
  }
  for (; i < end; ++i) {
    acc += b2f(alph[i]) * b2f(h[(unsigned)(csr[i] * 32 + lane32)]);
  }
  acc += b[lane32];
  acc = acc > 0.f ? acc : expm1f(acc);
  xs[hw * 32 + lane32] = f2bu(acc);
  __syncthreads();
  if (tid < 64) {   // gemm3 phase: 16-node tile @ K=32 -> 40 ch + a_s/a_d
    const int lane = tid;
    const int nloc = lane & 15;
    const int node3 = n0 + nloc;
    const int ch_base = (lane >> 4) * 4;
    bf16x8 bfr = *(const bf16x8*)&xs[nloc * 32 + (lane >> 4) * 8];
    float sA = 0.f, sD = 0.f;
    #pragma unroll
    for (int mf = 0; mf < 3; ++mf) {
      f32x4 c3 = {0.f, 0.f, 0.f, 0.f};
      c3 = __builtin_amdgcn_mfma_f32_16x16x32_bf16(W3f[mf * 64 + lane], bfr, c3, 0, 0, 0);
      int ch0 = mf * 16 + ch_base;
      float4 av = {0.f, 0.f, 0.f, 0.f}, dv = {0.f, 0.f, 0.f, 0.f};
      if (ch0 < 40) {
        av = *(const float4*)(as3 + ch0);
        dv = *(const float4*)(ad3 + ch0);
      }
      float ps = c3[0] * av.x + c3[1] * av.y + c3[2] * av.z + c3[3] * av.w;
      float pd = c3[0] * dv.x + c3[1] * dv.y + c3[2] * dv.z + c3[3] * dv.w;
      ps += __shfl_xor(ps, 16); ps += __shfl_xor(ps, 32);
      pd += __shfl_xor(pd, 16); pd += __shfl_xor(pd, 32);
      sA += ps; sD += pd;
      if (ch0 < 40) {
        ushort4 o;
        o.x = f2bu(c3[0]); o.y = f2bu(c3[1]); o.z = f2bu(c3[2]); o.w = f2bu(c3[3]);
        *(ushort4*)&h3[(unsigned)(node3 * 40 + ch0)] = o;
      }
    }
    if (lane < 16) { a_s[node3] = sA; a_d[node3] = sD; }
  }
}

// Layer-3 pure gather + bias + log_softmax -> f32 out. Wave per node,
// scalarized csr, 32-bit indexing, 4-deep MLP.
__global__ __launch_bounds__(256) void k_gather3(const int* __restrict__ rowptr,
                                                 const int* __restrict__ csr,
                                                 const unsigned short* __restrict__ alph,
                                                 const unsigned short* __restrict__ h,
                                                 const float* __restrict__ b,
                                                 float* __restrict__ out) {
  const int node = blockIdx.x * 4 + (threadIdx.x >> 6);
  const int lane = threadIdx.x & 63;
  const int beg = __builtin_amdgcn_readfirstlane(rowptr[node]);
  const int end = __builtin_amdgcn_readfirstlane(rowptr[node + 1]);
  float acc = 0.f;
  int i = beg;
  for (; i + 4 <= end; i += 4) {
    int s0 = __builtin_amdgcn_readfirstlane(csr[i]);
    int s1 = __builtin_amdgcn_readfirstlane(csr[i + 1]);
    int s2 = __builtin_amdgcn_readfirstlane(csr[i + 2]);
    int s3 = __builtin_amdgcn_readfirstlane(csr[i + 3]);
    float a0 = b2f(alph[i]), a1 = b2f(alph[i + 1]);
    float a2 = b2f(alph[i + 2]), a3 = b2f(alph[i + 3]);
    if (lane < 40) {
      unsigned short v0 = h[(unsigned)(s0 * 40 + lane)];
      unsigned short v1 = h[(unsigned)(s1 * 40 + lane)];
      unsigned short v2 = h[(unsigned)(s2 * 40 + lane)];
      unsigned short v3 = h[(unsigned)(s3 * 40 + lane)];
      acc += a0 * b2f(v0) + a1 * b2f(v1) + a2 * b2f(v2) + a3 * b2f(v3);
    }
  }
  for (; i < end; ++i) {
    int s0 = __builtin_amdgcn_readfirstlane(csr[i]);
    if (lane < 40) acc += b2f(alph[i]) * b2f(h[(unsigned)(s0 * 40 + lane)]);
  }
  float v = (lane < 40) ? acc + b[lane] : -FNEG;
  float vmax = v;
  #pragma unroll
  for (int off = 1; off < 64; off <<= 1) vmax = fmaxf(vmax, __shfl_xor(vmax, off));
  float ex = (lane < 40) ? __expf(v - vmax) : 0.f;
  float es = ex;
  #pragma unroll
  for (int off = 1; off < 64; off <<= 1) es += __shfl_xor(es, off);
  float lse = vmax + __logf(es);
  if (lane < 40) out[(long long)node * 40 + lane] = v - lse;
}

extern "C" void kernel_launch(void* const* d_in, const int* in_sizes, int n_in,
                              void* d_out, int out_size, void* d_ws, size_t ws_size,
                              hipStream_t stream) {
  const float* x   = (const float*)d_in[0];
  const int*   eix = (const int*)d_in[1];
  const float* W1  = (const float*)d_in[2];
  const float* as1 = (const float*)d_in[3];
  const float* ad1 = (const float*)d_in[4];
  const float* b1  = (const float*)d_in[5];
  const float* W2  = (const float*)d_in[6];
  const float* as2 = (const float*)d_in[7];
  const float* ad2 = (const float*)d_in[8];
  const float* b2  = (const float*)d_in[9];
  const float* W3  = (const float*)d_in[10];
  const float* as3 = (const float*)d_in[11];
  const float* ad3 = (const float*)d_in[12];
  const float* b3  = (const float*)d_in[13];
  float* out = (float*)d_out;

  if (ws_size < WS_NEED) {
    k_sentinel<<<(out_size + 255) / 256, 256, 0, stream>>>(out, out_size);
    return;
  }

  char* ws = (char*)d_ws;
  int*    src    = (int*)(ws + SRC_OFF);
  int*    dst    = (int*)(ws + DST_OFF);
  int*    rowptr = (int*)(ws + RP_OFF);
  int*    cnt    = (int*)(ws + CNT_OFF);
  int*    csr    = (int*)(ws + CSR_OFF);
  unsigned short* W1f = (unsigned short*)(ws + W1F_OFF);
  unsigned short* W2f = (unsigned short*)(ws + W2F_OFF);
  unsigned short* W3f = (unsigned short*)(ws + W3F_OFF);
  int*    bsum   = (int*)(ws + SC_OFF);
  unsigned short* h1b  = (unsigned short*)(ws + H_OFF);
  unsigned short* h2b  = (unsigned short*)(ws + H2B_OFF);
  unsigned short* h3b  = (unsigned short*)(ws + H3B_OFF);
  unsigned short* alph = (unsigned short*)(ws + ALPH_OFF);
  float*  aS     = (float*)(ws + ASN_OFF);
  float*  aD     = (float*)(ws + ADN_OFF);

  // ---- prep + CSR build (prep_edges overlapped with gemm1 in k_fatA) ----
  hipMemsetAsync(ws + CNT_OFF, 0, 400000, stream);
  k_prep_w<<<21, 256, 0, stream>>>(W1, W2, W3, W1f, W2f, W3f);
  k_fatA<<<FATA_NB, 256, 0, stream>>>(eix, src, dst, cnt, x, (const bf16x8*)W1f,
                                      as1, ad1, h1b, aS, aD);
  k_scan_a<<<NBSC, 1024, 0, stream>>>(cnt, rowptr, bsum);
  k_scan_b<<<1, 128, 0, stream>>>(bsum);
  k_scan_c<<<NBSC, 1024, 0, stream>>>(rowptr, bsum, cnt);
  k_fill<<<(ET + 255) / 256, 256, 0, stream>>>(src, dst, rowptr, cnt, csr);

  // ---- layer 1: 128 -> 8x32 concat (gemm2 fused into gather) ----
  k_msalpha1<<<NN / 4, 256, 0, stream>>>(rowptr, csr, aS, aD, alph);
  k_gather1f<<<NN / 16, 1024, 0, stream>>>(rowptr, csr, alph, h1b, b1,
                                           (const bf16x8*)W2f, as2, ad2,
                                           h2b, aS, aD);

  // ---- layer 2: 256 -> 32 (gemm3 fused into gather) ----
  k_msalpha2<<<NN / 8, 256, 0, stream>>>(rowptr, csr, aS, aD, alph);
  k_gather2f<<<NN / 16, 512, 0, stream>>>(rowptr, csr, alph, h2b, b2,
                                          (const bf16x8*)W3f, as3, ad3,
                                          h3b, aS, aD);

  // ---- layer 3: 32 -> 40 ----
  k_msalpha2<<<NN / 8, 256, 0, stream>>>(rowptr, csr, aS, aD, alph);
  k_gather3<<<NN / 4, 256, 0, stream>>>(rowptr, csr, alph, h3b, b3, out);
}

// Round 11
// 474.573 us; speedup vs baseline: 1.4288x; 1.0718x over previous
//
#include <hip/hip_runtime.h>

#define NN 100000
#define NE 1600000
#define ET 1700000        // NE + NN self-loops
#define NEG 0.2f
#define FNEG 3.4e38f
#define NBSC 98           // scan blocks: ceil(NN/1024)
#define GEMM1_NB 1563     // ceil(NN/64)
#define PE_NB 6641        // ceil(ET/256)
#define FATA_NB 8305      // 5 * 1661 covers 4:1 interleave of PE_NB:GEMM1_NB

// ---------------- workspace layout (bytes) ----------------
#define SRC_OFF   0ULL
#define DST_OFF   6800000ULL
#define RP_OFF    13600000ULL         // rowptr (NN+1)*4
#define CNT_OFF   14000128ULL         // deg / fill cursor NN*4
#define CSR_OFF   14400128ULL         // ET*4
#define W1F_OFF   21200128ULL         // 65536  (16mf x 4kk x 64lane x 8 bf16)
#define W2F_OFF   21265664ULL         // 16384
#define W3F_OFF   21282048ULL         // 3072
#define SC_OFF    21285120ULL         // 1024 (block sums)
#define H_OFF     21286144ULL         // h1b 51.2MB (bf16)
#define H2B_OFF   72486144ULL         // h2b 6.4MB
#define H3B_OFF   88486144ULL         // h3b 8MB
#define ALPH_OFF  123686144ULL        // alpha (layer1 only): ET*8*2 = 27.2MB
#define ASN_OFF   150886144ULL        // layer-2 a_s: 3.2MB (written by fatA/gather1f)
#define ADN_OFF   154086144ULL        // layer-2 a_d: 3.2MB
#define AS2_OFF   157286144ULL        // layer-3 a_s: 400KB (fresh buffer, no race)
#define AD2_OFF   157686144ULL        // layer-3 a_d: 400KB
#define WS_NEED   158086144ULL

typedef short bf16x8 __attribute__((ext_vector_type(8)));
typedef float f32x4 __attribute__((ext_vector_type(4)));

__device__ __forceinline__ float lrelu(float x) { return x > 0.f ? x : NEG * x; }
__device__ __forceinline__ float b2f(unsigned short u) {
  return __uint_as_float(((unsigned)u) << 16);
}
__device__ __forceinline__ unsigned short f2bu(float f) {   // RNE f32->bf16
  unsigned u = __float_as_uint(f);
  return (unsigned short)((u + 0x7FFFu + ((u >> 16) & 1u)) >> 16);
}

__global__ __launch_bounds__(256) void k_sentinel(float* out, int n) {
  int i = blockIdx.x * 256 + threadIdx.x;
  if (i < n) out[i] = 12345.0f;
}

// Pre-arrange W1/W2/W3 (f32) into MFMA A-fragment order as bf16.
// A-frag convention: row(channel) = lane&15, k = (lane>>4)*8 + j.
__global__ __launch_bounds__(256) void k_prep_w(const float* __restrict__ W1,
                                                const float* __restrict__ W2,
                                                const float* __restrict__ W3,
                                                unsigned short* __restrict__ W1f,
                                                unsigned short* __restrict__ W2f,
                                                unsigned short* __restrict__ W3f) {
  int idx = blockIdx.x * 256 + threadIdx.x;
  if (idx < 4096) {                       // W1: 16 mf x 4 kk
    int fg = idx >> 6, lane = idx & 63;
    int mf = fg >> 2, kk = fg & 3;
    int c = mf * 16 + (lane & 15), k0 = kk * 32 + (lane >> 4) * 8;
    unsigned short* o = W1f + idx * 8;
    #pragma unroll
    for (int j = 0; j < 8; ++j) o[j] = f2bu(W1[(k0 + j) * 256 + c]);
  } else if (idx < 5120) {                // W2: 2 mf x 8 kk
    int t = idx - 4096;
    int fg = t >> 6, lane = t & 63;
    int mf = fg >> 3, kk = fg & 7;
    int c = mf * 16 + (lane & 15), k0 = kk * 32 + (lane >> 4) * 8;
    unsigned short* o = W2f + t * 8;
    #pragma unroll
    for (int j = 0; j < 8; ++j) o[j] = f2bu(W2[(k0 + j) * 32 + c]);
  } else if (idx < 5312) {                // W3: 3 mf x 1 kk (pad ch>=40 with 0)
    int t = idx - 5120;
    int mf = t >> 6, lane = t & 63;
    int c = mf * 16 + (lane & 15), k0 = (lane >> 4) * 8;
    unsigned short* o = W3f + t * 8;
    #pragma unroll
    for (int j = 0; j < 8; ++j) o[j] = (c < 40) ? f2bu(W3[(k0 + j) * 40 + c]) : 0;
  }
}

// Fat kernel A: prep_edges (+deg count) interleaved 4:1 with gemm1
// (h1b = x@W1 + fused a_s/a_d epilogue). Independent workloads overlap.
__global__ __launch_bounds__(256) void k_fatA(const int* __restrict__ raw,
                                              int* __restrict__ src,
                                              int* __restrict__ dst,
                                              int* __restrict__ deg,
                                              const float* __restrict__ x,
                                              const bf16x8* __restrict__ W1f,
                                              const float* __restrict__ as1,
                                              const float* __restrict__ ad1,
                                              unsigned short* __restrict__ h,
                                              float* __restrict__ a_s,
                                              float* __restrict__ a_d) {
  __shared__ __align__(16) unsigned short xs[64 * 128];
  __shared__ float asL[256], adL[256];
  const int bid = blockIdx.x;
  const int grp = bid / 5, rem = bid - grp * 5;
  const int tid = threadIdx.x;

  if (rem != 4) {                               // ---- prep_edges ----
    int pe = grp * 4 + rem;
    if (pe >= PE_NB) return;
    bool is64 = true;
    #pragma unroll
    for (int i = 1; i < 32; i += 2) is64 = is64 && (raw[i] == 0);
    long long e = (long long)pe * 256 + tid;
    if (e >= ET) return;
    int s, d;
    if (e < NE) {
      if (is64) {
        const long long* r = (const long long*)raw;
        s = (int)r[e];
        d = (int)r[NE + e];
      } else {
        s = raw[e];
        d = raw[NE + e];
      }
    } else {
      s = d = (int)(e - NE);
    }
    src[e] = s;
    dst[e] = d;
    atomicAdd(&deg[d], 1);
    return;
  }

  // ---- gemm1 ----
  if (grp >= GEMM1_NB) return;
  const int n0 = grp * 64;
  asL[tid] = as1[tid];
  adL[tid] = ad1[tid];
  for (int j = tid; j < 2048; j += 256) {       // stage x -> bf16 LDS
    int r = j >> 5;
    int c4 = (j & 31) << 2;
    long long row = n0 + r; if (row >= NN) row = NN - 1;
    float4 v = *(const float4*)(x + row * 128 + c4);
    unsigned short* p = &xs[r * 128 + c4];
    p[0] = f2bu(v.x); p[1] = f2bu(v.y); p[2] = f2bu(v.z); p[3] = f2bu(v.w);
  }
  __syncthreads();
  const int w = tid >> 6, lane = tid & 63;
  const int nloc = w * 16 + (lane & 15);
  const int node = n0 + nloc;
  bf16x8 bfr[4];
  #pragma unroll
  for (int kk = 0; kk < 4; ++kk)
    bfr[kk] = *(const bf16x8*)&xs[nloc * 128 + kk * 32 + (lane >> 4) * 8];
  const int ch_base = (lane >> 4) * 4;
  float sA[8] = {}, sD[8] = {};
  #pragma unroll
  for (int mf = 0; mf < 16; ++mf) {
    f32x4 acc = {0.f, 0.f, 0.f, 0.f};
    #pragma unroll
    for (int kk = 0; kk < 4; ++kk) {
      bf16x8 af = W1f[(mf * 4 + kk) * 64 + lane];
      acc = __builtin_amdgcn_mfma_f32_16x16x32_bf16(af, bfr[kk], acc, 0, 0, 0);
    }
    const float* av = &asL[mf * 16 + ch_base];
    const float* dv = &adL[mf * 16 + ch_base];
    float ps = acc[0] * av[0] + acc[1] * av[1] + acc[2] * av[2] + acc[3] * av[3];
    float pd = acc[0] * dv[0] + acc[1] * dv[1] + acc[2] * dv[2] + acc[3] * dv[3];
    ps += __shfl_xor(ps, 16); ps += __shfl_xor(ps, 32);
    pd += __shfl_xor(pd, 16); pd += __shfl_xor(pd, 32);
    sA[mf >> 1] += ps; sD[mf >> 1] += pd;
    if (node < NN) {
      ushort4 o;
      o.x = f2bu(acc[0]); o.y = f2bu(acc[1]); o.z = f2bu(acc[2]); o.w = f2bu(acc[3]);
      *(ushort4*)&h[(unsigned)(node * 256 + mf * 16 + ch_base)] = o;
    }
  }
  if (lane < 16 && node < NN) {
    #pragma unroll
    for (int hd = 0; hd < 8; ++hd) {
      a_s[node * 8 + hd] = sA[hd];
      a_d[node * 8 + hd] = sD[hd];
    }
  }
}

// Block-level inclusive scan; rowptr[i+1] = block-local inclusive, bsum[b]=total.
__global__ __launch_bounds__(1024) void k_scan_a(const int* __restrict__ deg,
                                                 int* __restrict__ rowptr,
                                                 int* __restrict__ bsum) {
  __shared__ int wsum[16];
  const int lane = threadIdx.x & 63, wid = threadIdx.x >> 6;
  int i = blockIdx.x * 1024 + threadIdx.x;
  int x = (i < NN) ? deg[i] : 0;
  int inc = x;
  #pragma unroll
  for (int off = 1; off < 64; off <<= 1) {
    int t = __shfl_up(inc, off);
    if (lane >= off) inc += t;
  }
  if (lane == 63) wsum[wid] = inc;
  __syncthreads();
  if (wid == 0) {
    int w = (lane < 16) ? wsum[lane] : 0;
    #pragma unroll
    for (int off = 1; off < 16; off <<= 1) {
      int t = __shfl_up(w, off);
      if (lane >= off) w += t;
    }
    if (lane < 16) wsum[lane] = w;
  }
  __syncthreads();
  int base = wid ? wsum[wid - 1] : 0;
  if (i < NN) rowptr[i + 1] = base + inc;
  if (threadIdx.x == 1023) bsum[blockIdx.x] = base + inc;
}

// Exclusive scan of NBSC block sums (in place).
__global__ __launch_bounds__(128) void k_scan_b(int* __restrict__ bsum) {
  __shared__ int w0tot;
  int tid = threadIdx.x;
  int v = (tid < NBSC) ? bsum[tid] : 0;
  int inc = v;
  #pragma unroll
  for (int off = 1; off < 64; off <<= 1) {
    int t = __shfl_up(inc, off);
    if ((tid & 63) >= off) inc += t;
  }
  if (tid == 63) w0tot = inc;
  __syncthreads();
  if (tid >= 64) inc += w0tot;
  if (tid < NBSC) bsum[tid] = inc - v;
}

// Adds block offsets AND zeroes cnt for the fill pass (saves a memset dispatch).
__global__ __launch_bounds__(1024) void k_scan_c(int* __restrict__ rowptr,
                                                 const int* __restrict__ bsum,
                                                 int* __restrict__ cnt) {
  int i = blockIdx.x * 1024 + threadIdx.x;
  if (i < NN) {
    rowptr[i + 1] += bsum[blockIdx.x];
    cnt[i] = 0;
  }
  if (i == 0) rowptr[0] = 0;
}

__global__ __launch_bounds__(256) void k_fill(const int* __restrict__ src,
                                              const int* __restrict__ dst,
                                              const int* __restrict__ rowptr,
                                              int* __restrict__ cnt,
                                              int* __restrict__ csr) {
  long long e = (long long)blockIdx.x * 256 + threadIdx.x;
  if (e >= ET) return;
  int d = dst[e];
  int p = atomicAdd(&cnt[d], 1);
  csr[rowptr[d] + p] = src[e];
}

// Layer-1 softmax: per-node max/sum + write alpha[ET][8] bf16. Wave per node.
// Fast path (deg<=32, wave-uniform): cache v in 4 statically-indexed regs.
__global__ __launch_bounds__(256) void k_msalpha1(const int* __restrict__ rowptr,
                                                  const int* __restrict__ csr,
                                                  const float* __restrict__ a_s,
                                                  const float* __restrict__ a_d,
                                                  unsigned short* __restrict__ alph) {
  const int node = blockIdx.x * 4 + (threadIdx.x >> 6);
  const int lane = threadIdx.x & 63;
  const int beg = __builtin_amdgcn_readfirstlane(rowptr[node]);
  const int end = __builtin_amdgcn_readfirstlane(rowptr[node + 1]);
  const int hd = lane & 7;
  const int eg = lane >> 3;
  const float adv = a_d[node * 8 + hd];
  float mx = -FNEG, sm = 0.f;
  if (end - beg <= 32) {
    float vc0 = 0.f, vc1 = 0.f, vc2 = 0.f, vc3 = 0.f;
    #pragma unroll
    for (int k = 0; k < 4; ++k) {
      int i = beg + eg + k * 8;
      if (i < end) {
        float v = lrelu(a_s[csr[i] * 8 + hd] + adv);
        if (k == 0) vc0 = v; else if (k == 1) vc1 = v;
        else if (k == 2) vc2 = v; else vc3 = v;
        float nm = fmaxf(mx, v);
        sm = sm * __expf(mx - nm) + __expf(v - nm);
        mx = nm;
      }
    }
    #pragma unroll
    for (int off = 8; off < 64; off <<= 1) {
      float mo = __shfl_xor(mx, off);
      float so = __shfl_xor(sm, off);
      float nm = fmaxf(mx, mo);
      sm = sm * __expf(mx - nm) + so * __expf(mo - nm);
      mx = nm;
    }
    float rden = 1.0f / sm;
    #pragma unroll
    for (int k = 0; k < 4; ++k) {
      int i = beg + eg + k * 8;
      if (i < end) {
        float v = (k == 0) ? vc0 : (k == 1) ? vc1 : (k == 2) ? vc2 : vc3;
        alph[i * 8 + hd] = f2bu(__expf(v - mx) * rden);
      }
    }
  } else {
    for (int i = beg + eg; i < end; i += 8) {
      int s = csr[i];
      float v = lrelu(a_s[s * 8 + hd] + adv);
      float nm = fmaxf(mx, v);
      sm = sm * __expf(mx - nm) + __expf(v - nm);
      mx = nm;
    }
    #pragma unroll
    for (int off = 8; off < 64; off <<= 1) {
      float mo = __shfl_xor(mx, off);
      float so = __shfl_xor(sm, off);
      float nm = fmaxf(mx, mo);
      sm = sm * __expf(mx - nm) + so * __expf(mo - nm);
      mx = nm;
    }
    float rden = 1.0f / sm;
    for (int i = beg + eg; i < end; i += 8) {
      int s = csr[i];
      float v = lrelu(a_s[s * 8 + hd] + adv);
      alph[i * 8 + hd] = f2bu(__expf(v - mx) * rden);
    }
  }
}

// Layer-1 gather+bias+ELU fused with gemm2 (+layer-2 a_s/a_d epilogue).
// 1024 threads = 16 waves = 16 nodes/block. Scalarized csr/rowptr, 32-bit
// h indexing, 8-deep MLP (8 h-loads in flight per wave).
__global__ __launch_bounds__(1024) void k_gather1f(const int* __restrict__ rowptr,
                                                   const int* __restrict__ csr,
                                                   const unsigned short* __restrict__ alph,
                                                   const unsigned short* __restrict__ h,
                                                   const float* __restrict__ b,
                                                   const bf16x8* __restrict__ W2f,
                                                   const float* __restrict__ as2,
                                                   const float* __restrict__ ad2,
                                                   unsigned short* __restrict__ h2,
                                                   float* __restrict__ a_s,
                                                   float* __restrict__ a_d) {
  __shared__ __align__(16) unsigned short xs[16 * 256];
  const int tid = threadIdx.x;
  const int w = tid >> 6, lane = tid & 63;
  const int n0 = blockIdx.x * 16;
  const int node = n0 + w;
  const int beg = __builtin_amdgcn_readfirstlane(rowptr[node]);
  const int end = __builtin_amdgcn_readfirstlane(rowptr[node + 1]);
  const int hd2 = lane >> 3;
  const unsigned l4 = lane * 4;
  float4 acc = {0.f, 0.f, 0.f, 0.f};
  int i = beg;
  for (; i + 8 <= end; i += 8) {
    int s0 = __builtin_amdgcn_readfirstlane(csr[i]);
    int s1 = __builtin_amdgcn_readfirstlane(csr[i + 1]);
    int s2 = __builtin_amdgcn_readfirstlane(csr[i + 2]);
    int s3 = __builtin_amdgcn_readfirstlane(csr[i + 3]);
    int s4 = __builtin_amdgcn_readfirstlane(csr[i + 4]);
    int s5 = __builtin_amdgcn_readfirstlane(csr[i + 5]);
    int s6 = __builtin_amdgcn_readfirstlane(csr[i + 6]);
    int s7 = __builtin_amdgcn_readfirstlane(csr[i + 7]);
    float a0 = b2f(alph[(i + 0) * 8 + hd2]);
    float a1 = b2f(alph[(i + 1) * 8 + hd2]);
    float a2 = b2f(alph[(i + 2) * 8 + hd2]);
    float a3 = b2f(alph[(i + 3) * 8 + hd2]);
    float a4 = b2f(alph[(i + 4) * 8 + hd2]);
    float a5 = b2f(alph[(i + 5) * 8 + hd2]);
    float a6 = b2f(alph[(i + 6) * 8 + hd2]);
    float a7 = b2f(alph[(i + 7) * 8 + hd2]);
    ushort4 h0 = *(const ushort4*)(h + ((unsigned)(s0 << 8) + l4));
    ushort4 h1 = *(const ushort4*)(h + ((unsigned)(s1 << 8) + l4));
    ushort4 h2v = *(const ushort4*)(h + ((unsigned)(s2 << 8) + l4));
    ushort4 h3v = *(const ushort4*)(h + ((unsigned)(s3 << 8) + l4));
    ushort4 h4v = *(const ushort4*)(h + ((unsigned)(s4 << 8) + l4));
    ushort4 h5v = *(const ushort4*)(h + ((unsigned)(s5 << 8) + l4));
    ushort4 h6v = *(const ushort4*)(h + ((unsigned)(s6 << 8) + l4));
    ushort4 h7v = *(const ushort4*)(h + ((unsigned)(s7 << 8) + l4));
    acc.x += a0 * b2f(h0.x) + a1 * b2f(h1.x) + a2 * b2f(h2v.x) + a3 * b2f(h3v.x)
           + a4 * b2f(h4v.x) + a5 * b2f(h5v.x) + a6 * b2f(h6v.x) + a7 * b2f(h7v.x);
    acc.y += a0 * b2f(h0.y) + a1 * b2f(h1.y) + a2 * b2f(h2v.y) + a3 * b2f(h3v.y)
           + a4 * b2f(h4v.y) + a5 * b2f(h5v.y) + a6 * b2f(h6v.y) + a7 * b2f(h7v.y);
    acc.z += a0 * b2f(h0.z) + a1 * b2f(h1.z) + a2 * b2f(h2v.z) + a3 * b2f(h3v.z)
           + a4 * b2f(h4v.z) + a5 * b2f(h5v.z) + a6 * b2f(h6v.z) + a7 * b2f(h7v.z);
    acc.w += a0 * b2f(h0.w) + a1 * b2f(h1.w) + a2 * b2f(h2v.w) + a3 * b2f(h3v.w)
           + a4 * b2f(h4v.w) + a5 * b2f(h5v.w) + a6 * b2f(h6v.w) + a7 * b2f(h7v.w);
  }
  for (; i + 4 <= end; i += 4) {
    int s0 = __builtin_amdgcn_readfirstlane(csr[i]);
    int s1 = __builtin_amdgcn_readfirstlane(csr[i + 1]);
    int s2 = __builtin_amdgcn_readfirstlane(csr[i + 2]);
    int s3 = __builtin_amdgcn_readfirstlane(csr[i + 3]);
    float a0 = b2f(alph[(i + 0) * 8 + hd2]);
    float a1 = b2f(alph[(i + 1) * 8 + hd2]);
    float a2 = b2f(alph[(i + 2) * 8 + hd2]);
    float a3 = b2f(alph[(i + 3) * 8 + hd2]);
    ushort4 h0 = *(const ushort4*)(h + ((unsigned)(s0 << 8) + l4));
    ushort4 h1 = *(const ushort4*)(h + ((unsigned)(s1 << 8) + l4));
    ushort4 h2v = *(const ushort4*)(h + ((unsigned)(s2 << 8) + l4));
    ushort4 h3v = *(const ushort4*)(h + ((unsigned)(s3 << 8) + l4));
    acc.x += a0 * b2f(h0.x) + a1 * b2f(h1.x) + a2 * b2f(h2v.x) + a3 * b2f(h3v.x);
    acc.y += a0 * b2f(h0.y) + a1 * b2f(h1.y) + a2 * b2f(h2v.y) + a3 * b2f(h3v.y);
    acc.z += a0 * b2f(h0.z) + a1 * b2f(h1.z) + a2 * b2f(h2v.z) + a3 * b2f(h3v.z);
    acc.w += a0 * b2f(h0.w) + a1 * b2f(h1.w) + a2 * b2f(h2v.w) + a3 * b2f(h3v.w);
  }
  for (; i < end; ++i) {
    int s0 = __builtin_amdgcn_readfirstlane(csr[i]);
    float a0 = b2f(alph[i * 8 + hd2]);
    ushort4 h0 = *(const ushort4*)(h + ((unsigned)(s0 << 8) + l4));
    acc.x += a0 * b2f(h0.x);
    acc.y += a0 * b2f(h0.y);
    acc.z += a0 * b2f(h0.z);
    acc.w += a0 * b2f(h0.w);
  }
  float4 bv = *(const float4*)(b + l4);
  acc.x += bv.x; acc.y += bv.y; acc.z += bv.z; acc.w += bv.w;
  acc.x = acc.x > 0.f ? acc.x : expm1f(acc.x);
  acc.y = acc.y > 0.f ? acc.y : expm1f(acc.y);
  acc.z = acc.z > 0.f ? acc.z : expm1f(acc.z);
  acc.w = acc.w > 0.f ? acc.w : expm1f(acc.w);
  {
    ushort4 o;
    o.x = f2bu(acc.x); o.y = f2bu(acc.y); o.z = f2bu(acc.z); o.w = f2bu(acc.w);
    *(ushort4*)&xs[w * 256 + l4] = o;
  }
  __syncthreads();
  if (w == 0) {     // gemm2 phase: 16-node tile @ K=256 -> 32 ch + a_s/a_d
    const int nloc = lane & 15;
    const int node2 = n0 + nloc;
    const int ch_base = (lane >> 4) * 4;
    float sA = 0.f, sD = 0.f;
    #pragma unroll
    for (int mf = 0; mf < 2; ++mf) {
      f32x4 c2 = {0.f, 0.f, 0.f, 0.f};
      #pragma unroll
      for (int kk = 0; kk < 8; ++kk) {
        bf16x8 bfr = *(const bf16x8*)&xs[nloc * 256 + kk * 32 + (lane >> 4) * 8];
        c2 = __builtin_amdgcn_mfma_f32_16x16x32_bf16(W2f[(mf * 8 + kk) * 64 + lane],
                                                     bfr, c2, 0, 0, 0);
      }
      float4 av = *(const float4*)(as2 + mf * 16 + ch_base);
      float4 dv = *(const float4*)(ad2 + mf * 16 + ch_base);
      float ps = c2[0] * av.x + c2[1] * av.y + c2[2] * av.z + c2[3] * av.w;
      float pd = c2[0] * dv.x + c2[1] * dv.y + c2[2] * dv.z + c2[3] * dv.w;
      ps += __shfl_xor(ps, 16); ps += __shfl_xor(ps, 32);
      pd += __shfl_xor(pd, 16); pd += __shfl_xor(pd, 32);
      sA += ps; sD += pd;
      ushort4 o;
      o.x = f2bu(c2[0]); o.y = f2bu(c2[1]); o.z = f2bu(c2[2]); o.w = f2bu(c2[3]);
      *(ushort4*)&h2[(unsigned)(node2 * 32 + mf * 16 + ch_base)] = o;
    }
    if (lane < 16) { a_s[node2] = sA; a_d[node2] = sD; }
  }
}

// Layer-2: fused softmax (max/sum in-kernel, alpha recomputed) + gather +
// bias + ELU + gemm3 (+layer-3 a_s/a_d epilogue into FRESH buffers).
// 512 threads = 16 half-waves = 16 nodes/block.
__global__ __launch_bounds__(512) void k_gather2f(const int* __restrict__ rowptr,
                                                  const int* __restrict__ csr,
                                                  const float* __restrict__ a_s,
                                                  const float* __restrict__ a_d,
                                                  const unsigned short* __restrict__ h,
                                                  const float* __restrict__ b,
                                                  const bf16x8* __restrict__ W3f,
                                                  const float* __restrict__ as3,
                                                  const float* __restrict__ ad3,
                                                  unsigned short* __restrict__ h3,
                                                  float* __restrict__ a_s3,
                                                  float* __restrict__ a_d3) {
  __shared__ __align__(16) unsigned short xs[16 * 32];
  const int tid = threadIdx.x;
  const int hw = tid >> 5, lane32 = tid & 31;
  const int n0 = blockIdx.x * 16;
  const int node = n0 + hw;
  const int beg = rowptr[node], end = rowptr[node + 1];
  const float adv = a_d[node];

  // pass 1: online max/sum (strided 32)
  float mx = -FNEG, sm = 0.f;
  for (int i = beg + lane32; i < end; i += 32) {
    float v = lrelu(a_s[csr[i]] + adv);
    float nm = fmaxf(mx, v);
    sm = sm * __expf(mx - nm) + __expf(v - nm);
    mx = nm;
  }
  #pragma unroll
  for (int off = 1; off < 32; off <<= 1) {
    float mo = __shfl_xor(mx, off, 32);
    float so = __shfl_xor(sm, off, 32);
    float nm = fmaxf(mx, mo);
    sm = sm * __expf(mx - nm) + so * __expf(mo - nm);
    mx = nm;
  }
  float rden = 1.0f / sm;

  // pass 2: gather with recomputed alpha (a_s is 400KB -> L2-resident)
  float acc = 0.f;
  int i = beg;
  for (; i + 4 <= end; i += 4) {
    int s0 = csr[i], s1 = csr[i + 1], s2 = csr[i + 2], s3 = csr[i + 3];
    float a0 = __expf(lrelu(a_s[s0] + adv) - mx) * rden;
    float a1 = __expf(lrelu(a_s[s1] + adv) - mx) * rden;
    float a2 = __expf(lrelu(a_s[s2] + adv) - mx) * rden;
    float a3 = __expf(lrelu(a_s[s3] + adv) - mx) * rden;
    unsigned short v0 = h[(unsigned)(s0 * 32 + lane32)];
    unsigned short v1 = h[(unsigned)(s1 * 32 + lane32)];
    unsigned short v2 = h[(unsigned)(s2 * 32 + lane32)];
    unsigned short v3 = h[(unsigned)(s3 * 32 + lane32)];
    acc += a0 * b2f(v0) + a1 * b2f(v1) + a2 * b2f(v2) + a3 * b2f(v3);
  }
  for (; i < end; ++i) {
    int s0 = csr[i];
    float a0 = __expf(lrelu(a_s[s0] + adv) - mx) * rden;
    acc += a0 * b2f(h[(unsigned)(s0 * 32 + lane32)]);
  }
  acc += b[lane32];
  acc = acc > 0.f ? acc : expm1f(acc);
  xs[hw * 32 + lane32] = f2bu(acc);
  __syncthreads();
  if (tid < 64) {   // gemm3 phase: 16-node tile @ K=32 -> 40 ch + a_s/a_d
    const int lane = tid;
    const int nloc = lane & 15;
    const int node3 = n0 + nloc;
    const int ch_base = (lane >> 4) * 4;
    bf16x8 bfr = *(const bf16x8*)&xs[nloc * 32 + (lane >> 4) * 8];
    float sA = 0.f, sD = 0.f;
    #pragma unroll
    for (int mf = 0; mf < 3; ++mf) {
      f32x4 c3 = {0.f, 0.f, 0.f, 0.f};
      c3 = __builtin_amdgcn_mfma_f32_16x16x32_bf16(W3f[mf * 64 + lane], bfr, c3, 0, 0, 0);
      int ch0 = mf * 16 + ch_base;
      float4 av = {0.f, 0.f, 0.f, 0.f}, dv = {0.f, 0.f, 0.f, 0.f};
      if (ch0 < 40) {
        av = *(const float4*)(as3 + ch0);
        dv = *(const float4*)(ad3 + ch0);
      }
      float ps = c3[0] * av.x + c3[1] * av.y + c3[2] * av.z + c3[3] * av.w;
      float pd = c3[0] * dv.x + c3[1] * dv.y + c3[2] * dv.z + c3[3] * dv.w;
      ps += __shfl_xor(ps, 16); ps += __shfl_xor(ps, 32);
      pd += __shfl_xor(pd, 16); pd += __shfl_xor(pd, 32);
      sA += ps; sD += pd;
      if (ch0 < 40) {
        ushort4 o;
        o.x = f2bu(c3[0]); o.y = f2bu(c3[1]); o.z = f2bu(c3[2]); o.w = f2bu(c3[3]);
        *(ushort4*)&h3[(unsigned)(node3 * 40 + ch0)] = o;
      }
    }
    if (lane < 16) { a_s3[node3] = sA; a_d3[node3] = sD; }
  }
}

// Layer-3: fused softmax + gather + bias + log_softmax -> f32 out.
// Wave per node; pass1 64-lane strided; pass2 scalarized csr + uniform alpha.
__global__ __launch_bounds__(256) void k_gather3f(const int* __restrict__ rowptr,
                                                  const int* __restrict__ csr,
                                                  const float* __restrict__ a_s,
                                                  const float* __restrict__ a_d,
                                                  const unsigned short* __restrict__ h,
                                                  const float* __restrict__ b,
                                                  float* __restrict__ out) {
  const int node = blockIdx.x * 4 + (threadIdx.x >> 6);
  const int lane = threadIdx.x & 63;
  const int beg = __builtin_amdgcn_readfirstlane(rowptr[node]);
  const int end = __builtin_amdgcn_readfirstlane(rowptr[node + 1]);
  const float adv = a_d[node];

  // pass 1: online max/sum (strided 64)
  float mx = -FNEG, sm = 0.f;
  for (int i = beg + lane; i < end; i += 64) {
    float v = lrelu(a_s[csr[i]] + adv);
    float nm = fmaxf(mx, v);
    sm = sm * __expf(mx - nm) + __expf(v - nm);
    mx = nm;
  }
  #pragma unroll
  for (int off = 1; off < 64; off <<= 1) {
    float mo = __shfl_xor(mx, off);
    float so = __shfl_xor(sm, off);
    float nm = fmaxf(mx, mo);
    sm = sm * __expf(mx - nm) + so * __expf(mo - nm);
    mx = nm;
  }
  float rden = 1.0f / sm;

  // pass 2: gather with recomputed (wave-uniform) alpha
  float acc = 0.f;
  int i = beg;
  for (; i + 4 <= end; i += 4) {
    int s0 = __builtin_amdgcn_readfirstlane(csr[i]);
    int s1 = __builtin_amdgcn_readfirstlane(csr[i + 1]);
    int s2 = __builtin_amdgcn_readfirstlane(csr[i + 2]);
    int s3 = __builtin_amdgcn_readfirstlane(csr[i + 3]);
    float a0 = __expf(lrelu(a_s[s0] + adv) - mx) * rden;
    float a1 = __expf(lrelu(a_s[s1] + adv) - mx) * rden;
    float a2 = __expf(lrelu(a_s[s2] + adv) - mx) * rden;
    float a3 = __expf(lrelu(a_s[s3] + adv) - mx) * rden;
    if (lane < 40) {
      unsigned short v0 = h[(unsigned)(s0 * 40 + lane)];
      unsigned short v1 = h[(unsigned)(s1 * 40 + lane)];
      unsigned short v2 = h[(unsigned)(s2 * 40 + lane)];
      unsigned short v3 = h[(unsigned)(s3 * 40 + lane)];
      acc += a0 * b2f(v0) + a1 * b2f(v1) + a2 * b2f(v2) + a3 * b2f(v3);
    }
  }
  for (; i < end; ++i) {
    int s0 = __builtin_amdgcn_readfirstlane(csr[i]);
    float a0 = __expf(lrelu(a_s[s0] + adv) - mx) * rden;
    if (lane < 40) acc += a0 * b2f(h[(unsigned)(s0 * 40 + lane)]);
  }
  float v = (lane < 40) ? acc + b[lane] : -FNEG;
  float vmax = v;
  #pragma unroll
  for (int off = 1; off < 64; off <<= 1) vmax = fmaxf(vmax, __shfl_xor(vmax, off));
  float ex = (lane < 40) ? __expf(v - vmax) : 0.f;
  float es = ex;
  #pragma unroll
  for (int off = 1; off < 64; off <<= 1) es += __shfl_xor(es, off);
  float lse = vmax + __logf(es);
  if (lane < 40) out[(long long)node * 40 + lane] = v - lse;
}

extern "C" void kernel_launch(void* const* d_in, const int* in_sizes, int n_in,
                              void* d_out, int out_size, void* d_ws, size_t ws_size,
                              hipStream_t stream) {
  const float* x   = (const float*)d_in[0];
  const int*   eix = (const int*)d_in[1];
  const float* W1  = (const float*)d_in[2];
  const float* as1 = (const float*)d_in[3];
  const float* ad1 = (const float*)d_in[4];
  const float* b1  = (const float*)d_in[5];
  const float* W2  = (const float*)d_in[6];
  const float* as2 = (const float*)d_in[7];
  const float* ad2 = (const float*)d_in[8];
  const float* b2  = (const float*)d_in[9];
  const float* W3  = (const float*)d_in[10];
  const float* as3 = (const float*)d_in[11];
  const float* ad3 = (const float*)d_in[12];
  const float* b3  = (const float*)d_in[13];
  float* out = (float*)d_out;

  if (ws_size < WS_NEED) {
    k_sentinel<<<(out_size + 255) / 256, 256, 0, stream>>>(out, out_size);
    return;
  }

  char* ws = (char*)d_ws;
  int*    src    = (int*)(ws + SRC_OFF);
  int*    dst    = (int*)(ws + DST_OFF);
  int*    rowptr = (int*)(ws + RP_OFF);
  int*    cnt    = (int*)(ws + CNT_OFF);
  int*    csr    = (int*)(ws + CSR_OFF);
  unsigned short* W1f = (unsigned short*)(ws + W1F_OFF);
  unsigned short* W2f = (unsigned short*)(ws + W2F_OFF);
  unsigned short* W3f = (unsigned short*)(ws + W3F_OFF);
  int*    bsum   = (int*)(ws + SC_OFF);
  unsigned short* h1b  = (unsigned short*)(ws + H_OFF);
  unsigned short* h2b  = (unsigned short*)(ws + H2B_OFF);
  unsigned short* h3b  = (unsigned short*)(ws + H3B_OFF);
  unsigned short* alph = (unsigned short*)(ws + ALPH_OFF);
  float*  aS     = (float*)(ws + ASN_OFF);
  float*  aD     = (float*)(ws + ADN_OFF);
  float*  aS2    = (float*)(ws + AS2_OFF);
  float*  aD2    = (float*)(ws + AD2_OFF);

  // ---- prep + CSR build (prep_edges overlapped with gemm1 in k_fatA) ----
  hipMemsetAsync(ws + CNT_OFF, 0, 400000, stream);
  k_prep_w<<<21, 256, 0, stream>>>(W1, W2, W3, W1f, W2f, W3f);
  k_fatA<<<FATA_NB, 256, 0, stream>>>(eix, src, dst, cnt, x, (const bf16x8*)W1f,
                                      as1, ad1, h1b, aS, aD);
  k_scan_a<<<NBSC, 1024, 0, stream>>>(cnt, rowptr, bsum);
  k_scan_b<<<1, 128, 0, stream>>>(bsum);
  k_scan_c<<<NBSC, 1024, 0, stream>>>(rowptr, bsum, cnt);
  k_fill<<<(ET + 255) / 256, 256, 0, stream>>>(src, dst, rowptr, cnt, csr);

  // ---- layer 1: 128 -> 8x32 concat (gemm2 fused into gather) ----
  k_msalpha1<<<NN / 4, 256, 0, stream>>>(rowptr, csr, aS, aD, alph);
  k_gather1f<<<NN / 16, 1024, 0, stream>>>(rowptr, csr, alph, h1b, b1,
                                           (const bf16x8*)W2f, as2, ad2,
                                           h2b, aS, aD);

  // ---- layer 2: 256 -> 32 (softmax + gemm3 fused into gather) ----
  k_gather2f<<<NN / 16, 512, 0, stream>>>(rowptr, csr, aS, aD, h2b, b2,
                                          (const bf16x8*)W3f, as3, ad3,
                                          h3b, aS2, aD2);

  // ---- layer 3: 32 -> 40 (softmax fused into gather) ----
  k_gather3f<<<NN / 4, 256, 0, stream>>>(rowptr, csr, aS2, aD2, h3b, b3, out);
}

// Round 12
// 434.500 us; speedup vs baseline: 1.5606x; 1.0922x over previous
//
#include <hip/hip_runtime.h>

#define NN 100000
#define NE 1600000
#define ET 1700000        // NE + NN self-loops
#define NEG 0.2f
#define FNEG 3.4e38f
#define NBSC 98           // scan blocks: ceil(NN/1024)
#define GEMM1_NB 1563     // ceil(NN/64)
#define PE_NB 6641        // ceil(ET/256)
#define FATA_NB 8305      // 5 * 1661 covers 4:1 interleave of PE_NB:GEMM1_NB
#define FILL_CH 425000    // ET/4 (divisible by 8)

// ---------------- workspace layout (bytes) ----------------
#define SRC_OFF   0ULL
#define DST_OFF   6800000ULL
#define RP_OFF    13600000ULL         // rowptr (NN+1)*4
#define CSR_OFF   14400128ULL         // ET*4
#define W1F_OFF   21200128ULL         // 65536  (16mf x 4kk x 64lane x 8 bf16)
#define W2F_OFF   21265664ULL         // 16384
#define W3F_OFF   21282048ULL         // 3072
#define SC_OFF    21285120ULL         // 1024 (block sums)
#define H_OFF     21286144ULL         // h1b 51.2MB (bf16)
#define H2B_OFF   72486144ULL         // h2b 6.4MB
#define H3B_OFF   88486144ULL         // h3b 8MB
#define ALPH_OFF  123686144ULL        // alpha (layer1 only): ET*8*2 = 27.2MB
#define ASN_OFF   150886144ULL        // layer-2 a_s: 3.2MB
#define ADN_OFF   154086144ULL        // layer-2 a_d: 3.2MB
#define AS2_OFF   157286144ULL        // layer-3 a_s: 400KB
#define AD2_OFF   157686144ULL        // layer-3 a_d: 400KB
#define CNT8_OFF  158086144ULL        // replicated histogram 8*NN*4 = 3.2MB
#define RANK_OFF  161286144ULL        // per-edge rank within replica: ET*4
#define WS_NEED   168086144ULL

typedef short bf16x8 __attribute__((ext_vector_type(8)));
typedef float f32x4 __attribute__((ext_vector_type(4)));

__device__ __forceinline__ float lrelu(float x) { return x > 0.f ? x : NEG * x; }
__device__ __forceinline__ float b2f(unsigned short u) {
  return __uint_as_float(((unsigned)u) << 16);
}
__device__ __forceinline__ unsigned short f2bu(float f) {   // RNE f32->bf16
  unsigned u = __float_as_uint(f);
  return (unsigned short)((u + 0x7FFFu + ((u >> 16) & 1u)) >> 16);
}

__global__ __launch_bounds__(256) void k_sentinel(float* out, int n) {
  int i = blockIdx.x * 256 + threadIdx.x;
  if (i < n) out[i] = 12345.0f;
}

// Pre-arrange W1/W2/W3 (f32) into MFMA A-fragment order as bf16.
__global__ __launch_bounds__(256) void k_prep_w(const float* __restrict__ W1,
                                                const float* __restrict__ W2,
                                                const float* __restrict__ W3,
                                                unsigned short* __restrict__ W1f,
                                                unsigned short* __restrict__ W2f,
                                                unsigned short* __restrict__ W3f) {
  int idx = blockIdx.x * 256 + threadIdx.x;
  if (idx < 4096) {                       // W1: 16 mf x 4 kk
    int fg = idx >> 6, lane = idx & 63;
    int mf = fg >> 2, kk = fg & 3;
    int c = mf * 16 + (lane & 15), k0 = kk * 32 + (lane >> 4) * 8;
    unsigned short* o = W1f + idx * 8;
    #pragma unroll
    for (int j = 0; j < 8; ++j) o[j] = f2bu(W1[(k0 + j) * 256 + c]);
  } else if (idx < 5120) {                // W2: 2 mf x 8 kk
    int t = idx - 4096;
    int fg = t >> 6, lane = t & 63;
    int mf = fg >> 3, kk = fg & 7;
    int c = mf * 16 + (lane & 15), k0 = kk * 32 + (lane >> 4) * 8;
    unsigned short* o = W2f + t * 8;
    #pragma unroll
    for (int j = 0; j < 8; ++j) o[j] = f2bu(W2[(k0 + j) * 32 + c]);
  } else if (idx < 5312) {                // W3: 3 mf x 1 kk (pad ch>=40 with 0)
    int t = idx - 5120;
    int mf = t >> 6, lane = t & 63;
    int c = mf * 16 + (lane & 15), k0 = (lane >> 4) * 8;
    unsigned short* o = W3f + t * 8;
    #pragma unroll
    for (int j = 0; j < 8; ++j) o[j] = (c < 40) ? f2bu(W3[(k0 + j) * 40 + c]) : 0;
  }
}

// Fat kernel A: prep_edges (+replicated deg count, rank capture) interleaved
// 4:1 with gemm1 (h1b = x@W1 + fused a_s/a_d epilogue).
__global__ __launch_bounds__(256) void k_fatA(const int* __restrict__ raw,
                                              int* __restrict__ src,
                                              int* __restrict__ dst,
                                              int* __restrict__ cnt8,
                                              int* __restrict__ rank,
                                              const float* __restrict__ x,
                                              const bf16x8* __restrict__ W1f,
                                              const float* __restrict__ as1,
                                              const float* __restrict__ ad1,
                                              unsigned short* __restrict__ h,
                                              float* __restrict__ a_s,
                                              float* __restrict__ a_d) {
  __shared__ __align__(16) unsigned short xs[64 * 128];
  __shared__ float asL[256], adL[256];
  const int bid = blockIdx.x;
  const int grp = bid / 5, rem = bid - grp * 5;
  const int tid = threadIdx.x;

  if (rem != 4) {                               // ---- prep_edges ----
    int pe = grp * 4 + rem;
    if (pe >= PE_NB) return;
    bool is64 = true;
    #pragma unroll
    for (int i = 1; i < 32; i += 2) is64 = is64 && (raw[i] == 0);
    long long e = (long long)pe * 256 + tid;
    if (e >= ET) return;
    int s, d;
    if (e < NE) {
      if (is64) {
        const long long* r = (const long long*)raw;
        s = (int)r[e];
        d = (int)r[NE + e];
      } else {
        s = raw[e];
        d = raw[NE + e];
      }
    } else {
      s = d = (int)(e - NE);
    }
    src[e] = s;
    dst[e] = d;
    // replicated histogram (replica = e&7 = tid&7); keep rank for atomic-free fill
    rank[e] = atomicAdd(&cnt8[(tid & 7) * NN + d], 1);
    return;
  }

  // ---- gemm1 ----
  if (grp >= GEMM1_NB) return;
  const int n0 = grp * 64;
  asL[tid] = as1[tid];
  adL[tid] = ad1[tid];
  for (int j = tid; j < 2048; j += 256) {       // stage x -> bf16 LDS
    int r = j >> 5;
    int c4 = (j & 31) << 2;
    long long row = n0 + r; if (row >= NN) row = NN - 1;
    float4 v = *(const float4*)(x + row * 128 + c4);
    unsigned short* p = &xs[r * 128 + c4];
    p[0] = f2bu(v.x); p[1] = f2bu(v.y); p[2] = f2bu(v.z); p[3] = f2bu(v.w);
  }
  __syncthreads();
  const int w = tid >> 6, lane = tid & 63;
  const int nloc = w * 16 + (lane & 15);
  const int node = n0 + nloc;
  bf16x8 bfr[4];
  #pragma unroll
  for (int kk = 0; kk < 4; ++kk)
    bfr[kk] = *(const bf16x8*)&xs[nloc * 128 + kk * 32 + (lane >> 4) * 8];
  const int ch_base = (lane >> 4) * 4;
  float sA[8] = {}, sD[8] = {};
  #pragma unroll
  for (int mf = 0; mf < 16; ++mf) {
    f32x4 acc = {0.f, 0.f, 0.f, 0.f};
    #pragma unroll
    for (int kk = 0; kk < 4; ++kk) {
      bf16x8 af = W1f[(mf * 4 + kk) * 64 + lane];
      acc = __builtin_amdgcn_mfma_f32_16x16x32_bf16(af, bfr[kk], acc, 0, 0, 0);
    }
    const float* av = &asL[mf * 16 + ch_base];
    const float* dv = &adL[mf * 16 + ch_base];
    float ps = acc[0] * av[0] + acc[1] * av[1] + acc[2] * av[2] + acc[3] * av[3];
    float pd = acc[0] * dv[0] + acc[1] * dv[1] + acc[2] * dv[2] + acc[3] * dv[3];
    ps += __shfl_xor(ps, 16); ps += __shfl_xor(ps, 32);
    pd += __shfl_xor(pd, 16); pd += __shfl_xor(pd, 32);
    sA[mf >> 1] += ps; sD[mf >> 1] += pd;
    if (node < NN) {
      ushort4 o;
      o.x = f2bu(acc[0]); o.y = f2bu(acc[1]); o.z = f2bu(acc[2]); o.w = f2bu(acc[3]);
      *(ushort4*)&h[(unsigned)(node * 256 + mf * 16 + ch_base)] = o;
    }
  }
  if (lane < 16 && node < NN) {
    #pragma unroll
    for (int hd = 0; hd < 8; ++hd) {
      a_s[node * 8 + hd] = sA[hd];
      a_d[node * 8 + hd] = sD[hd];
    }
  }
}

// Block-level inclusive scan over node degrees. Folds the 8 histogram
// replicas: in-place exclusive prefix per node (giving per-replica base
// offsets for the fill), deg = total.
__global__ __launch_bounds__(1024) void k_scan_a(int* __restrict__ cnt8,
                                                 int* __restrict__ rowptr,
                                                 int* __restrict__ bsum) {
  __shared__ int wsum[16];
  const int lane = threadIdx.x & 63, wid = threadIdx.x >> 6;
  int i = blockIdx.x * 1024 + threadIdx.x;
  int x = 0;
  if (i < NN) {
    int run = 0;
    #pragma unroll
    for (int k = 0; k < 8; ++k) {
      int c = cnt8[k * NN + i];
      cnt8[k * NN + i] = run;        // exclusive prefix (per-replica base)
      run += c;
    }
    x = run;                          // total degree
  }
  int inc = x;
  #pragma unroll
  for (int off = 1; off < 64; off <<= 1) {
    int t = __shfl_up(inc, off);
    if (lane >= off) inc += t;
  }
  if (lane == 63) wsum[wid] = inc;
  __syncthreads();
  if (wid == 0) {
    int w = (lane < 16) ? wsum[lane] : 0;
    #pragma unroll
    for (int off = 1; off < 16; off <<= 1) {
      int t = __shfl_up(w, off);
      if (lane >= off) w += t;
    }
    if (lane < 16) wsum[lane] = w;
  }
  __syncthreads();
  int base = wid ? wsum[wid - 1] : 0;
  if (i < NN) rowptr[i + 1] = base + inc;
  if (threadIdx.x == 1023) bsum[blockIdx.x] = base + inc;
}

// Exclusive scan of NBSC block sums (in place).
__global__ __launch_bounds__(128) void k_scan_b(int* __restrict__ bsum) {
  __shared__ int w0tot;
  int tid = threadIdx.x;
  int v = (tid < NBSC) ? bsum[tid] : 0;
  int inc = v;
  #pragma unroll
  for (int off = 1; off < 64; off <<= 1) {
    int t = __shfl_up(inc, off);
    if ((tid & 63) >= off) inc += t;
  }
  if (tid == 63) w0tot = inc;
  __syncthreads();
  if (tid >= 64) inc += w0tot;
  if (tid < NBSC) bsum[tid] = inc - v;
}

__global__ __launch_bounds__(1024) void k_scan_c(int* __restrict__ rowptr,
                                                 const int* __restrict__ bsum) {
  int i = blockIdx.x * 1024 + threadIdx.x;
  if (i < NN) rowptr[i + 1] += bsum[blockIdx.x];
  if (i == 0) rowptr[0] = 0;
}

// Atomic-free CSR fill: slot = rowptr[d] + prefix8[e&7][d] + rank[e].
// 4 edges per thread (coalesced chunks), all loads independent -> MLP.
__global__ __launch_bounds__(256) void k_fill_nr(const int* __restrict__ src,
                                                 const int* __restrict__ dst,
                                                 const int* __restrict__ rank,
                                                 const int* __restrict__ cnt8,
                                                 const int* __restrict__ rowptr,
                                                 int* __restrict__ csr) {
  int gid = blockIdx.x * 256 + threadIdx.x;
  if (gid >= FILL_CH) return;
  const int h = gid & 7;                 // FILL_CH % 8 == 0 -> e&7 == gid&7
  int e0 = gid, e1 = gid + FILL_CH, e2 = gid + 2 * FILL_CH, e3 = gid + 3 * FILL_CH;
  int d0 = dst[e0], d1 = dst[e1], d2 = dst[e2], d3 = dst[e3];
  int r0 = rank[e0], r1 = rank[e1], r2 = rank[e2], r3 = rank[e3];
  int s0 = src[e0], s1 = src[e1], s2 = src[e2], s3 = src[e3];
  int p0 = cnt8[h * NN + d0], p1 = cnt8[h * NN + d1];
  int p2 = cnt8[h * NN + d2], p3 = cnt8[h * NN + d3];
  int b0 = rowptr[d0], b1 = rowptr[d1], b2 = rowptr[d2], b3 = rowptr[d3];
  csr[b0 + p0 + r0] = s0;
  csr[b1 + p1 + r1] = s1;
  csr[b2 + p2 + r2] = s2;
  csr[b3 + p3 + r3] = s3;
}

// Layer-1 softmax: per-node max/sum + write alpha[ET][8] bf16. Wave per node.
__global__ __launch_bounds__(256) void k_msalpha1(const int* __restrict__ rowptr,
                                                  const int* __restrict__ csr,
                                                  const float* __restrict__ a_s,
                                                  const float* __restrict__ a_d,
                                                  unsigned short* __restrict__ alph) {
  const int node = blockIdx.x * 4 + (threadIdx.x >> 6);
  const int lane = threadIdx.x & 63;
  const int beg = __builtin_amdgcn_readfirstlane(rowptr[node]);
  const int end = __builtin_amdgcn_readfirstlane(rowptr[node + 1]);
  const int hd = lane & 7;
  const int eg = lane >> 3;
  const float adv = a_d[node * 8 + hd];
  float mx = -FNEG, sm = 0.f;
  if (end - beg <= 32) {
    float vc0 = 0.f, vc1 = 0.f, vc2 = 0.f, vc3 = 0.f;
    #pragma unroll
    for (int k = 0; k < 4; ++k) {
      int i = beg + eg + k * 8;
      if (i < end) {
        float v = lrelu(a_s[csr[i] * 8 + hd] + adv);
        if (k == 0) vc0 = v; else if (k == 1) vc1 = v;
        else if (k == 2) vc2 = v; else vc3 = v;
        float nm = fmaxf(mx, v);
        sm = sm * __expf(mx - nm) + __expf(v - nm);
        mx = nm;
      }
    }
    #pragma unroll
    for (int off = 8; off < 64; off <<= 1) {
      float mo = __shfl_xor(mx, off);
      float so = __shfl_xor(sm, off);
      float nm = fmaxf(mx, mo);
      sm = sm * __expf(mx - nm) + so * __expf(mo - nm);
      mx = nm;
    }
    float rden = 1.0f / sm;
    #pragma unroll
    for (int k = 0; k < 4; ++k) {
      int i = beg + eg + k * 8;
      if (i < end) {
        float v = (k == 0) ? vc0 : (k == 1) ? vc1 : (k == 2) ? vc2 : vc3;
        alph[i * 8 + hd] = f2bu(__expf(v - mx) * rden);
      }
    }
  } else {
    for (int i = beg + eg; i < end; i += 8) {
      int s = csr[i];
      float v = lrelu(a_s[s * 8 + hd] + adv);
      float nm = fmaxf(mx, v);
      sm = sm * __expf(mx - nm) + __expf(v - nm);
      mx = nm;
    }
    #pragma unroll
    for (int off = 8; off < 64; off <<= 1) {
      float mo = __shfl_xor(mx, off);
      float so = __shfl_xor(sm, off);
      float nm = fmaxf(mx, mo);
      sm = sm * __expf(mx - nm) + so * __expf(mo - nm);
      mx = nm;
    }
    float rden = 1.0f / sm;
    for (int i = beg + eg; i < end; i += 8) {
      int s = csr[i];
      float v = lrelu(a_s[s * 8 + hd] + adv);
      alph[i * 8 + hd] = f2bu(__expf(v - mx) * rden);
    }
  }
}

// Layer-1 gather+bias+ELU fused with gemm2 (+layer-2 a_s/a_d epilogue).
// 1024 threads = 16 waves = 16 nodes/block. Scalarized csr/rowptr, 32-bit
// h indexing, 8-deep MLP.
__global__ __launch_bounds__(1024) void k_gather1f(const int* __restrict__ rowptr,
                                                   const int* __restrict__ csr,
                                                   const unsigned short* __restrict__ alph,
                                                   const unsigned short* __restrict__ h,
                                                   const float* __restrict__ b,
                                                   const bf16x8* __restrict__ W2f,
                                                   const float* __restrict__ as2,
                                                   const float* __restrict__ ad2,
                                                   unsigned short* __restrict__ h2,
                                                   float* __restrict__ a_s,
                                                   float* __restrict__ a_d) {
  __shared__ __align__(16) unsigned short xs[16 * 256];
  const int tid = threadIdx.x;
  const int w = tid >> 6, lane = tid & 63;
  const int n0 = blockIdx.x * 16;
  const int node = n0 + w;
  const int beg = __builtin_amdgcn_readfirstlane(rowptr[node]);
  const int end = __builtin_amdgcn_readfirstlane(rowptr[node + 1]);
  const int hd2 = lane >> 3;
  const unsigned l4 = lane * 4;
  float4 acc = {0.f, 0.f, 0.f, 0.f};
  int i = beg;
  for (; i + 8 <= end; i += 8) {
    int s0 = __builtin_amdgcn_readfirstlane(csr[i]);
    int s1 = __builtin_amdgcn_readfirstlane(csr[i + 1]);
    int s2 = __builtin_amdgcn_readfirstlane(csr[i + 2]);
    int s3 = __builtin_amdgcn_readfirstlane(csr[i + 3]);
    int s4 = __builtin_amdgcn_readfirstlane(csr[i + 4]);
    int s5 = __builtin_amdgcn_readfirstlane(csr[i + 5]);
    int s6 = __builtin_amdgcn_readfirstlane(csr[i + 6]);
    int s7 = __builtin_amdgcn_readfirstlane(csr[i + 7]);
    float a0 = b2f(alph[(i + 0) * 8 + hd2]);
    float a1 = b2f(alph[(i + 1) * 8 + hd2]);
    float a2 = b2f(alph[(i + 2) * 8 + hd2]);
    float a3 = b2f(alph[(i + 3) * 8 + hd2]);
    float a4 = b2f(alph[(i + 4) * 8 + hd2]);
    float a5 = b2f(alph[(i + 5) * 8 + hd2]);
    float a6 = b2f(alph[(i + 6) * 8 + hd2]);
    float a7 = b2f(alph[(i + 7) * 8 + hd2]);
    ushort4 h0 = *(const ushort4*)(h + ((unsigned)(s0 << 8) + l4));
    ushort4 h1 = *(const ushort4*)(h + ((unsigned)(s1 << 8) + l4));
    ushort4 h2v = *(const ushort4*)(h + ((unsigned)(s2 << 8) + l4));
    ushort4 h3v = *(const ushort4*)(h + ((unsigned)(s3 << 8) + l4));
    ushort4 h4v = *(const ushort4*)(h + ((unsigned)(s4 << 8) + l4));
    ushort4 h5v = *(const ushort4*)(h + ((unsigned)(s5 << 8) + l4));
    ushort4 h6v = *(const ushort4*)(h + ((unsigned)(s6 << 8) + l4));
    ushort4 h7v = *(const ushort4*)(h + ((unsigned)(s7 << 8) + l4));
    acc.x += a0 * b2f(h0.x) + a1 * b2f(h1.x) + a2 * b2f(h2v.x) + a3 * b2f(h3v.x)
           + a4 * b2f(h4v.x) + a5 * b2f(h5v.x) + a6 * b2f(h6v.x) + a7 * b2f(h7v.x);
    acc.y += a0 * b2f(h0.y) + a1 * b2f(h1.y) + a2 * b2f(h2v.y) + a3 * b2f(h3v.y)
           + a4 * b2f(h4v.y) + a5 * b2f(h5v.y) + a6 * b2f(h6v.y) + a7 * b2f(h7v.y);
    acc.z += a0 * b2f(h0.z) + a1 * b2f(h1.z) + a2 * b2f(h2v.z) + a3 * b2f(h3v.z)
           + a4 * b2f(h4v.z) + a5 * b2f(h5v.z) + a6 * b2f(h6v.z) + a7 * b2f(h7v.z);
    acc.w += a0 * b2f(h0.w) + a1 * b2f(h1.w) + a2 * b2f(h2v.w) + a3 * b2f(h3v.w)
           + a4 * b2f(h4v.w) + a5 * b2f(h5v.w) + a6 * b2f(h6v.w) + a7 * b2f(h7v.w);
  }
  for (; i + 4 <= end; i += 4) {
    int s0 = __builtin_amdgcn_readfirstlane(csr[i]);
    int s1 = __builtin_amdgcn_readfirstlane(csr[i + 1]);
    int s2 = __builtin_amdgcn_readfirstlane(csr[i + 2]);
    int s3 = __builtin_amdgcn_readfirstlane(csr[i + 3]);
    float a0 = b2f(alph[(i + 0) * 8 + hd2]);
    float a1 = b2f(alph[(i + 1) * 8 + hd2]);
    float a2 = b2f(alph[(i + 2) * 8 + hd2]);
    float a3 = b2f(alph[(i + 3) * 8 + hd2]);
    ushort4 h0 = *(const ushort4*)(h + ((unsigned)(s0 << 8) + l4));
    ushort4 h1 = *(const ushort4*)(h + ((unsigned)(s1 << 8) + l4));
    ushort4 h2v = *(const ushort4*)(h + ((unsigned)(s2 << 8) + l4));
    ushort4 h3v = *(const ushort4*)(h + ((unsigned)(s3 << 8) + l4));
    acc.x += a0 * b2f(h0.x) + a1 * b2f(h1.x) + a2 * b2f(h2v.x) + a3 * b2f(h3v.x);
    acc.y += a0 * b2f(h0.y) + a1 * b2f(h1.y) + a2 * b2f(h2v.y) + a3 * b2f(h3v.y);
    acc.z += a0 * b2f(h0.z) + a1 * b2f(h1.z) + a2 * b2f(h2v.z) + a3 * b2f(h3v.z);
    acc.w += a0 * b2f(h0.w) + a1 * b2f(h1.w) + a2 * b2f(h2v.w) + a3 * b2f(h3v.w);
  }
  for (; i < end; ++i) {
    int s0 = __builtin_amdgcn_readfirstlane(csr[i]);
    float a0 = b2f(alph[i * 8 + hd2]);
    ushort4 h0 = *(const ushort4*)(h + ((unsigned)(s0 << 8) + l4));
    acc.x += a0 * b2f(h0.x);
    acc.y += a0 * b2f(h0.y);
    acc.z += a0 * b2f(h0.z);
    acc.w += a0 * b2f(h0.w);
  }
  float4 bv = *(const float4*)(b + l4);
  acc.x += bv.x; acc.y += bv.y; acc.z += bv.z; acc.w += bv.w;
  acc.x = acc.x > 0.f ? acc.x : expm1f(acc.x);
  acc.y = acc.y > 0.f ? acc.y : expm1f(acc.y);
  acc.z = acc.z > 0.f ? acc.z : expm1f(acc.z);
  acc.w = acc.w > 0.f ? acc.w : expm1f(acc.w);
  {
    ushort4 o;
    o.x = f2bu(acc.x); o.y = f2bu(acc.y); o.z = f2bu(acc.z); o.w = f2bu(acc.w);
    *(ushort4*)&xs[w * 256 + l4] = o;
  }
  __syncthreads();
  if (w == 0) {     // gemm2 phase: 16-node tile @ K=256 -> 32 ch + a_s/a_d
    const int nloc = lane & 15;
    const int node2 = n0 + nloc;
    const int ch_base = (lane >> 4) * 4;
    float sA = 0.f, sD = 0.f;
    #pragma unroll
    for (int mf = 0; mf < 2; ++mf) {
      f32x4 c2 = {0.f, 0.f, 0.f, 0.f};
      #pragma unroll
      for (int kk = 0; kk < 8; ++kk) {
        bf16x8 bfr = *(const bf16x8*)&xs[nloc * 256 + kk * 32 + (lane >> 4) * 8];
        c2 = __builtin_amdgcn_mfma_f32_16x16x32_bf16(W2f[(mf * 8 + kk) * 64 + lane],
                                                     bfr, c2, 0, 0, 0);
      }
      float4 av = *(const float4*)(as2 + mf * 16 + ch_base);
      float4 dv = *(const float4*)(ad2 + mf * 16 + ch_base);
      float ps = c2[0] * av.x + c2[1] * av.y + c2[2] * av.z + c2[3] * av.w;
      float pd = c2[0] * dv.x + c2[1] * dv.y + c2[2] * dv.z + c2[3] * dv.w;
      ps += __shfl_xor(ps, 16); ps += __shfl_xor(ps, 32);
      pd += __shfl_xor(pd, 16); pd += __shfl_xor(pd, 32);
      sA += ps; sD += pd;
      ushort4 o;
      o.x = f2bu(c2[0]); o.y = f2bu(c2[1]); o.z = f2bu(c2[2]); o.w = f2bu(c2[3]);
      *(ushort4*)&h2[(unsigned)(node2 * 32 + mf * 16 + ch_base)] = o;
    }
    if (lane < 16) { a_s[node2] = sA; a_d[node2] = sD; }
  }
}

// Layer-2: fused softmax + gather + bias + ELU + gemm3 (+layer-3 a_s/a_d
// epilogue into fresh buffers). 512 threads = 16 half-waves = 16 nodes/block.
__global__ __launch_bounds__(512) void k_gather2f(const int* __restrict__ rowptr,
                                                  const int* __restrict__ csr,
                                                  const float* __restrict__ a_s,
                                                  const float* __restrict__ a_d,
                                                  const unsigned short* __restrict__ h,
                                                  const float* __restrict__ b,
                                                  const bf16x8* __restrict__ W3f,
                                                  const float* __restrict__ as3,
                                                  const float* __restrict__ ad3,
                                                  unsigned short* __restrict__ h3,
                                                  float* __restrict__ a_s3,
                                                  float* __restrict__ a_d3) {
  __shared__ __align__(16) unsigned short xs[16 * 32];
  const int tid = threadIdx.x;
  const int hw = tid >> 5, lane32 = tid & 31;
  const int n0 = blockIdx.x * 16;
  const int node = n0 + hw;
  const int beg = rowptr[node], end = rowptr[node + 1];
  const float adv = a_d[node];

  float mx = -FNEG, sm = 0.f;
  for (int i = beg + lane32; i < end; i += 32) {
    float v = lrelu(a_s[csr[i]] + adv);
    float nm = fmaxf(mx, v);
    sm = sm * __expf(mx - nm) + __expf(v - nm);
    mx = nm;
  }
  #pragma unroll
  for (int off = 1; off < 32; off <<= 1) {
    float mo = __shfl_xor(mx, off, 32);
    float so = __shfl_xor(sm, off, 32);
    float nm = fmaxf(mx, mo);
    sm = sm * __expf(mx - nm) + so * __expf(mo - nm);
    mx = nm;
  }
  float rden = 1.0f / sm;

  float acc = 0.f;
  int i = beg;
  for (; i + 4 <= end; i += 4) {
    int s0 = csr[i], s1 = csr[i + 1], s2 = csr[i + 2], s3 = csr[i + 3];
    float a0 = __expf(lrelu(a_s[s0] + adv) - mx) * rden;
    float a1 = __expf(lrelu(a_s[s1] + adv) - mx) * rden;
    float a2 = __expf(lrelu(a_s[s2] + adv) - mx) * rden;
    float a3 = __expf(lrelu(a_s[s3] + adv) - mx) * rden;
    unsigned short v0 = h[(unsigned)(s0 * 32 + lane32)];
    unsigned short v1 = h[(unsigned)(s1 * 32 + lane32)];
    unsigned short v2 = h[(unsigned)(s2 * 32 + lane32)];
    unsigned short v3 = h[(unsigned)(s3 * 32 + lane32)];
    acc += a0 * b2f(v0) + a1 * b2f(v1) + a2 * b2f(v2) + a3 * b2f(v3);
  }
  for (; i < end; ++i) {
    int s0 = csr[i];
    float a0 = __expf(lrelu(a_s[s0] + adv) - mx) * rden;
    acc += a0 * b2f(h[(unsigned)(s0 * 32 + lane32)]);
  }
  acc += b[lane32];
  acc = acc > 0.f ? acc : expm1f(acc);
  xs[hw * 32 + lane32] = f2bu(acc);
  __syncthreads();
  if (tid < 64) {   // gemm3 phase: 16-node tile @ K=32 -> 40 ch + a_s/a_d
    const int lane = tid;
    const int nloc = lane & 15;
    const int node3 = n0 + nloc;
    const int ch_base = (lane >> 4) * 4;
    bf16x8 bfr = *(const bf16x8*)&xs[nloc * 32 + (lane >> 4) * 8];
    float sA = 0.f, sD = 0.f;
    #pragma unroll
    for (int mf = 0; mf < 3; ++mf) {
      f32x4 c3 = {0.f, 0.f, 0.f, 0.f};
      c3 = __builtin_amdgcn_mfma_f32_16x16x32_bf16(W3f[mf * 64 + lane], bfr, c3, 0, 0, 0);
      int ch0 = mf * 16 + ch_base;
      float4 av = {0.f, 0.f, 0.f, 0.f}, dv = {0.f, 0.f, 0.f, 0.f};
      if (ch0 < 40) {
        av = *(const float4*)(as3 + ch0);
        dv = *(const float4*)(ad3 + ch0);
      }
      float ps = c3[0] * av.x + c3[1] * av.y + c3[2] * av.z + c3[3] * av.w;
      float pd = c3[0] * dv.x + c3[1] * dv.y + c3[2] * dv.z + c3[3] * dv.w;
      ps += __shfl_xor(ps, 16); ps += __shfl_xor(ps, 32);
      pd += __shfl_xor(pd, 16); pd += __shfl_xor(pd, 32);
      sA += ps; sD += pd;
      if (ch0 < 40) {
        ushort4 o;
        o.x = f2bu(c3[0]); o.y = f2bu(c3[1]); o.z = f2bu(c3[2]); o.w = f2bu(c3[3]);
        *(ushort4*)&h3[(unsigned)(node3 * 40 + ch0)] = o;
      }
    }
    if (lane < 16) { a_s3[node3] = sA; a_d3[node3] = sD; }
  }
}

// Layer-3: fused softmax + gather + bias + log_softmax -> f32 out.
__global__ __launch_bounds__(256) void k_gather3f(const int* __restrict__ rowptr,
                                                  const int* __restrict__ csr,
                                                  const float* __restrict__ a_s,
                                                  const float* __restrict__ a_d,
                                                  const unsigned short* __restrict__ h,
                                                  const float* __restrict__ b,
                                                  float* __restrict__ out) {
  const int node = blockIdx.x * 4 + (threadIdx.x >> 6);
  const int lane = threadIdx.x & 63;
  const int beg = __builtin_amdgcn_readfirstlane(rowptr[node]);
  const int end = __builtin_amdgcn_readfirstlane(rowptr[node + 1]);
  const float adv = a_d[node];

  float mx = -FNEG, sm = 0.f;
  for (int i = beg + lane; i < end; i += 64) {
    float v = lrelu(a_s[csr[i]] + adv);
    float nm = fmaxf(mx, v);
    sm = sm * __expf(mx - nm) + __expf(v - nm);
    mx = nm;
  }
  #pragma unroll
  for (int off = 1; off < 64; off <<= 1) {
    float mo = __shfl_xor(mx, off);
    float so = __shfl_xor(sm, off);
    float nm = fmaxf(mx, mo);
    sm = sm * __expf(mx - nm) + so * __expf(mo - nm);
    mx = nm;
  }
  float rden = 1.0f / sm;

  float acc = 0.f;
  int i = beg;
  for (; i + 4 <= end; i += 4) {
    int s0 = __builtin_amdgcn_readfirstlane(csr[i]);
    int s1 = __builtin_amdgcn_readfirstlane(csr[i + 1]);
    int s2 = __builtin_amdgcn_readfirstlane(csr[i + 2]);
    int s3 = __builtin_amdgcn_readfirstlane(csr[i + 3]);
    float a0 = __expf(lrelu(a_s[s0] + adv) - mx) * rden;
    float a1 = __expf(lrelu(a_s[s1] + adv) - mx) * rden;
    float a2 = __expf(lrelu(a_s[s2] + adv) - mx) * rden;
    float a3 = __expf(lrelu(a_s[s3] + adv) - mx) * rden;
    if (lane < 40) {
      unsigned short v0 = h[(unsigned)(s0 * 40 + lane)];
      unsigned short v1 = h[(unsigned)(s1 * 40 + lane)];
      unsigned short v2 = h[(unsigned)(s2 * 40 + lane)];
      unsigned short v3 = h[(unsigned)(s3 * 40 + lane)];
      acc += a0 * b2f(v0) + a1 * b2f(v1) + a2 * b2f(v2) + a3 * b2f(v3);
    }
  }
  for (; i < end; ++i) {
    int s0 = __builtin_amdgcn_readfirstlane(csr[i]);
    float a0 = __expf(lrelu(a_s[s0] + adv) - mx) * rden;
    if (lane < 40) acc += a0 * b2f(h[(unsigned)(s0 * 40 + lane)]);
  }
  float v = (lane < 40) ? acc + b[lane] : -FNEG;
  float vmax = v;
  #pragma unroll
  for (int off = 1; off < 64; off <<= 1) vmax = fmaxf(vmax, __shfl_xor(vmax, off));
  float ex = (lane < 40) ? __expf(v - vmax) : 0.f;
  float es = ex;
  #pragma unroll
  for (int off = 1; off < 64; off <<= 1) es += __shfl_xor(es, off);
  float lse = vmax + __logf(es);
  if (lane < 40) out[(long long)node * 40 + lane] = v - lse;
}

extern "C" void kernel_launch(void* const* d_in, const int* in_sizes, int n_in,
                              void* d_out, int out_size, void* d_ws, size_t ws_size,
                              hipStream_t stream) {
  const float* x   = (const float*)d_in[0];
  const int*   eix = (const int*)d_in[1];
  const float* W1  = (const float*)d_in[2];
  const float* as1 = (const float*)d_in[3];
  const float* ad1 = (const float*)d_in[4];
  const float* b1  = (const float*)d_in[5];
  const float* W2  = (const float*)d_in[6];
  const float* as2 = (const float*)d_in[7];
  const float* ad2 = (const float*)d_in[8];
  const float* b2  = (const float*)d_in[9];
  const float* W3  = (const float*)d_in[10];
  const float* as3 = (const float*)d_in[11];
  const float* ad3 = (const float*)d_in[12];
  const float* b3  = (const float*)d_in[13];
  float* out = (float*)d_out;

  if (ws_size < WS_NEED) {
    k_sentinel<<<(out_size + 255) / 256, 256, 0, stream>>>(out, out_size);
    return;
  }

  char* ws = (char*)d_ws;
  int*    src    = (int*)(ws + SRC_OFF);
  int*    dst    = (int*)(ws + DST_OFF);
  int*    rowptr = (int*)(ws + RP_OFF);
  int*    csr    = (int*)(ws + CSR_OFF);
  unsigned short* W1f = (unsigned short*)(ws + W1F_OFF);
  unsigned short* W2f = (unsigned short*)(ws + W2F_OFF);
  unsigned short* W3f = (unsigned short*)(ws + W3F_OFF);
  int*    bsum   = (int*)(ws + SC_OFF);
  unsigned short* h1b  = (unsigned short*)(ws + H_OFF);
  unsigned short* h2b  = (unsigned short*)(ws + H2B_OFF);
  unsigned short* h3b  = (unsigned short*)(ws + H3B_OFF);
  unsigned short* alph = (unsigned short*)(ws + ALPH_OFF);
  float*  aS     = (float*)(ws + ASN_OFF);
  float*  aD     = (float*)(ws + ADN_OFF);
  float*  aS2    = (float*)(ws + AS2_OFF);
  float*  aD2    = (float*)(ws + AD2_OFF);
  int*    cnt8   = (int*)(ws + CNT8_OFF);
  int*    rank   = (int*)(ws + RANK_OFF);

  // ---- prep + CSR build (prep_edges overlapped with gemm1 in k_fatA) ----
  hipMemsetAsync(ws + CNT8_OFF, 0, 3200000, stream);
  k_prep_w<<<21, 256, 0, stream>>>(W1, W2, W3, W1f, W2f, W3f);
  k_fatA<<<FATA_NB, 256, 0, stream>>>(eix, src, dst, cnt8, rank, x,
                                      (const bf16x8*)W1f, as1, ad1, h1b, aS, aD);
  k_scan_a<<<NBSC, 1024, 0, stream>>>(cnt8, rowptr, bsum);
  k_scan_b<<<1, 128, 0, stream>>>(bsum);
  k_scan_c<<<NBSC, 1024, 0, stream>>>(rowptr, bsum);
  k_fill_nr<<<(FILL_CH + 255) / 256, 256, 0, stream>>>(src, dst, rank, cnt8,
                                                       rowptr, csr);

  // ---- layer 1: 128 -> 8x32 concat (gemm2 fused into gather) ----
  k_msalpha1<<<NN / 4, 256, 0, stream>>>(rowptr, csr, aS, aD, alph);
  k_gather1f<<<NN / 16, 1024, 0, stream>>>(rowptr, csr, alph, h1b, b1,
                                           (const bf16x8*)W2f, as2, ad2,
                                           h2b, aS, aD);

  // ---- layer 2: 256 -> 32 (softmax + gemm3 fused into gather) ----
  k_gather2f<<<NN / 16, 512, 0, stream>>>(rowptr, csr, aS, aD, h2b, b2,
                                          (const bf16x8*)W3f, as3, ad3,
                                          h3b, aS2, aD2);

  // ---- layer 3: 32 -> 40 (softmax fused into gather) ----
  k_gather3f<<<NN / 4, 256, 0, stream>>>(rowptr, csr, aS2, aD2, h3b, b3, out);
}

// Round 13
// 394.409 us; speedup vs baseline: 1.7192x; 1.1016x over previous
//
#include <hip/hip_runtime.h>

#define NN 100000
#define NE 1600000
#define ET 1700000        // NE + NN self-loops
#define NEG 0.2f
#define FNEG 3.4e38f
#define NBSC 98           // scan blocks: ceil(NN/1024)
#define GEMM1_NB 1563     // ceil(NN/64)
#define PE_NB 6641        // ceil(ET/256)
#define FATA_NB 8305      // 5 * 1661 covers 4:1 interleave of PE_NB:GEMM1_NB
#define FILL_CH 425000    // ET/4 (divisible by 8)

// ---------------- workspace layout (bytes) ----------------
#define SRC_OFF   0ULL
#define DST_OFF   6800000ULL
#define RP_OFF    13600000ULL         // rowptr (NN+1)*4
#define CSR_OFF   14400128ULL         // ET*4
#define W1F_OFF   21200128ULL         // 65536  (16mf x 4kk x 64lane x 8 bf16)
#define W2F_OFF   21265664ULL         // 16384
#define W3F_OFF   21282048ULL         // 3072
#define SC_OFF    21285120ULL         // 1024 (block sums)
#define H_OFF     21286144ULL         // h1 as fp8 e4m3: N*256 = 25.6MB
#define H2B_OFF   72486144ULL         // h2b 6.4MB (bf16)
#define H3B_OFF   88486144ULL         // h3b 8MB (bf16)
#define ALPH_OFF  123686144ULL        // alpha (layer1 only): ET*8*2 = 27.2MB
#define ASN_OFF   150886144ULL        // layer-2 a_s: 3.2MB
#define ADN_OFF   154086144ULL        // layer-2 a_d: 3.2MB
#define AS2_OFF   157286144ULL        // layer-3 a_s: 400KB
#define AD2_OFF   157686144ULL        // layer-3 a_d: 400KB
#define CNT8_OFF  158086144ULL        // replicated histogram 8*NN*4 = 3.2MB
#define RANK_OFF  161286144ULL        // per-edge rank within replica: ET*4
#define WS_NEED   168086144ULL

typedef short bf16x8 __attribute__((ext_vector_type(8)));
typedef float f32x4 __attribute__((ext_vector_type(4)));
typedef float f32x2 __attribute__((ext_vector_type(2)));

__device__ __forceinline__ float lrelu(float x) { return x > 0.f ? x : NEG * x; }
__device__ __forceinline__ float b2f(unsigned short u) {
  return __uint_as_float(((unsigned)u) << 16);
}
__device__ __forceinline__ unsigned short f2bu(float f) {   // RNE f32->bf16
  unsigned u = __float_as_uint(f);
  return (unsigned short)((u + 0x7FFFu + ((u >> 16) & 1u)) >> 16);
}

__global__ __launch_bounds__(256) void k_sentinel(float* out, int n) {
  int i = blockIdx.x * 256 + threadIdx.x;
  if (i < n) out[i] = 12345.0f;
}

// Pre-arrange W1/W2/W3 (f32) into MFMA A-fragment order as bf16.
__global__ __launch_bounds__(256) void k_prep_w(const float* __restrict__ W1,
                                                const float* __restrict__ W2,
                                                const float* __restrict__ W3,
                                                unsigned short* __restrict__ W1f,
                                                unsigned short* __restrict__ W2f,
                                                unsigned short* __restrict__ W3f) {
  int idx = blockIdx.x * 256 + threadIdx.x;
  if (idx < 4096) {                       // W1: 16 mf x 4 kk
    int fg = idx >> 6, lane = idx & 63;
    int mf = fg >> 2, kk = fg & 3;
    int c = mf * 16 + (lane & 15), k0 = kk * 32 + (lane >> 4) * 8;
    unsigned short* o = W1f + idx * 8;
    #pragma unroll
    for (int j = 0; j < 8; ++j) o[j] = f2bu(W1[(k0 + j) * 256 + c]);
  } else if (idx < 5120) {                // W2: 2 mf x 8 kk
    int t = idx - 4096;
    int fg = t >> 6, lane = t & 63;
    int mf = fg >> 3, kk = fg & 7;
    int c = mf * 16 + (lane & 15), k0 = kk * 32 + (lane >> 4) * 8;
    unsigned short* o = W2f + t * 8;
    #pragma unroll
    for (int j = 0; j < 8; ++j) o[j] = f2bu(W2[(k0 + j) * 32 + c]);
  } else if (idx < 5312) {                // W3: 3 mf x 1 kk (pad ch>=40 with 0)
    int t = idx - 5120;
    int mf = t >> 6, lane = t & 63;
    int c = mf * 16 + (lane & 15), k0 = (lane >> 4) * 8;
    unsigned short* o = W3f + t * 8;
    #pragma unroll
    for (int j = 0; j < 8; ++j) o[j] = (c < 40) ? f2bu(W3[(k0 + j) * 40 + c]) : 0;
  }
}

// Fat kernel A: prep_edges (+replicated deg count, rank capture) interleaved
// 4:1 with gemm1 (h1 = x@W1 -> fp8 e4m3 + fused a_s/a_d epilogue in f32).
__global__ __launch_bounds__(256) void k_fatA(const int* __restrict__ raw,
                                              int* __restrict__ src,
                                              int* __restrict__ dst,
                                              int* __restrict__ cnt8,
                                              int* __restrict__ rank,
                                              const float* __restrict__ x,
                                              const bf16x8* __restrict__ W1f,
                                              const float* __restrict__ as1,
                                              const float* __restrict__ ad1,
                                              unsigned char* __restrict__ h8,
                                              float* __restrict__ a_s,
                                              float* __restrict__ a_d) {
  __shared__ __align__(16) unsigned short xs[64 * 128];
  __shared__ float asL[256], adL[256];
  const int bid = blockIdx.x;
  const int grp = bid / 5, rem = bid - grp * 5;
  const int tid = threadIdx.x;

  if (rem != 4) {                               // ---- prep_edges ----
    int pe = grp * 4 + rem;
    if (pe >= PE_NB) return;
    bool is64 = true;
    #pragma unroll
    for (int i = 1; i < 32; i += 2) is64 = is64 && (raw[i] == 0);
    long long e = (long long)pe * 256 + tid;
    if (e >= ET) return;
    int s, d;
    if (e < NE) {
      if (is64) {
        const long long* r = (const long long*)raw;
        s = (int)r[e];
        d = (int)r[NE + e];
      } else {
        s = raw[e];
        d = raw[NE + e];
      }
    } else {
      s = d = (int)(e - NE);
    }
    src[e] = s;
    dst[e] = d;
    rank[e] = atomicAdd(&cnt8[(tid & 7) * NN + d], 1);
    return;
  }

  // ---- gemm1 ----
  if (grp >= GEMM1_NB) return;
  const int n0 = grp * 64;
  asL[tid] = as1[tid];
  adL[tid] = ad1[tid];
  for (int j = tid; j < 2048; j += 256) {       // stage x -> bf16 LDS
    int r = j >> 5;
    int c4 = (j & 31) << 2;
    long long row = n0 + r; if (row >= NN) row = NN - 1;
    float4 v = *(const float4*)(x + row * 128 + c4);
    unsigned short* p = &xs[r * 128 + c4];
    p[0] = f2bu(v.x); p[1] = f2bu(v.y); p[2] = f2bu(v.z); p[3] = f2bu(v.w);
  }
  __syncthreads();
  const int w = tid >> 6, lane = tid & 63;
  const int nloc = w * 16 + (lane & 15);
  const int node = n0 + nloc;
  bf16x8 bfr[4];
  #pragma unroll
  for (int kk = 0; kk < 4; ++kk)
    bfr[kk] = *(const bf16x8*)&xs[nloc * 128 + kk * 32 + (lane >> 4) * 8];
  const int ch_base = (lane >> 4) * 4;
  float sA[8] = {}, sD[8] = {};
  #pragma unroll
  for (int mf = 0; mf < 16; ++mf) {
    f32x4 acc = {0.f, 0.f, 0.f, 0.f};
    #pragma unroll
    for (int kk = 0; kk < 4; ++kk) {
      bf16x8 af = W1f[(mf * 4 + kk) * 64 + lane];
      acc = __builtin_amdgcn_mfma_f32_16x16x32_bf16(af, bfr[kk], acc, 0, 0, 0);
    }
    const float* av = &asL[mf * 16 + ch_base];
    const float* dv = &adL[mf * 16 + ch_base];
    float ps = acc[0] * av[0] + acc[1] * av[1] + acc[2] * av[2] + acc[3] * av[3];
    float pd = acc[0] * dv[0] + acc[1] * dv[1] + acc[2] * dv[2] + acc[3] * dv[3];
    ps += __shfl_xor(ps, 16); ps += __shfl_xor(ps, 32);
    pd += __shfl_xor(pd, 16); pd += __shfl_xor(pd, 32);
    sA[mf >> 1] += ps; sD[mf >> 1] += pd;
    if (node < NN) {
      // pack 4 channels to fp8 e4m3 (OCP on gfx950) via HW converts
      int w01 = __builtin_amdgcn_cvt_pk_fp8_f32(acc[0], acc[1], 0, false);
      int w0123 = __builtin_amdgcn_cvt_pk_fp8_f32(acc[2], acc[3], w01, true);
      *(unsigned*)&h8[(unsigned)(node * 256 + mf * 16 + ch_base)] = (unsigned)w0123;
    }
  }
  if (lane < 16 && node < NN) {
    #pragma unroll
    for (int hd = 0; hd < 8; ++hd) {
      a_s[node * 8 + hd] = sA[hd];
      a_d[node * 8 + hd] = sD[hd];
    }
  }
}

// Block-level inclusive scan over node degrees, folding the 8 replicas.
__global__ __launch_bounds__(1024) void k_scan_a(int* __restrict__ cnt8,
                                                 int* __restrict__ rowptr,
                                                 int* __restrict__ bsum) {
  __shared__ int wsum[16];
  const int lane = threadIdx.x & 63, wid = threadIdx.x >> 6;
  int i = blockIdx.x * 1024 + threadIdx.x;
  int x = 0;
  if (i < NN) {
    int run = 0;
    #pragma unroll
    for (int k = 0; k < 8; ++k) {
      int c = cnt8[k * NN + i];
      cnt8[k * NN + i] = run;
      run += c;
    }
    x = run;
  }
  int inc = x;
  #pragma unroll
  for (int off = 1; off < 64; off <<= 1) {
    int t = __shfl_up(inc, off);
    if (lane >= off) inc += t;
  }
  if (lane == 63) wsum[wid] = inc;
  __syncthreads();
  if (wid == 0) {
    int w = (lane < 16) ? wsum[lane] : 0;
    #pragma unroll
    for (int off = 1; off < 16; off <<= 1) {
      int t = __shfl_up(w, off);
      if (lane >= off) w += t;
    }
    if (lane < 16) wsum[lane] = w;
  }
  __syncthreads();
  int base = wid ? wsum[wid - 1] : 0;
  if (i < NN) rowptr[i + 1] = base + inc;
  if (threadIdx.x == 1023) bsum[blockIdx.x] = base + inc;
}

// Exclusive scan of NBSC block sums (in place).
__global__ __launch_bounds__(128) void k_scan_b(int* __restrict__ bsum) {
  __shared__ int w0tot;
  int tid = threadIdx.x;
  int v = (tid < NBSC) ? bsum[tid] : 0;
  int inc = v;
  #pragma unroll
  for (int off = 1; off < 64; off <<= 1) {
    int t = __shfl_up(inc, off);
    if ((tid & 63) >= off) inc += t;
  }
  if (tid == 63) w0tot = inc;
  __syncthreads();
  if (tid >= 64) inc += w0tot;
  if (tid < NBSC) bsum[tid] = inc - v;
}

__global__ __launch_bounds__(1024) void k_scan_c(int* __restrict__ rowptr,
                                                 const int* __restrict__ bsum) {
  int i = blockIdx.x * 1024 + threadIdx.x;
  if (i < NN) rowptr[i + 1] += bsum[blockIdx.x];
  if (i == 0) rowptr[0] = 0;
}

// Atomic-free CSR fill: slot = rowptr[d] + prefix8[e&7][d] + rank[e].
__global__ __launch_bounds__(256) void k_fill_nr(const int* __restrict__ src,
                                                 const int* __restrict__ dst,
                                                 const int* __restrict__ rank,
                                                 const int* __restrict__ cnt8,
                                                 const int* __restrict__ rowptr,
                                                 int* __restrict__ csr) {
  int gid = blockIdx.x * 256 + threadIdx.x;
  if (gid >= FILL_CH) return;
  const int h = gid & 7;
  int e0 = gid, e1 = gid + FILL_CH, e2 = gid + 2 * FILL_CH, e3 = gid + 3 * FILL_CH;
  int d0 = dst[e0], d1 = dst[e1], d2 = dst[e2], d3 = dst[e3];
  int r0 = rank[e0], r1 = rank[e1], r2 = rank[e2], r3 = rank[e3];
  int s0 = src[e0], s1 = src[e1], s2 = src[e2], s3 = src[e3];
  int p0 = cnt8[h * NN + d0], p1 = cnt8[h * NN + d1];
  int p2 = cnt8[h * NN + d2], p3 = cnt8[h * NN + d3];
  int b0 = rowptr[d0], b1 = rowptr[d1], b2 = rowptr[d2], b3 = rowptr[d3];
  csr[b0 + p0 + r0] = s0;
  csr[b1 + p1 + r1] = s1;
  csr[b2 + p2 + r2] = s2;
  csr[b3 + p3 + r3] = s3;
}

// Layer-1 softmax: per-node max/sum + write alpha[ET][8] bf16. Wave per node.
__global__ __launch_bounds__(256) void k_msalpha1(const int* __restrict__ rowptr,
                                                  const int* __restrict__ csr,
                                                  const float* __restrict__ a_s,
                                                  const float* __restrict__ a_d,
                                                  unsigned short* __restrict__ alph) {
  const int node = blockIdx.x * 4 + (threadIdx.x >> 6);
  const int lane = threadIdx.x & 63;
  const int beg = __builtin_amdgcn_readfirstlane(rowptr[node]);
  const int end = __builtin_amdgcn_readfirstlane(rowptr[node + 1]);
  const int hd = lane & 7;
  const int eg = lane >> 3;
  const float adv = a_d[node * 8 + hd];
  float mx = -FNEG, sm = 0.f;
  if (end - beg <= 32) {
    float vc0 = 0.f, vc1 = 0.f, vc2 = 0.f, vc3 = 0.f;
    #pragma unroll
    for (int k = 0; k < 4; ++k) {
      int i = beg + eg + k * 8;
      if (i < end) {
        float v = lrelu(a_s[csr[i] * 8 + hd] + adv);
        if (k == 0) vc0 = v; else if (k == 1) vc1 = v;
        else if (k == 2) vc2 = v; else vc3 = v;
        float nm = fmaxf(mx, v);
        sm = sm * __expf(mx - nm) + __expf(v - nm);
        mx = nm;
      }
    }
    #pragma unroll
    for (int off = 8; off < 64; off <<= 1) {
      float mo = __shfl_xor(mx, off);
      float so = __shfl_xor(sm, off);
      float nm = fmaxf(mx, mo);
      sm = sm * __expf(mx - nm) + so * __expf(mo - nm);
      mx = nm;
    }
    float rden = 1.0f / sm;
    #pragma unroll
    for (int k = 0; k < 4; ++k) {
      int i = beg + eg + k * 8;
      if (i < end) {
        float v = (k == 0) ? vc0 : (k == 1) ? vc1 : (k == 2) ? vc2 : vc3;
        alph[i * 8 + hd] = f2bu(__expf(v - mx) * rden);
      }
    }
  } else {
    for (int i = beg + eg; i < end; i += 8) {
      int s = csr[i];
      float v = lrelu(a_s[s * 8 + hd] + adv);
      float nm = fmaxf(mx, v);
      sm = sm * __expf(mx - nm) + __expf(v - nm);
      mx = nm;
    }
    #pragma unroll
    for (int off = 8; off < 64; off <<= 1) {
      float mo = __shfl_xor(mx, off);
      float so = __shfl_xor(sm, off);
      float nm = fmaxf(mx, mo);
      sm = sm * __expf(mx - nm) + so * __expf(mo - nm);
      mx = nm;
    }
    float rden = 1.0f / sm;
    for (int i = beg + eg; i < end; i += 8) {
      int s = csr[i];
      float v = lrelu(a_s[s * 8 + hd] + adv);
      alph[i * 8 + hd] = f2bu(__expf(v - mx) * rden);
    }
  }
}

// Layer-1 gather (fp8 h) + bias+ELU fused with gemm2 (+layer-2 a_s/a_d).
// 1024 threads = 16 waves = 16 nodes/block. Scalarized csr/rowptr, 32-bit
// byte indexing, 8-deep MLP, HW fp8->f32 packed converts.
__global__ __launch_bounds__(1024) void k_gather1f(const int* __restrict__ rowptr,
                                                   const int* __restrict__ csr,
                                                   const unsigned short* __restrict__ alph,
                                                   const unsigned char* __restrict__ h8,
                                                   const float* __restrict__ b,
                                                   const bf16x8* __restrict__ W2f,
                                                   const float* __restrict__ as2,
                                                   const float* __restrict__ ad2,
                                                   unsigned short* __restrict__ h2,
                                                   float* __restrict__ a_s,
                                                   float* __restrict__ a_d) {
  __shared__ __align__(16) unsigned short xs[16 * 256];
  const int tid = threadIdx.x;
  const int w = tid >> 6, lane = tid & 63;
  const int n0 = blockIdx.x * 16;
  const int node = n0 + w;
  const int beg = __builtin_amdgcn_readfirstlane(rowptr[node]);
  const int end = __builtin_amdgcn_readfirstlane(rowptr[node + 1]);
  const int hd2 = lane >> 3;
  const unsigned l4 = lane * 4;
  float4 acc = {0.f, 0.f, 0.f, 0.f};
  int i = beg;
  for (; i + 8 <= end; i += 8) {
    int s0 = __builtin_amdgcn_readfirstlane(csr[i]);
    int s1 = __builtin_amdgcn_readfirstlane(csr[i + 1]);
    int s2 = __builtin_amdgcn_readfirstlane(csr[i + 2]);
    int s3 = __builtin_amdgcn_readfirstlane(csr[i + 3]);
    int s4 = __builtin_amdgcn_readfirstlane(csr[i + 4]);
    int s5 = __builtin_amdgcn_readfirstlane(csr[i + 5]);
    int s6 = __builtin_amdgcn_readfirstlane(csr[i + 6]);
    int s7 = __builtin_amdgcn_readfirstlane(csr[i + 7]);
    float a0 = b2f(alph[(i + 0) * 8 + hd2]);
    float a1 = b2f(alph[(i + 1) * 8 + hd2]);
    float a2 = b2f(alph[(i + 2) * 8 + hd2]);
    float a3 = b2f(alph[(i + 3) * 8 + hd2]);
    float a4 = b2f(alph[(i + 4) * 8 + hd2]);
    float a5 = b2f(alph[(i + 5) * 8 + hd2]);
    float a6 = b2f(alph[(i + 6) * 8 + hd2]);
    float a7 = b2f(alph[(i + 7) * 8 + hd2]);
    unsigned w0 = *(const unsigned*)(h8 + ((unsigned)(s0 << 8) + l4));
    unsigned w1 = *(const unsigned*)(h8 + ((unsigned)(s1 << 8) + l4));
    unsigned w2 = *(const unsigned*)(h8 + ((unsigned)(s2 << 8) + l4));
    unsigned w3 = *(const unsigned*)(h8 + ((unsigned)(s3 << 8) + l4));
    unsigned w4 = *(const unsigned*)(h8 + ((unsigned)(s4 << 8) + l4));
    unsigned w5 = *(const unsigned*)(h8 + ((unsigned)(s5 << 8) + l4));
    unsigned w6 = *(const unsigned*)(h8 + ((unsigned)(s6 << 8) + l4));
    unsigned w7 = *(const unsigned*)(h8 + ((unsigned)(s7 << 8) + l4));
    f32x2 lo, hi;
    lo = __builtin_amdgcn_cvt_pk_f32_fp8(w0, false); hi = __builtin_amdgcn_cvt_pk_f32_fp8(w0, true);
    acc.x += a0 * lo[0]; acc.y += a0 * lo[1]; acc.z += a0 * hi[0]; acc.w += a0 * hi[1];
    lo = __builtin_amdgcn_cvt_pk_f32_fp8(w1, false); hi = __builtin_amdgcn_cvt_pk_f32_fp8(w1, true);
    acc.x += a1 * lo[0]; acc.y += a1 * lo[1]; acc.z += a1 * hi[0]; acc.w += a1 * hi[1];
    lo = __builtin_amdgcn_cvt_pk_f32_fp8(w2, false); hi = __builtin_amdgcn_cvt_pk_f32_fp8(w2, true);
    acc.x += a2 * lo[0]; acc.y += a2 * lo[1]; acc.z += a2 * hi[0]; acc.w += a2 * hi[1];
    lo = __builtin_amdgcn_cvt_pk_f32_fp8(w3, false); hi = __builtin_amdgcn_cvt_pk_f32_fp8(w3, true);
    acc.x += a3 * lo[0]; acc.y += a3 * lo[1]; acc.z += a3 * hi[0]; acc.w += a3 * hi[1];
    lo = __builtin_amdgcn_cvt_pk_f32_fp8(w4, false); hi = __builtin_amdgcn_cvt_pk_f32_fp8(w4, true);
    acc.x += a4 * lo[0]; acc.y += a4 * lo[1]; acc.z += a4 * hi[0]; acc.w += a4 * hi[1];
    lo = __builtin_amdgcn_cvt_pk_f32_fp8(w5, false); hi = __builtin_amdgcn_cvt_pk_f32_fp8(w5, true);
    acc.x += a5 * lo[0]; acc.y += a5 * lo[1]; acc.z += a5 * hi[0]; acc.w += a5 * hi[1];
    lo = __builtin_amdgcn_cvt_pk_f32_fp8(w6, false); hi = __builtin_amdgcn_cvt_pk_f32_fp8(w6, true);
    acc.x += a6 * lo[0]; acc.y += a6 * lo[1]; acc.z += a6 * hi[0]; acc.w += a6 * hi[1];
    lo = __builtin_amdgcn_cvt_pk_f32_fp8(w7, false); hi = __builtin_amdgcn_cvt_pk_f32_fp8(w7, true);
    acc.x += a7 * lo[0]; acc.y += a7 * lo[1]; acc.z += a7 * hi[0]; acc.w += a7 * hi[1];
  }
  for (; i < end; ++i) {
    int s0 = __builtin_amdgcn_readfirstlane(csr[i]);
    float a0 = b2f(alph[i * 8 + hd2]);
    unsigned w0 = *(const unsigned*)(h8 + ((unsigned)(s0 << 8) + l4));
    f32x2 lo = __builtin_amdgcn_cvt_pk_f32_fp8(w0, false);
    f32x2 hi = __builtin_amdgcn_cvt_pk_f32_fp8(w0, true);
    acc.x += a0 * lo[0]; acc.y += a0 * lo[1]; acc.z += a0 * hi[0]; acc.w += a0 * hi[1];
  }
  float4 bv = *(const float4*)(b + l4);
  acc.x += bv.x; acc.y += bv.y; acc.z += bv.z; acc.w += bv.w;
  acc.x = acc.x > 0.f ? acc.x : expm1f(acc.x);
  acc.y = acc.y > 0.f ? acc.y : expm1f(acc.y);
  acc.z = acc.z > 0.f ? acc.z : expm1f(acc.z);
  acc.w = acc.w > 0.f ? acc.w : expm1f(acc.w);
  {
    ushort4 o;
    o.x = f2bu(acc.x); o.y = f2bu(acc.y); o.z = f2bu(acc.z); o.w = f2bu(acc.w);
    *(ushort4*)&xs[w * 256 + l4] = o;
  }
  __syncthreads();
  if (w == 0) {     // gemm2 phase: 16-node tile @ K=256 -> 32 ch + a_s/a_d
    const int nloc = lane & 15;
    const int node2 = n0 + nloc;
    const int ch_base = (lane >> 4) * 4;
    float sA = 0.f, sD = 0.f;
    #pragma unroll
    for (int mf = 0; mf < 2; ++mf) {
      f32x4 c2 = {0.f, 0.f, 0.f, 0.f};
      #pragma unroll
      for (int kk = 0; kk < 8; ++kk) {
        bf16x8 bfr = *(const bf16x8*)&xs[nloc * 256 + kk * 32 + (lane >> 4) * 8];
        c2 = __builtin_amdgcn_mfma_f32_16x16x32_bf16(W2f[(mf * 8 + kk) * 64 + lane],
                                                     bfr, c2, 0, 0, 0);
      }
      float4 av = *(const float4*)(as2 + mf * 16 + ch_base);
      float4 dv = *(const float4*)(ad2 + mf * 16 + ch_base);
      float ps = c2[0] * av.x + c2[1] * av.y + c2[2] * av.z + c2[3] * av.w;
      float pd = c2[0] * dv.x + c2[1] * dv.y + c2[2] * dv.z + c2[3] * dv.w;
      ps += __shfl_xor(ps, 16); ps += __shfl_xor(ps, 32);
      pd += __shfl_xor(pd, 16); pd += __shfl_xor(pd, 32);
      sA += ps; sD += pd;
      ushort4 o;
      o.x = f2bu(c2[0]); o.y = f2bu(c2[1]); o.z = f2bu(c2[2]); o.w = f2bu(c2[3]);
      *(ushort4*)&h2[(unsigned)(node2 * 32 + mf * 16 + ch_base)] = o;
    }
    if (lane < 16) { a_s[node2] = sA; a_d[node2] = sD; }
  }
}

// Layer-2: fused softmax + gather + bias + ELU + gemm3 (+layer-3 a_s/a_d
// epilogue into fresh buffers). 512 threads = 16 half-waves = 16 nodes/block.
__global__ __launch_bounds__(512) void k_gather2f(const int* __restrict__ rowptr,
                                                  const int* __restrict__ csr,
                                                  const float* __restrict__ a_s,
                                                  const float* __restrict__ a_d,
                                                  const unsigned short* __restrict__ h,
                                                  const float* __restrict__ b,
                                                  const bf16x8* __restrict__ W3f,
                                                  const float* __restrict__ as3,
                                                  const float* __restrict__ ad3,
                                                  unsigned short* __restrict__ h3,
                                                  float* __restrict__ a_s3,
                                                  float* __restrict__ a_d3) {
  __shared__ __align__(16) unsigned short xs[16 * 32];
  const int tid = threadIdx.x;
  const int hw = tid >> 5, lane32 = tid & 31;
  const int n0 = blockIdx.x * 16;
  const int node = n0 + hw;
  const int beg = rowptr[node], end = rowptr[node + 1];
  const float adv = a_d[node];

  float mx = -FNEG, sm = 0.f;
  for (int i = beg + lane32; i < end; i += 32) {
    float v = lrelu(a_s[csr[i]] + adv);
    float nm = fmaxf(mx, v);
    sm = sm * __expf(mx - nm) + __expf(v - nm);
    mx = nm;
  }
  #pragma unroll
  for (int off = 1; off < 32; off <<= 1) {
    float mo = __shfl_xor(mx, off, 32);
    float so = __shfl_xor(sm, off, 32);
    float nm = fmaxf(mx, mo);
    sm = sm * __expf(mx - nm) + so * __expf(mo - nm);
    mx = nm;
  }
  float rden = 1.0f / sm;

  float acc = 0.f;
  int i = beg;
  for (; i + 4 <= end; i += 4) {
    int s0 = csr[i], s1 = csr[i + 1], s2 = csr[i + 2], s3 = csr[i + 3];
    float a0 = __expf(lrelu(a_s[s0] + adv) - mx) * rden;
    float a1 = __expf(lrelu(a_s[s1] + adv) - mx) * rden;
    float a2 = __expf(lrelu(a_s[s2] + adv) - mx) * rden;
    float a3 = __expf(lrelu(a_s[s3] + adv) - mx) * rden;
    unsigned short v0 = h[(unsigned)(s0 * 32 + lane32)];
    unsigned short v1 = h[(unsigned)(s1 * 32 + lane32)];
    unsigned short v2 = h[(unsigned)(s2 * 32 + lane32)];
    unsigned short v3 = h[(unsigned)(s3 * 32 + lane32)];
    acc += a0 * b2f(v0) + a1 * b2f(v1) + a2 * b2f(v2) + a3 * b2f(v3);
  }
  for (; i < end; ++i) {
    int s0 = csr[i];
    float a0 = __expf(lrelu(a_s[s0] + adv) - mx) * rden;
    acc += a0 * b2f(h[(unsigned)(s0 * 32 + lane32)]);
  }
  acc += b[lane32];
  acc = acc > 0.f ? acc : expm1f(acc);
  xs[hw * 32 + lane32] = f2bu(acc);
  __syncthreads();
  if (tid < 64) {   // gemm3 phase: 16-node tile @ K=32 -> 40 ch + a_s/a_d
    const int lane = tid;
    const int nloc = lane & 15;
    const int node3 = n0 + nloc;
    const int ch_base = (lane >> 4) * 4;
    bf16x8 bfr = *(const bf16x8*)&xs[nloc * 32 + (lane >> 4) * 8];
    float sA = 0.f, sD = 0.f;
    #pragma unroll
    for (int mf = 0; mf < 3; ++mf) {
      f32x4 c3 = {0.f, 0.f, 0.f, 0.f};
      c3 = __builtin_amdgcn_mfma_f32_16x16x32_bf16(W3f[mf * 64 + lane], bfr, c3, 0, 0, 0);
      int ch0 = mf * 16 + ch_base;
      float4 av = {0.f, 0.f, 0.f, 0.f}, dv = {0.f, 0.f, 0.f, 0.f};
      if (ch0 < 40) {
        av = *(const float4*)(as3 + ch0);
        dv = *(const float4*)(ad3 + ch0);
      }
      float ps = c3[0] * av.x + c3[1] * av.y + c3[2] * av.z + c3[3] * av.w;
      float pd = c3[0] * dv.x + c3[1] * dv.y + c3[2] * dv.z + c3[3] * dv.w;
      ps += __shfl_xor(ps, 16); ps += __shfl_xor(ps, 32);
      pd += __shfl_xor(pd, 16); pd += __shfl_xor(pd, 32);
      sA += ps; sD += pd;
      if (ch0 < 40) {
        ushort4 o;
        o.x = f2bu(c3[0]); o.y = f2bu(c3[1]); o.z = f2bu(c3[2]); o.w = f2bu(c3[3]);
        *(ushort4*)&h3[(unsigned)(node3 * 40 + ch0)] = o;
      }
    }
    if (lane < 16) { a_s3[node3] = sA; a_d3[node3] = sD; }
  }
}

// Layer-3: fused softmax + gather + bias + log_softmax -> f32 out.
__global__ __launch_bounds__(256) void k_gather3f(const int* __restrict__ rowptr,
                                                  const int* __restrict__ csr,
                                                  const float* __restrict__ a_s,
                                                  const float* __restrict__ a_d,
                                                  const unsigned short* __restrict__ h,
                                                  const float* __restrict__ b,
                                                  float* __restrict__ out) {
  const int node = blockIdx.x * 4 + (threadIdx.x >> 6);
  const int lane = threadIdx.x & 63;
  const int beg = __builtin_amdgcn_readfirstlane(rowptr[node]);
  const int end = __builtin_amdgcn_readfirstlane(rowptr[node + 1]);
  const float adv = a_d[node];

  float mx = -FNEG, sm = 0.f;
  for (int i = beg + lane; i < end; i += 64) {
    float v = lrelu(a_s[csr[i]] + adv);
    float nm = fmaxf(mx, v);
    sm = sm * __expf(mx - nm) + __expf(v - nm);
    mx = nm;
  }
  #pragma unroll
  for (int off = 1; off < 64; off <<= 1) {
    float mo = __shfl_xor(mx, off);
    float so = __shfl_xor(sm, off);
    float nm = fmaxf(mx, mo);
    sm = sm * __expf(mx - nm) + so * __expf(mo - nm);
    mx = nm;
  }
  float rden = 1.0f / sm;

  float acc = 0.f;
  int i = beg;
  for (; i + 4 <= end; i += 4) {
    int s0 = __builtin_amdgcn_readfirstlane(csr[i]);
    int s1 = __builtin_amdgcn_readfirstlane(csr[i + 1]);
    int s2 = __builtin_amdgcn_readfirstlane(csr[i + 2]);
    int s3 = __builtin_amdgcn_readfirstlane(csr[i + 3]);
    float a0 = __expf(lrelu(a_s[s0] + adv) - mx) * rden;
    float a1 = __expf(lrelu(a_s[s1] + adv) - mx) * rden;
    float a2 = __expf(lrelu(a_s[s2] + adv) - mx) * rden;
    float a3 = __expf(lrelu(a_s[s3] + adv) - mx) * rden;
    if (lane < 40) {
      unsigned short v0 = h[(unsigned)(s0 * 40 + lane)];
      unsigned short v1 = h[(unsigned)(s1 * 40 + lane)];
      unsigned short v2 = h[(unsigned)(s2 * 40 + lane)];
      unsigned short v3 = h[(unsigned)(s3 * 40 + lane)];
      acc += a0 * b2f(v0) + a1 * b2f(v1) + a2 * b2f(v2) + a3 * b2f(v3);
    }
  }
  for (; i < end; ++i) {
    int s0 = __builtin_amdgcn_readfirstlane(csr[i]);
    float a0 = __expf(lrelu(a_s[s0] + adv) - mx) * rden;
    if (lane < 40) acc += a0 * b2f(h[(unsigned)(s0 * 40 + lane)]);
  }
  float v = (lane < 40) ? acc + b[lane] : -FNEG;
  float vmax = v;
  #pragma unroll
  for (int off = 1; off < 64; off <<= 1) vmax = fmaxf(vmax, __shfl_xor(vmax, off));
  float ex = (lane < 40) ? __expf(v - vmax) : 0.f;
  float es = ex;
  #pragma unroll
  for (int off = 1; off < 64; off <<= 1) es += __shfl_xor(es, off);
  float lse = vmax + __logf(es);
  if (lane < 40) out[(long long)node * 40 + lane] = v - lse;
}

extern "C" void kernel_launch(void* const* d_in, const int* in_sizes, int n_in,
                              void* d_out, int out_size, void* d_ws, size_t ws_size,
                              hipStream_t stream) {
  const float* x   = (const float*)d_in[0];
  const int*   eix = (const int*)d_in[1];
  const float* W1  = (const float*)d_in[2];
  const float* as1 = (const float*)d_in[3];
  const float* ad1 = (const float*)d_in[4];
  const float* b1  = (const float*)d_in[5];
  const float* W2  = (const float*)d_in[6];
  const float* as2 = (const float*)d_in[7];
  const float* ad2 = (const float*)d_in[8];
  const float* b2  = (const float*)d_in[9];
  const float* W3  = (const float*)d_in[10];
  const float* as3 = (const float*)d_in[11];
  const float* ad3 = (const float*)d_in[12];
  const float* b3  = (const float*)d_in[13];
  float* out = (float*)d_out;

  if (ws_size < WS_NEED) {
    k_sentinel<<<(out_size + 255) / 256, 256, 0, stream>>>(out, out_size);
    return;
  }

  char* ws = (char*)d_ws;
  int*    src    = (int*)(ws + SRC_OFF);
  int*    dst    = (int*)(ws + DST_OFF);
  int*    rowptr = (int*)(ws + RP_OFF);
  int*    csr    = (int*)(ws + CSR_OFF);
  unsigned short* W1f = (unsigned short*)(ws + W1F_OFF);
  unsigned short* W2f = (unsigned short*)(ws + W2F_OFF);
  unsigned short* W3f = (unsigned short*)(ws + W3F_OFF);
  int*    bsum   = (int*)(ws + SC_OFF);
  unsigned char*  h1q  = (unsigned char*)(ws + H_OFF);
  unsigned short* h2b  = (unsigned short*)(ws + H2B_OFF);
  unsigned short* h3b  = (unsigned short*)(ws + H3B_OFF);
  unsigned short* alph = (unsigned short*)(ws + ALPH_OFF);
  float*  aS     = (float*)(ws + ASN_OFF);
  float*  aD     = (float*)(ws + ADN_OFF);
  float*  aS2    = (float*)(ws + AS2_OFF);
  float*  aD2    = (float*)(ws + AD2_OFF);
  int*    cnt8   = (int*)(ws + CNT8_OFF);
  int*    rank   = (int*)(ws + RANK_OFF);

  // ---- prep + CSR build (prep_edges overlapped with gemm1 in k_fatA) ----
  hipMemsetAsync(ws + CNT8_OFF, 0, 3200000, stream);
  k_prep_w<<<21, 256, 0, stream>>>(W1, W2, W3, W1f, W2f, W3f);
  k_fatA<<<FATA_NB, 256, 0, stream>>>(eix, src, dst, cnt8, rank, x,
                                      (const bf16x8*)W1f, as1, ad1, h1q, aS, aD);
  k_scan_a<<<NBSC, 1024, 0, stream>>>(cnt8, rowptr, bsum);
  k_scan_b<<<1, 128, 0, stream>>>(bsum);
  k_scan_c<<<NBSC, 1024, 0, stream>>>(rowptr, bsum);
  k_fill_nr<<<(FILL_CH + 255) / 256, 256, 0, stream>>>(src, dst, rank, cnt8,
                                                       rowptr, csr);

  // ---- layer 1: 128 -> 8x32 concat (gemm2 fused into gather) ----
  k_msalpha1<<<NN / 4, 256, 0, stream>>>(rowptr, csr, aS, aD, alph);
  k_gather1f<<<NN / 16, 1024, 0, stream>>>(rowptr, csr, alph, h1q, b1,
                                           (const bf16x8*)W2f, as2, ad2,
                                           h2b, aS, aD);

  // ---- layer 2: 256 -> 32 (softmax + gemm3 fused into gather) ----
  k_gather2f<<<NN / 16, 512, 0, stream>>>(rowptr, csr, aS, aD, h2b, b2,
                                          (const bf16x8*)W3f, as3, ad3,
                                          h3b, aS2, aD2);

  // ---- layer 3: 32 -> 40 (softmax fused into gather) ----
  k_gather3f<<<NN / 4, 256, 0, stream>>>(rowptr, csr, aS2, aD2, h3b, b3, out);
}